// Round 1
// baseline (5707.047 us; speedup 1.0000x reference)
//
#include <hip/hip_runtime.h>
#include <math.h>

#define B_ 2
#define HEADS_ 16
#define HD_ 64
#define DIM_ 1024
#define TEXT_ 226
#define NC_ 8
#define FRAMES_ 4
#define PATCHES_ 384
#define IMG_ 1536
#define S_MAIN 1762
#define S2_ 1770
#define TD_ 512
#define FF_ 4096
#define ROWS_ (B_*S2_)   // 3540

// ---- workspace offsets (floats) ----
#define OFF_S1   0L
#define OFF_S2   12288L
#define OFF_MISC 24576L
#define OFF_SIM  25600L
#define OFF_IMAP 222208L
#define OFF_AC   418816L
#define OFF_X    435200L
#define OFF_PROJ 4060160L
#define OFF_XN   7685120L
#define OFF_Q    11310080L
#define OFF_K    14935040L
#define OFF_V    18560000L
#define OFF_AO   22184960L
#define OFF_FFH  OFF_Q     // reuses q/k/v/ao region after maps done

// ---- output offsets (floats) ----
#define O_H    0L
#define O_E    3145728L
#define O_C    3608576L
#define O_SELI 3624960L
#define O_ISUM 3637248L
#define O_CMAP 3649536L
#define O_XMAP 3661824L

// s1/s2 = silu(temb) @ norm_w + norm_b, both mats
__global__ __launch_bounds__(256) void k_silu_mod(
    const float* __restrict__ temb, const float* __restrict__ w1, const float* __restrict__ b1,
    const float* __restrict__ w2, const float* __restrict__ b2,
    float* __restrict__ s1, float* __restrict__ s2)
{
    int idx = blockIdx.x * 256 + threadIdx.x;   // < 24576
    int which = idx / 12288;
    int r = idx % 12288;
    int b = r / 6144, n = r % 6144;
    const float* w = which ? w2 : w1;
    const float* bb = which ? b2 : b1;
    const float* t = temb + b * TD_;
    float acc = 0.f;
    for (int k = 0; k < TD_; ++k) {
        float tv = t[k];
        float sv = tv / (1.f + expf(-tv));
        acc += sv * w[(long)k * 6144 + n];
    }
    (which ? s2 : s1)[b * 6144 + n] = acc + bb[n];
}

// fused layernorm + adaLN modulation into combined (B,1770,1024) buffer
__global__ __launch_bounds__(256) void k_ln_mod(
    const float* pe, long bse, const float* ph, long bsh, const float* pc, long bsc,
    const float* __restrict__ smod, const float* __restrict__ lnw, const float* __restrict__ lnb,
    float* __restrict__ out)
{
    long row = blockIdx.x;
    int b = (int)(row / S2_), s = (int)(row % S2_);
    const float* src; int shiftB, scaleB;
    if (s < TEXT_)       { src = pe + (long)b*bse + (long)s*DIM_;          shiftB = 3072; scaleB = 4096; }
    else if (s < S_MAIN) { src = ph + (long)b*bsh + (long)(s-TEXT_)*DIM_;  shiftB = 0;    scaleB = 1024; }
    else                 { src = pc + (long)b*bsc + (long)(s-S_MAIN)*DIM_; shiftB = 3072; scaleB = 4096; }
    int tid = threadIdx.x;
    int col = tid * 4;
    float4 x = *(const float4*)(src + col);
    float lsum = x.x + x.y + x.z + x.w;
    float lsq  = x.x*x.x + x.y*x.y + x.z*x.z + x.w*x.w;
    __shared__ float r1[256], r2[256];
    r1[tid] = lsum; r2[tid] = lsq; __syncthreads();
    for (int st = 128; st; st >>= 1) {
        if (tid < st) { r1[tid] += r1[tid+st]; r2[tid] += r2[tid+st]; }
        __syncthreads();
    }
    float mu = r1[0] * (1.f / DIM_);
    float var = r2[0] * (1.f / DIM_) - mu * mu;
    float rstd = rsqrtf(var + 1e-5f);
    const float* sb = smod + (long)b * 6144;
    float xs[4] = {x.x, x.y, x.z, x.w};
    float res[4];
    #pragma unroll
    for (int i = 0; i < 4; ++i) {
        int cc = col + i;
        float yy = (xs[i] - mu) * rstd * lnw[cc] + lnb[cc];
        res[i] = yy * (1.f + sb[scaleB + cc]) + sb[shiftB + cc];
    }
    *(float4*)(out + row * DIM_ + col) = make_float4(res[0], res[1], res[2], res[3]);
}

// fp32 tiled GEMM: C = act(A@W + bias). A (M,K) rm, W (K,N) rm.
// headed=1: store C[(b,h,s,d)] layout with b=r/1770, s=r%1770, h=n>>6, d=n&63
__global__ __launch_bounds__(256) void k_gemm(
    const float* __restrict__ A, const float* __restrict__ W, const float* __restrict__ bias,
    float* __restrict__ C, int M, int N, int K, int act, int headed)
{
    __shared__ float As[16][68];
    __shared__ float Bs[16][68];
    int tid = threadIdx.x;
    int bm = blockIdx.y * 64, bn = blockIdx.x * 64;
    int tr = tid >> 4, tc = tid & 15;
    int ar = tid >> 2, akk = (tid & 3) * 4;
    int bkk = tid >> 4, bn4 = (tid & 15) * 4;
    float acc[4][4] = {{0.f}};
    int garow = bm + ar;
    const float* Aptr = A + (size_t)garow * K + akk;
    const float* Wptr = W + (size_t)bkk * N + bn + bn4;
    for (int k0 = 0; k0 < K; k0 += 16) {
        float4 av = make_float4(0.f, 0.f, 0.f, 0.f);
        if (garow < M) av = *(const float4*)(Aptr + k0);
        As[akk+0][ar] = av.x; As[akk+1][ar] = av.y; As[akk+2][ar] = av.z; As[akk+3][ar] = av.w;
        float4 bv = *(const float4*)(Wptr + (size_t)k0 * N);
        Bs[bkk][bn4+0] = bv.x; Bs[bkk][bn4+1] = bv.y; Bs[bkk][bn4+2] = bv.z; Bs[bkk][bn4+3] = bv.w;
        __syncthreads();
        #pragma unroll
        for (int kk = 0; kk < 16; ++kk) {
            float4 a = *(const float4*)&As[kk][tr*4];
            float4 bq = *(const float4*)&Bs[kk][tc*4];
            float avv[4] = {a.x, a.y, a.z, a.w};
            float bvv[4] = {bq.x, bq.y, bq.z, bq.w};
            #pragma unroll
            for (int i = 0; i < 4; ++i)
                #pragma unroll
                for (int j = 0; j < 4; ++j)
                    acc[i][j] += avv[i] * bvv[j];
        }
        __syncthreads();
    }
    #pragma unroll
    for (int i = 0; i < 4; ++i) {
        int r = bm + tr*4 + i;
        if (r >= M) continue;
        #pragma unroll
        for (int j = 0; j < 4; ++j) {
            int n = bn + tc*4 + j;
            float v = acc[i][j] + (bias ? bias[n] : 0.f);
            if (act == 1) {
                float x = v;
                v = 0.5f * x * (1.f + tanhf(0.7978845608028654f * (x + 0.044715f * x*x*x)));
            }
            if (headed) {
                int b = r / S2_, s = r % S2_;
                int hh = n >> 6, d = n & 63;
                C[(((size_t)b*HEADS_ + hh)*S2_ + s)*64 + d] = v;
            } else {
                C[(size_t)r * N + n] = v;
            }
        }
    }
}

// per-head layernorm (eps 1e-6) + RoPE for image rows, in place on q_h / k_h
__global__ __launch_bounds__(256) void k_qk_ln_rope(
    float* qh, float* kh, const float* __restrict__ nqw, const float* __restrict__ nqb,
    const float* __restrict__ nkw, const float* __restrict__ nkb,
    const float* __restrict__ rc, const float* __restrict__ rs)
{
    int which = blockIdx.y;
    int wid = threadIdx.x >> 6;
    int lane = threadIdx.x & 63;
    long row = (long)blockIdx.x * 4 + wid;   // < 56640 = 2*16*1770
    long s = row % S2_;
    float* base = (which ? kh : qh) + row * 64;
    const float* w  = which ? nkw : nqw;
    const float* bb = which ? nkb : nqb;
    float x = base[lane];
    float sum = x;
    for (int off = 1; off < 64; off <<= 1) sum += __shfl_xor(sum, off, 64);
    float mu = sum * (1.f / 64.f);
    float dx = x - mu;
    float v = dx * dx;
    for (int off = 1; off < 64; off <<= 1) v += __shfl_xor(v, off, 64);
    float rstd = rsqrtf(v * (1.f / 64.f) + 1e-6f);
    float y = dx * rstd * w[lane] + bb[lane];
    if (s >= TEXT_ && s < S_MAIN) {
        long p = s - TEXT_;
        float part = __shfl_xor(y, 1, 64);
        float rot = (lane & 1) ? part : -part;
        y = y * rc[p*64 + lane] + rot * rs[p*64 + lane];
    }
    base[lane] = y;
}

// flash attention: 16-query tiles, 64-key chunks, two key ranges.
// q/k/v in (B,H,1770,64). out in (B,H,NQ,64).
__global__ __launch_bounds__(256) void k_flash(
    const float* __restrict__ qp, const float* __restrict__ kp, const float* __restrict__ vp,
    float* __restrict__ outp, int NQ, int q_off, int r0s, int r0e, int r1s, int r1e)
{
    int h = blockIdx.y, b = blockIdx.z;
    int qt = blockIdx.x * 16;
    int tid = threadIdx.x;
    int q = tid >> 4;
    int lane16 = tid & 15;
    int dbase = lane16 * 4;
    __shared__ float qs[16][64];
    __shared__ float ks[64][64];
    __shared__ float vs[64][64];
    __shared__ float ps[16][64];
    const float* qbase = qp + (((size_t)b*HEADS_ + h)*S2_ + q_off) * 64;
    const float* kbase = kp + (((size_t)b*HEADS_ + h)*S2_) * 64;
    const float* vbase = vp + (((size_t)b*HEADS_ + h)*S2_) * 64;
    #pragma unroll
    for (int i = 0; i < 4; ++i) {
        int l = tid + i*256; int row = l >> 6, d = l & 63;
        int gq = qt + row;
        qs[row][d] = (gq < NQ) ? qbase[(size_t)gq*64 + d] : 0.f;
    }
    float m = -INFINITY, lsum = 0.f;
    float o0 = 0.f, o1 = 0.f, o2 = 0.f, o3 = 0.f;
    __syncthreads();
    for (int rgi = 0; rgi < 2; ++rgi) {
        int rstart = rgi ? r1s : r0s, rend = rgi ? r1e : r0e;
        for (int j0 = rstart; j0 < rend; j0 += 64) {
            int cnt = min(64, rend - j0);
            #pragma unroll
            for (int i = 0; i < 16; ++i) {
                int l = tid + i*256; int row = l >> 6, d = l & 63;
                bool ok = row < cnt;
                ks[row][d] = ok ? kbase[(size_t)(j0+row)*64 + d] : 0.f;
                vs[row][d] = ok ? vbase[(size_t)(j0+row)*64 + d] : 0.f;
            }
            __syncthreads();
            float sc[4];
            #pragma unroll
            for (int jj = 0; jj < 4; ++jj) {
                int j = lane16*4 + jj;
                float acc = 0.f;
                #pragma unroll
                for (int d = 0; d < 64; d += 4) {
                    float4 qv = *(const float4*)&qs[q][d];
                    float4 kv = *(const float4*)&ks[j][d];
                    acc += qv.x*kv.x + qv.y*kv.y + qv.z*kv.z + qv.w*kv.w;
                }
                sc[jj] = (j < cnt) ? acc * 0.125f : -INFINITY;
            }
            float cmax = fmaxf(fmaxf(sc[0], sc[1]), fmaxf(sc[2], sc[3]));
            for (int off = 1; off < 16; off <<= 1)
                cmax = fmaxf(cmax, __shfl_xor(cmax, off, 64));
            float newm = fmaxf(m, cmax);
            float alpha = expf(m - newm);
            float pv[4]; float psum = 0.f;
            #pragma unroll
            for (int jj = 0; jj < 4; ++jj) { pv[jj] = expf(sc[jj] - newm); psum += pv[jj]; }
            for (int off = 1; off < 16; off <<= 1) psum += __shfl_xor(psum, off, 64);
            lsum = lsum * alpha + psum;
            m = newm;
            o0 *= alpha; o1 *= alpha; o2 *= alpha; o3 *= alpha;
            #pragma unroll
            for (int jj = 0; jj < 4; ++jj) ps[q][lane16*4 + jj] = pv[jj];
            __syncthreads();
            #pragma unroll 8
            for (int j = 0; j < 64; ++j) {
                float p = ps[q][j];
                float4 vv = *(const float4*)&vs[j][dbase];
                o0 += p*vv.x; o1 += p*vv.y; o2 += p*vv.z; o3 += p*vv.w;
            }
            __syncthreads();
        }
    }
    int gq = qt + q;
    if (gq < NQ) {
        float inv = 1.f / lsum;
        float* o = outp + (((size_t)b*HEADS_ + h)*NQ + gq)*64 + dbase;
        o[0] = o0*inv; o[1] = o1*inv; o[2] = o2*inv; o[3] = o3*inv;
    }
}

// head_score[h] = std over p of mean over d of img_hidden[1]
__global__ __launch_bounds__(256) void k_head_score(const float* __restrict__ ao, float* __restrict__ score)
{
    int h = blockIdx.x, tid = threadIdx.x;
    const float* base = ao + (((long)HEADS_ + h)*S_MAIN + TEXT_)*64;
    float sA = 0.f, sB = 0.f;
    for (int p = tid; p < IMG_; p += 256) {
        const float* r = base + (long)p*64;
        float mm = 0.f;
        for (int d = 0; d < 64; d += 4) {
            float4 v = *(const float4*)(r + d);
            mm += v.x + v.y + v.z + v.w;
        }
        mm *= (1.f / 64.f);
        sA += mm; sB += mm*mm;
    }
    __shared__ float r1[256], r2[256];
    r1[tid] = sA; r2[tid] = sB; __syncthreads();
    for (int st = 128; st; st >>= 1) {
        if (tid < st) { r1[tid] += r1[tid+st]; r2[tid] += r2[tid+st]; }
        __syncthreads();
    }
    if (tid == 0) {
        float mean = r1[0] / IMG_, ms = r2[0] / IMG_;
        score[h] = sqrtf(fmaxf(ms - mean*mean, 0.f));
    }
}

__global__ void k_top4(const float* __restrict__ score, int* __restrict__ sel)
{
    if (threadIdx.x == 0 && blockIdx.x == 0) {
        int used = 0;
        for (int k = 0; k < 4; ++k) {
            float best = -INFINITY; int bi = 0;
            for (int h2 = 0; h2 < 16; ++h2) {
                if (used & (1 << h2)) continue;
                if (score[h2] > best) { best = score[h2]; bi = h2; }
            }
            used |= 1 << bi; sel[k] = bi;
        }
    }
}

// sim[h,t,fp] = iq1[h,fp,:] . ck1[h,t,:]; also per-(h,t,f) argmax over p
__global__ __launch_bounds__(512) void k_sim(
    const float* __restrict__ qh, const float* __restrict__ kh,
    float* __restrict__ sim, int* __restrict__ selvis)
{
    int blk = blockIdx.x;    // (h*8+t)*4+f
    int h = blk >> 5, t = (blk >> 2) & 7, f = blk & 3;
    int tid = threadIdx.x;
    __shared__ float ckv[64];
    if (tid < 64) ckv[tid] = kh[(((long)HEADS_ + h)*S2_ + S_MAIN + t)*64 + tid];
    __syncthreads();
    float val = -INFINITY; int idx = 0x7fffffff;
    if (tid < PATCHES_) {
        const float* qrow = qh + (((long)HEADS_ + h)*S2_ + TEXT_ + f*PATCHES_ + tid)*64;
        float acc = 0.f;
        for (int d = 0; d < 64; d += 4) {
            float4 qv = *(const float4*)(qrow + d);
            acc += qv.x*ckv[d] + qv.y*ckv[d+1] + qv.z*ckv[d+2] + qv.w*ckv[d+3];
        }
        sim[((long)h*NC_ + t)*IMG_ + f*PATCHES_ + tid] = acc;
        val = acc; idx = tid;
    }
    __shared__ float sv[512]; __shared__ int si[512];
    sv[tid] = val; si[tid] = idx; __syncthreads();
    for (int st = 256; st; st >>= 1) {
        if (tid < st) {
            float v2 = sv[tid+st]; int i2 = si[tid+st];
            if (v2 > sv[tid] || (v2 == sv[tid] && i2 < si[tid])) { sv[tid] = v2; si[tid] = i2; }
        }
        __syncthreads();
    }
    if (tid == 0) selvis[blk] = si[0];
}

__global__ __launch_bounds__(256) void k_cross(const float* __restrict__ sim, float* __restrict__ out)
{
    int i = blockIdx.x*256 + threadIdx.x;   // < 12288
    int c = i / IMG_, p = i % IMG_;
    float acc = 0.f;
    for (int h = 0; h < 16; ++h) acc += sim[((long)h*NC_ + c)*IMG_ + p];
    out[O_XMAP + i] = acc * (1.f / 16.f);
}

__global__ __launch_bounds__(256) void k_concept_maps(
    const float* __restrict__ ac, const float* __restrict__ ao, float* __restrict__ out)
{
    int i = blockIdx.x*256 + threadIdx.x;   // < 12288
    int c = i / IMG_, p = i % IMG_;
    float acc = 0.f;
    for (int h = 0; h < 16; ++h) {
        const float* a = ac + (((long)HEADS_ + h)*NC_ + c)*64;
        const float* g = ao + (((long)HEADS_ + h)*S_MAIN + TEXT_ + p)*64;
        for (int d = 0; d < 64; d += 4) {
            float4 av = *(const float4*)(a + d);
            float4 gv = *(const float4*)(g + d);
            acc += av.x*gv.x + av.y*gv.y + av.z*gv.z + av.w*gv.w;
        }
    }
    out[O_CMAP + i] = acc;
}

__global__ void k_imap_raw(const float* __restrict__ ao, const int* __restrict__ selvis,
                           float* __restrict__ imap)
{
    int blk = blockIdx.x;   // (h*8+t)*4+f
    int h = blk >> 5, t = (blk >> 2) & 7, f = blk & 3;
    int tid = threadIdx.x;  // 384
    __shared__ float sel[64];
    int pstar = selvis[blk];
    if (tid < 64) sel[tid] = ao[(((long)HEADS_ + h)*S_MAIN + TEXT_ + f*PATCHES_ + pstar)*64 + tid];
    __syncthreads();
    const float* g = ao + (((long)HEADS_ + h)*S_MAIN + TEXT_ + f*PATCHES_ + tid)*64;
    float acc = 0.f;
    for (int d = 0; d < 64; d += 4) {
        float4 gv = *(const float4*)(g + d);
        acc += gv.x*sel[d] + gv.y*sel[d+1] + gv.z*sel[d+2] + gv.w*sel[d+3];
    }
    imap[((long)h*NC_ + t)*IMG_ + f*PATCHES_ + tid] = acc;
}

__global__ __launch_bounds__(256) void k_imap_norm(float* __restrict__ imap)
{
    int i = blockIdx.x*256 + threadIdx.x;   // < 24576
    int h = i / IMG_, fp = i % IMG_;
    float v[8]; float mu = 0.f;
    #pragma unroll
    for (int t = 0; t < 8; ++t) { v[t] = imap[((long)h*NC_ + t)*IMG_ + fp]; mu += v[t]; }
    mu *= 0.125f;
    float var = 0.f;
    #pragma unroll
    for (int t = 0; t < 8; ++t) var += (v[t]-mu)*(v[t]-mu);
    float sd = sqrtf(var * (1.f / 7.f));
    float inv = 1.f / (sd + 1e-6f);
    #pragma unroll
    for (int t = 0; t < 8; ++t) imap[((long)h*NC_ + t)*IMG_ + fp] = (v[t]-mu)*inv;
}

__global__ __launch_bounds__(256) void k_imap_reduce(
    const float* __restrict__ imap, const int* __restrict__ sel, float* __restrict__ out)
{
    int i = blockIdx.x*256 + threadIdx.x;   // < 12288
    int t = i / IMG_, fp = i % IMG_;
    float sum = 0.f;
    for (int h = 0; h < 16; ++h) sum += imap[((long)h*NC_ + t)*IMG_ + fp];
    float ss = 0.f;
    for (int k = 0; k < 4; ++k) { int h = sel[k]; ss += imap[((long)h*NC_ + t)*IMG_ + fp]; }
    out[O_ISUM + i] = sum;
    out[O_SELI + i] = ss * 0.25f;
}

// merge (B,H,S,64) -> (B,S,1024); concept rows from ac
__global__ __launch_bounds__(256) void k_merge(
    const float* __restrict__ ao, const float* __restrict__ ac, float* __restrict__ xo)
{
    long i = (long)blockIdx.x*256 + threadIdx.x;   // < 3,624,960
    int col = (int)(i & 1023);
    long row = i >> 10;
    int b = (int)(row / S2_), s = (int)(row % S2_);
    int h = col >> 6, d = col & 63;
    float v;
    if (s < S_MAIN) v = ao[(((long)b*HEADS_ + h)*S_MAIN + s)*64 + d];
    else            v = ac[(((long)b*HEADS_ + h)*NC_ + (s - S_MAIN))*64 + d];
    xo[i] = v;
}

__global__ __launch_bounds__(256) void k_residual1(
    const float* __restrict__ pe, const float* __restrict__ ph, const float* __restrict__ pc,
    const float* __restrict__ proj, const float* __restrict__ s1, float* __restrict__ X)
{
    long i = (long)blockIdx.x*256 + threadIdx.x;
    int col = (int)(i & 1023);
    long row = i >> 10;
    int b = (int)(row / S2_), s = (int)(row % S2_);
    const float* sb = s1 + (long)b * 6144;
    float orig, gate;
    if (s < TEXT_)       { orig = pe[((long)b*TEXT_ + s)*DIM_ + col];            gate = sb[5120 + col]; }
    else if (s < S_MAIN) { orig = ph[((long)b*IMG_ + (s-TEXT_))*DIM_ + col];     gate = sb[2048 + col]; }
    else                 { orig = pc[((long)b*NC_ + (s-S_MAIN))*DIM_ + col];     gate = sb[5120 + col]; }
    X[i] = orig + gate * proj[i];
}

__global__ __launch_bounds__(256) void k_final(
    const float* __restrict__ X, const float* __restrict__ ffo,
    const float* __restrict__ s2, float* __restrict__ out)
{
    long i = (long)blockIdx.x*256 + threadIdx.x;
    int col = (int)(i & 1023);
    long row = i >> 10;
    int b = (int)(row / S2_), s = (int)(row % S2_);
    const float* sb = s2 + (long)b * 6144;
    float gate; float* o;
    if (s < TEXT_)       { gate = sb[5120 + col]; o = out + O_E + ((long)b*TEXT_ + s)*DIM_ + col; }
    else if (s < S_MAIN) { gate = sb[2048 + col]; o = out + O_H + ((long)b*IMG_ + (s-TEXT_))*DIM_ + col; }
    else                 { gate = sb[5120 + col]; o = out + O_C + ((long)b*NC_ + (s-S_MAIN))*DIM_ + col; }
    *o = X[i] + gate * ffo[i];
}

extern "C" void kernel_launch(void* const* d_in, const int* in_sizes, int n_in,
                              void* d_out, int out_size, void* d_ws, size_t ws_size,
                              hipStream_t stream)
{
    (void)in_sizes; (void)n_in; (void)out_size; (void)ws_size;
    const float* h_in = (const float*)d_in[0];
    const float* e_in = (const float*)d_in[1];
    const float* c_in = (const float*)d_in[2];
    const float* temb = (const float*)d_in[3];
    const float* rcos = (const float*)d_in[4];
    const float* rsin = (const float*)d_in[5];
    const float* n1w  = (const float*)d_in[6];
    const float* n1b  = (const float*)d_in[7];
    const float* ln1w = (const float*)d_in[8];
    const float* ln1b = (const float*)d_in[9];
    const float* n2w  = (const float*)d_in[10];
    const float* n2b  = (const float*)d_in[11];
    const float* ln2w = (const float*)d_in[12];
    const float* ln2b = (const float*)d_in[13];
    const float* wq   = (const float*)d_in[14];
    const float* wk   = (const float*)d_in[15];
    const float* wv   = (const float*)d_in[16];
    const float* nqw  = (const float*)d_in[17];
    const float* nqb  = (const float*)d_in[18];
    const float* nkw  = (const float*)d_in[19];
    const float* nkb  = (const float*)d_in[20];
    const float* wo   = (const float*)d_in[21];
    const float* bo   = (const float*)d_in[22];
    const float* fw1  = (const float*)d_in[23];
    const float* fb1  = (const float*)d_in[24];
    const float* fw2  = (const float*)d_in[25];
    const float* fb2  = (const float*)d_in[26];

    float* ws  = (float*)d_ws;
    float* out = (float*)d_out;
    float* s1   = ws + OFF_S1;
    float* s2   = ws + OFF_S2;
    float* score  = ws + OFF_MISC;
    int*   selh   = (int*)(ws + OFF_MISC + 16);
    int*   selvis = (int*)(ws + OFF_MISC + 32);
    float* sim  = ws + OFF_SIM;
    float* imap = ws + OFF_IMAP;
    float* ac   = ws + OFF_AC;
    float* X    = ws + OFF_X;
    float* proj = ws + OFF_PROJ;
    float* xn   = ws + OFF_XN;
    float* qh   = ws + OFF_Q;
    float* kh   = ws + OFF_K;
    float* vh   = ws + OFF_V;
    float* ao   = ws + OFF_AO;
    float* ffh  = ws + OFF_FFH;
    float* ffo  = proj;   // reuse after residual1 consumed proj

    // adaLN modulation vectors
    hipLaunchKernelGGL(k_silu_mod, dim3(96), dim3(256), 0, stream, temb, n1w, n1b, n2w, n2b, s1, s2);
    // norm1 + modulation -> xn (B,1770,1024): [e | h | c]
    hipLaunchKernelGGL(k_ln_mod, dim3(ROWS_), dim3(256), 0, stream,
        e_in, (long)TEXT_*DIM_, h_in, (long)IMG_*DIM_, c_in, (long)NC_*DIM_, s1, ln1w, ln1b, xn);
    // QKV projections, headed layout (B,H,1770,64)
    dim3 g1(16, 56);
    hipLaunchKernelGGL(k_gemm, g1, dim3(256), 0, stream, xn, wq, (const float*)nullptr, qh, ROWS_, DIM_, DIM_, 0, 1);
    hipLaunchKernelGGL(k_gemm, g1, dim3(256), 0, stream, xn, wk, (const float*)nullptr, kh, ROWS_, DIM_, DIM_, 0, 1);
    hipLaunchKernelGGL(k_gemm, g1, dim3(256), 0, stream, xn, wv, (const float*)nullptr, vh, ROWS_, DIM_, DIM_, 0, 1);
    // QK layernorm + RoPE in place
    hipLaunchKernelGGL(k_qk_ln_rope, dim3(14160, 2), dim3(256), 0, stream, qh, kh, nqw, nqb, nkw, nkb, rcos, rsin);
    // main attention: queries rows [0,1762), keys [0,1762)
    hipLaunchKernelGGL(k_flash, dim3(111, 16, 2), dim3(256), 0, stream,
        qh, kh, vh, ao, S_MAIN, 0, 0, S_MAIN, 0, 0);
    // concept attention: queries = cq rows [1762,1770), keys = [ck | ik]
    hipLaunchKernelGGL(k_flash, dim3(1, 16, 2), dim3(256), 0, stream,
        qh, kh, vh, ac, NC_, S_MAIN, S_MAIN, S2_, TEXT_, S_MAIN);
    // ---- maps (batch 1) ----
    hipLaunchKernelGGL(k_head_score, dim3(16), dim3(256), 0, stream, ao, score);
    hipLaunchKernelGGL(k_top4, dim3(1), dim3(64), 0, stream, score, selh);
    hipLaunchKernelGGL(k_sim, dim3(512), dim3(512), 0, stream, qh, kh, sim, selvis);
    hipLaunchKernelGGL(k_cross, dim3(48), dim3(256), 0, stream, sim, out);
    hipLaunchKernelGGL(k_concept_maps, dim3(48), dim3(256), 0, stream, ac, ao, out);
    hipLaunchKernelGGL(k_imap_raw, dim3(512), dim3(384), 0, stream, ao, selvis, imap);
    hipLaunchKernelGGL(k_imap_norm, dim3(96), dim3(256), 0, stream, imap);
    hipLaunchKernelGGL(k_imap_reduce, dim3(48), dim3(256), 0, stream, imap, selh, out);
    // ---- merge + output projection + residual ----
    hipLaunchKernelGGL(k_merge, dim3(14160), dim3(256), 0, stream, ao, ac, xn);  // xn reused as xo
    hipLaunchKernelGGL(k_gemm, g1, dim3(256), 0, stream, xn, wo, bo, proj, ROWS_, DIM_, DIM_, 0, 0);
    hipLaunchKernelGGL(k_residual1, dim3(14160), dim3(256), 0, stream, e_in, h_in, c_in, proj, s1, X);
    // ---- norm2 + FF ----
    hipLaunchKernelGGL(k_ln_mod, dim3(ROWS_), dim3(256), 0, stream,
        X, (long)S2_*DIM_, X + (long)TEXT_*DIM_, (long)S2_*DIM_, X + (long)S_MAIN*DIM_, (long)S2_*DIM_,
        s2, ln2w, ln2b, xn);
    hipLaunchKernelGGL(k_gemm, dim3(64, 56), dim3(256), 0, stream, xn, fw1, fb1, ffh, ROWS_, FF_, DIM_, 1, 0);
    hipLaunchKernelGGL(k_gemm, dim3(16, 56), dim3(256), 0, stream, ffh, fw2, fb2, ffo, ROWS_, DIM_, FF_, 0, 0);
    hipLaunchKernelGGL(k_final, dim3(14160), dim3(256), 0, stream, X, ffo, s2, out);
}

// Round 2
// 3579.132 us; speedup vs baseline: 1.5945x; 1.5945x over previous
//
#include <hip/hip_runtime.h>
#include <math.h>

#define B_ 2
#define HEADS_ 16
#define HD_ 64
#define DIM_ 1024
#define TEXT_ 226
#define NC_ 8
#define FRAMES_ 4
#define PATCHES_ 384
#define IMG_ 1536
#define S_MAIN 1762
#define S2_ 1770
#define TD_ 512
#define FF_ 4096
#define ROWS_ (B_*S2_)   // 3540

// ---- workspace offsets (floats) ----
#define OFF_S1   0L
#define OFF_S2   12288L
#define OFF_MISC 24576L
#define OFF_SIM  25600L
#define OFF_IMAP 222208L
#define OFF_AC   418816L
#define OFF_X    435200L
#define OFF_PROJ 4060160L
#define OFF_XN   7685120L
#define OFF_Q    11310080L
#define OFF_K    14935040L
#define OFF_V    18560000L
#define OFF_AO   22184960L
#define OFF_FFH  OFF_Q     // reuses q/k/v/ao region after maps done

// ---- output offsets (floats) ----
#define O_H    0L
#define O_E    3145728L
#define O_C    3608576L
#define O_SELI 3624960L
#define O_ISUM 3637248L
#define O_CMAP 3649536L
#define O_XMAP 3661824L

// s1/s2 = silu(temb) @ norm_w + norm_b, both mats
__global__ __launch_bounds__(256) void k_silu_mod(
    const float* __restrict__ temb, const float* __restrict__ w1, const float* __restrict__ b1,
    const float* __restrict__ w2, const float* __restrict__ b2,
    float* __restrict__ s1, float* __restrict__ s2)
{
    int idx = blockIdx.x * 256 + threadIdx.x;   // < 24576
    int which = idx / 12288;
    int r = idx % 12288;
    int b = r / 6144, n = r % 6144;
    const float* w = which ? w2 : w1;
    const float* bb = which ? b2 : b1;
    const float* t = temb + b * TD_;
    float acc = 0.f;
    for (int k = 0; k < TD_; ++k) {
        float tv = t[k];
        float sv = tv / (1.f + expf(-tv));
        acc += sv * w[(long)k * 6144 + n];
    }
    (which ? s2 : s1)[b * 6144 + n] = acc + bb[n];
}

// fused layernorm + adaLN modulation into combined (B,1770,1024) buffer
__global__ __launch_bounds__(256) void k_ln_mod(
    const float* pe, long bse, const float* ph, long bsh, const float* pc, long bsc,
    const float* __restrict__ smod, const float* __restrict__ lnw, const float* __restrict__ lnb,
    float* __restrict__ out)
{
    long row = blockIdx.x;
    int b = (int)(row / S2_), s = (int)(row % S2_);
    const float* src; int shiftB, scaleB;
    if (s < TEXT_)       { src = pe + (long)b*bse + (long)s*DIM_;          shiftB = 3072; scaleB = 4096; }
    else if (s < S_MAIN) { src = ph + (long)b*bsh + (long)(s-TEXT_)*DIM_;  shiftB = 0;    scaleB = 1024; }
    else                 { src = pc + (long)b*bsc + (long)(s-S_MAIN)*DIM_; shiftB = 3072; scaleB = 4096; }
    int tid = threadIdx.x;
    int col = tid * 4;
    float4 x = *(const float4*)(src + col);
    float lsum = x.x + x.y + x.z + x.w;
    float lsq  = x.x*x.x + x.y*x.y + x.z*x.z + x.w*x.w;
    __shared__ float r1[256], r2[256];
    r1[tid] = lsum; r2[tid] = lsq; __syncthreads();
    for (int st = 128; st; st >>= 1) {
        if (tid < st) { r1[tid] += r1[tid+st]; r2[tid] += r2[tid+st]; }
        __syncthreads();
    }
    float mu = r1[0] * (1.f / DIM_);
    float var = r2[0] * (1.f / DIM_) - mu * mu;
    float rstd = rsqrtf(var + 1e-5f);
    const float* sb = smod + (long)b * 6144;
    float xs[4] = {x.x, x.y, x.z, x.w};
    float res[4];
    #pragma unroll
    for (int i = 0; i < 4; ++i) {
        int cc = col + i;
        float yy = (xs[i] - mu) * rstd * lnw[cc] + lnb[cc];
        res[i] = yy * (1.f + sb[scaleB + cc]) + sb[shiftB + cc];
    }
    *(float4*)(out + row * DIM_ + col) = make_float4(res[0], res[1], res[2], res[3]);
}

// fp32 tiled GEMM: C = act(A@W + bias). A (M,K) rm, W (K,N) rm.
// headed=1: store C[(b,h,s,d)] layout with b=r/1770, s=r%1770, h=n>>6, d=n&63
__global__ __launch_bounds__(256) void k_gemm(
    const float* __restrict__ A, const float* __restrict__ W, const float* __restrict__ bias,
    float* __restrict__ C, int M, int N, int K, int act, int headed)
{
    __shared__ float As[16][68];
    __shared__ float Bs[16][68];
    int tid = threadIdx.x;
    int bm = blockIdx.y * 64, bn = blockIdx.x * 64;
    int tr = tid >> 4, tc = tid & 15;
    int ar = tid >> 2, akk = (tid & 3) * 4;
    int bkk = tid >> 4, bn4 = (tid & 15) * 4;
    float acc[4][4] = {{0.f}};
    int garow = bm + ar;
    const float* Aptr = A + (size_t)garow * K + akk;
    const float* Wptr = W + (size_t)bkk * N + bn + bn4;
    for (int k0 = 0; k0 < K; k0 += 16) {
        float4 av = make_float4(0.f, 0.f, 0.f, 0.f);
        if (garow < M) av = *(const float4*)(Aptr + k0);
        As[akk+0][ar] = av.x; As[akk+1][ar] = av.y; As[akk+2][ar] = av.z; As[akk+3][ar] = av.w;
        float4 bv = *(const float4*)(Wptr + (size_t)k0 * N);
        Bs[bkk][bn4+0] = bv.x; Bs[bkk][bn4+1] = bv.y; Bs[bkk][bn4+2] = bv.z; Bs[bkk][bn4+3] = bv.w;
        __syncthreads();
        #pragma unroll
        for (int kk = 0; kk < 16; ++kk) {
            float4 a = *(const float4*)&As[kk][tr*4];
            float4 bq = *(const float4*)&Bs[kk][tc*4];
            float avv[4] = {a.x, a.y, a.z, a.w};
            float bvv[4] = {bq.x, bq.y, bq.z, bq.w};
            #pragma unroll
            for (int i = 0; i < 4; ++i)
                #pragma unroll
                for (int j = 0; j < 4; ++j)
                    acc[i][j] += avv[i] * bvv[j];
        }
        __syncthreads();
    }
    #pragma unroll
    for (int i = 0; i < 4; ++i) {
        int r = bm + tr*4 + i;
        if (r >= M) continue;
        #pragma unroll
        for (int j = 0; j < 4; ++j) {
            int n = bn + tc*4 + j;
            float v = acc[i][j] + (bias ? bias[n] : 0.f);
            if (act == 1) {
                float x = v;
                v = 0.5f * x * (1.f + tanhf(0.7978845608028654f * (x + 0.044715f * x*x*x)));
            }
            if (headed) {
                int b = r / S2_, s = r % S2_;
                int hh = n >> 6, d = n & 63;
                C[(((size_t)b*HEADS_ + hh)*S2_ + s)*64 + d] = v;
            } else {
                C[(size_t)r * N + n] = v;
            }
        }
    }
}

// per-head layernorm (eps 1e-6) + RoPE for image rows, in place on q_h / k_h
__global__ __launch_bounds__(256) void k_qk_ln_rope(
    float* qh, float* kh, const float* __restrict__ nqw, const float* __restrict__ nqb,
    const float* __restrict__ nkw, const float* __restrict__ nkb,
    const float* __restrict__ rc, const float* __restrict__ rs)
{
    int which = blockIdx.y;
    int wid = threadIdx.x >> 6;
    int lane = threadIdx.x & 63;
    long row = (long)blockIdx.x * 4 + wid;   // < 56640 = 2*16*1770
    long s = row % S2_;
    float* base = (which ? kh : qh) + row * 64;
    const float* w  = which ? nkw : nqw;
    const float* bb = which ? nkb : nqb;
    float x = base[lane];
    float sum = x;
    for (int off = 1; off < 64; off <<= 1) sum += __shfl_xor(sum, off, 64);
    float mu = sum * (1.f / 64.f);
    float dx = x - mu;
    float v = dx * dx;
    for (int off = 1; off < 64; off <<= 1) v += __shfl_xor(v, off, 64);
    float rstd = rsqrtf(v * (1.f / 64.f) + 1e-6f);
    float y = dx * rstd * w[lane] + bb[lane];
    if (s >= TEXT_ && s < S_MAIN) {
        long p = s - TEXT_;
        float part = __shfl_xor(y, 1, 64);
        float rot = (lane & 1) ? part : -part;
        y = y * rc[p*64 + lane] + rot * rs[p*64 + lane];
    }
    base[lane] = y;
}

// flash attention: 16-query tiles, 64-key chunks, two key ranges.
// q/k/v in (B,H,1770,64). out in (B,H,NQ,64).
// LDS tiles padded to stride 68 (272B): lane16's K-row bank base = lane16*4 mod 32
// -> 2-way aliasing only (free). Q read hoisted over jj. P passed via shfl, no LDS.
__global__ __launch_bounds__(256) void k_flash(
    const float* __restrict__ qp, const float* __restrict__ kp, const float* __restrict__ vp,
    float* __restrict__ outp, int NQ, int q_off, int r0s, int r0e, int r1s, int r1e)
{
    int h = blockIdx.y, b = blockIdx.z;
    int qt = blockIdx.x * 16;
    int tid = threadIdx.x;
    int q = tid >> 4;        // 0..15 (4 per wave)
    int lane16 = tid & 15;
    int dbase = lane16 * 4;
    __shared__ float qs[16][68];
    __shared__ float ks[64][68];
    __shared__ float vs[64][68];
    const float* qbase = qp + (((size_t)b*HEADS_ + h)*S2_ + q_off) * 64;
    const float* kbase = kp + (((size_t)b*HEADS_ + h)*S2_) * 64;
    const float* vbase = vp + (((size_t)b*HEADS_ + h)*S2_) * 64;
    #pragma unroll
    for (int i = 0; i < 4; ++i) {
        int l = tid + i*256; int row = l >> 6, d = l & 63;
        int gq = qt + row;
        qs[row][d] = (gq < NQ) ? qbase[(size_t)gq*64 + d] : 0.f;
    }
    float m = -INFINITY, lsum = 0.f;
    float o0 = 0.f, o1 = 0.f, o2 = 0.f, o3 = 0.f;
    __syncthreads();
    for (int rgi = 0; rgi < 2; ++rgi) {
        int rstart = rgi ? r1s : r0s, rend = rgi ? r1e : r0e;
        for (int j0 = rstart; j0 < rend; j0 += 64) {
            int cnt = min(64, rend - j0);
            #pragma unroll
            for (int i = 0; i < 16; ++i) {
                int l = tid + i*256; int row = l >> 6, d = l & 63;
                bool ok = row < cnt;
                ks[row][d] = ok ? kbase[(size_t)(j0+row)*64 + d] : 0.f;
                vs[row][d] = ok ? vbase[(size_t)(j0+row)*64 + d] : 0.f;
            }
            __syncthreads();
            // scores: thread (q,lane16) computes j = lane16 + jj*16
            float sc[4] = {0.f, 0.f, 0.f, 0.f};
            #pragma unroll
            for (int d = 0; d < 64; d += 4) {
                float4 qv = *(const float4*)&qs[q][d];
                #pragma unroll
                for (int jj = 0; jj < 4; ++jj) {
                    float4 kv = *(const float4*)&ks[lane16 + jj*16][d];
                    sc[jj] += qv.x*kv.x + qv.y*kv.y + qv.z*kv.z + qv.w*kv.w;
                }
            }
            #pragma unroll
            for (int jj = 0; jj < 4; ++jj) {
                int j = lane16 + jj*16;
                sc[jj] = (j < cnt) ? sc[jj] * 0.125f : -INFINITY;
            }
            float cmax = fmaxf(fmaxf(sc[0], sc[1]), fmaxf(sc[2], sc[3]));
            #pragma unroll
            for (int off = 1; off < 16; off <<= 1)
                cmax = fmaxf(cmax, __shfl_xor(cmax, off, 64));
            float newm = fmaxf(m, cmax);
            float alpha = expf(m - newm);
            float pv[4]; float psum = 0.f;
            #pragma unroll
            for (int jj = 0; jj < 4; ++jj) { pv[jj] = expf(sc[jj] - newm); psum += pv[jj]; }
            #pragma unroll
            for (int off = 1; off < 16; off <<= 1) psum += __shfl_xor(psum, off, 64);
            lsum = lsum * alpha + psum;
            m = newm;
            o0 *= alpha; o1 *= alpha; o2 *= alpha; o3 *= alpha;
            // PV: p for (q,j) lives in lane q*16 + (j&15), reg jj=j>>4
            int srcbase = q << 4;
            #pragma unroll 8
            for (int j = 0; j < 64; ++j) {
                float p = __shfl(pv[j >> 4], srcbase | (j & 15), 64);
                float4 vv = *(const float4*)&vs[j][dbase];
                o0 += p*vv.x; o1 += p*vv.y; o2 += p*vv.z; o3 += p*vv.w;
            }
            __syncthreads();
        }
    }
    int gq = qt + q;
    if (gq < NQ) {
        float inv = 1.f / lsum;
        float* o = outp + (((size_t)b*HEADS_ + h)*NQ + gq)*64 + dbase;
        o[0] = o0*inv; o[1] = o1*inv; o[2] = o2*inv; o[3] = o3*inv;
    }
}

// head_score[h] = std over p of mean over d of img_hidden[1]
__global__ __launch_bounds__(256) void k_head_score(const float* __restrict__ ao, float* __restrict__ score)
{
    int h = blockIdx.x, tid = threadIdx.x;
    const float* base = ao + (((long)HEADS_ + h)*S_MAIN + TEXT_)*64;
    float sA = 0.f, sB = 0.f;
    for (int p = tid; p < IMG_; p += 256) {
        const float* r = base + (long)p*64;
        float mm = 0.f;
        for (int d = 0; d < 64; d += 4) {
            float4 v = *(const float4*)(r + d);
            mm += v.x + v.y + v.z + v.w;
        }
        mm *= (1.f / 64.f);
        sA += mm; sB += mm*mm;
    }
    __shared__ float r1[256], r2[256];
    r1[tid] = sA; r2[tid] = sB; __syncthreads();
    for (int st = 128; st; st >>= 1) {
        if (tid < st) { r1[tid] += r1[tid+st]; r2[tid] += r2[tid+st]; }
        __syncthreads();
    }
    if (tid == 0) {
        float mean = r1[0] / IMG_, ms = r2[0] / IMG_;
        score[h] = sqrtf(fmaxf(ms - mean*mean, 0.f));
    }
}

__global__ void k_top4(const float* __restrict__ score, int* __restrict__ sel)
{
    if (threadIdx.x == 0 && blockIdx.x == 0) {
        int used = 0;
        for (int k = 0; k < 4; ++k) {
            float best = -INFINITY; int bi = 0;
            for (int h2 = 0; h2 < 16; ++h2) {
                if (used & (1 << h2)) continue;
                if (score[h2] > best) { best = score[h2]; bi = h2; }
            }
            used |= 1 << bi; sel[k] = bi;
        }
    }
}

// sim[h,t,fp] = iq1[h,fp,:] . ck1[h,t,:]; also per-(h,t,f) argmax over p
__global__ __launch_bounds__(512) void k_sim(
    const float* __restrict__ qh, const float* __restrict__ kh,
    float* __restrict__ sim, int* __restrict__ selvis)
{
    int blk = blockIdx.x;    // (h*8+t)*4+f
    int h = blk >> 5, t = (blk >> 2) & 7, f = blk & 3;
    int tid = threadIdx.x;
    __shared__ float ckv[64];
    if (tid < 64) ckv[tid] = kh[(((long)HEADS_ + h)*S2_ + S_MAIN + t)*64 + tid];
    __syncthreads();
    float val = -INFINITY; int idx = 0x7fffffff;
    if (tid < PATCHES_) {
        const float* qrow = qh + (((long)HEADS_ + h)*S2_ + TEXT_ + f*PATCHES_ + tid)*64;
        float acc = 0.f;
        for (int d = 0; d < 64; d += 4) {
            float4 qv = *(const float4*)(qrow + d);
            acc += qv.x*ckv[d] + qv.y*ckv[d+1] + qv.z*ckv[d+2] + qv.w*ckv[d+3];
        }
        sim[((long)h*NC_ + t)*IMG_ + f*PATCHES_ + tid] = acc;
        val = acc; idx = tid;
    }
    __shared__ float sv[512]; __shared__ int si[512];
    sv[tid] = val; si[tid] = idx; __syncthreads();
    for (int st = 256; st; st >>= 1) {
        if (tid < st) {
            float v2 = sv[tid+st]; int i2 = si[tid+st];
            if (v2 > sv[tid] || (v2 == sv[tid] && i2 < si[tid])) { sv[tid] = v2; si[tid] = i2; }
        }
        __syncthreads();
    }
    if (tid == 0) selvis[blk] = si[0];
}

__global__ __launch_bounds__(256) void k_cross(const float* __restrict__ sim, float* __restrict__ out)
{
    int i = blockIdx.x*256 + threadIdx.x;   // < 12288
    int c = i / IMG_, p = i % IMG_;
    float acc = 0.f;
    for (int h = 0; h < 16; ++h) acc += sim[((long)h*NC_ + c)*IMG_ + p];
    out[O_XMAP + i] = acc * (1.f / 16.f);
}

__global__ __launch_bounds__(256) void k_concept_maps(
    const float* __restrict__ ac, const float* __restrict__ ao, float* __restrict__ out)
{
    int i = blockIdx.x*256 + threadIdx.x;   // < 12288
    int c = i / IMG_, p = i % IMG_;
    float acc = 0.f;
    for (int h = 0; h < 16; ++h) {
        const float* a = ac + (((long)HEADS_ + h)*NC_ + c)*64;
        const float* g = ao + (((long)HEADS_ + h)*S_MAIN + TEXT_ + p)*64;
        for (int d = 0; d < 64; d += 4) {
            float4 av = *(const float4*)(a + d);
            float4 gv = *(const float4*)(g + d);
            acc += av.x*gv.x + av.y*gv.y + av.z*gv.z + av.w*gv.w;
        }
    }
    out[O_CMAP + i] = acc;
}

__global__ void k_imap_raw(const float* __restrict__ ao, const int* __restrict__ selvis,
                           float* __restrict__ imap)
{
    int blk = blockIdx.x;   // (h*8+t)*4+f
    int h = blk >> 5, t = (blk >> 2) & 7, f = blk & 3;
    int tid = threadIdx.x;  // 384
    __shared__ float sel[64];
    int pstar = selvis[blk];
    if (tid < 64) sel[tid] = ao[(((long)HEADS_ + h)*S_MAIN + TEXT_ + f*PATCHES_ + pstar)*64 + tid];
    __syncthreads();
    const float* g = ao + (((long)HEADS_ + h)*S_MAIN + TEXT_ + f*PATCHES_ + tid)*64;
    float acc = 0.f;
    for (int d = 0; d < 64; d += 4) {
        float4 gv = *(const float4*)(g + d);
        acc += gv.x*sel[d] + gv.y*sel[d+1] + gv.z*sel[d+2] + gv.w*sel[d+3];
    }
    imap[((long)h*NC_ + t)*IMG_ + f*PATCHES_ + tid] = acc;
}

__global__ __launch_bounds__(256) void k_imap_norm(float* __restrict__ imap)
{
    int i = blockIdx.x*256 + threadIdx.x;   // < 24576
    int h = i / IMG_, fp = i % IMG_;
    float v[8]; float mu = 0.f;
    #pragma unroll
    for (int t = 0; t < 8; ++t) { v[t] = imap[((long)h*NC_ + t)*IMG_ + fp]; mu += v[t]; }
    mu *= 0.125f;
    float var = 0.f;
    #pragma unroll
    for (int t = 0; t < 8; ++t) var += (v[t]-mu)*(v[t]-mu);
    float sd = sqrtf(var * (1.f / 7.f));
    float inv = 1.f / (sd + 1e-6f);
    #pragma unroll
    for (int t = 0; t < 8; ++t) imap[((long)h*NC_ + t)*IMG_ + fp] = (v[t]-mu)*inv;
}

__global__ __launch_bounds__(256) void k_imap_reduce(
    const float* __restrict__ imap, const int* __restrict__ sel, float* __restrict__ out)
{
    int i = blockIdx.x*256 + threadIdx.x;   // < 12288
    int t = i / IMG_, fp = i % IMG_;
    float sum = 0.f;
    for (int h = 0; h < 16; ++h) sum += imap[((long)h*NC_ + t)*IMG_ + fp];
    float ss = 0.f;
    for (int k = 0; k < 4; ++k) { int h = sel[k]; ss += imap[((long)h*NC_ + t)*IMG_ + fp]; }
    out[O_ISUM + i] = sum;
    out[O_SELI + i] = ss * 0.25f;
}

// merge (B,H,S,64) -> (B,S,1024); concept rows from ac
__global__ __launch_bounds__(256) void k_merge(
    const float* __restrict__ ao, const float* __restrict__ ac, float* __restrict__ xo)
{
    long i = (long)blockIdx.x*256 + threadIdx.x;   // < 3,624,960
    int col = (int)(i & 1023);
    long row = i >> 10;
    int b = (int)(row / S2_), s = (int)(row % S2_);
    int h = col >> 6, d = col & 63;
    float v;
    if (s < S_MAIN) v = ao[(((long)b*HEADS_ + h)*S_MAIN + s)*64 + d];
    else            v = ac[(((long)b*HEADS_ + h)*NC_ + (s - S_MAIN))*64 + d];
    xo[i] = v;
}

__global__ __launch_bounds__(256) void k_residual1(
    const float* __restrict__ pe, const float* __restrict__ ph, const float* __restrict__ pc,
    const float* __restrict__ proj, const float* __restrict__ s1, float* __restrict__ X)
{
    long i = (long)blockIdx.x*256 + threadIdx.x;
    int col = (int)(i & 1023);
    long row = i >> 10;
    int b = (int)(row / S2_), s = (int)(row % S2_);
    const float* sb = s1 + (long)b * 6144;
    float orig, gate;
    if (s < TEXT_)       { orig = pe[((long)b*TEXT_ + s)*DIM_ + col];            gate = sb[5120 + col]; }
    else if (s < S_MAIN) { orig = ph[((long)b*IMG_ + (s-TEXT_))*DIM_ + col];     gate = sb[2048 + col]; }
    else                 { orig = pc[((long)b*NC_ + (s-S_MAIN))*DIM_ + col];     gate = sb[5120 + col]; }
    X[i] = orig + gate * proj[i];
}

__global__ __launch_bounds__(256) void k_final(
    const float* __restrict__ X, const float* __restrict__ ffo,
    const float* __restrict__ s2, float* __restrict__ out)
{
    long i = (long)blockIdx.x*256 + threadIdx.x;
    int col = (int)(i & 1023);
    long row = i >> 10;
    int b = (int)(row / S2_), s = (int)(row % S2_);
    const float* sb = s2 + (long)b * 6144;
    float gate; float* o;
    if (s < TEXT_)       { gate = sb[5120 + col]; o = out + O_E + ((long)b*TEXT_ + s)*DIM_ + col; }
    else if (s < S_MAIN) { gate = sb[2048 + col]; o = out + O_H + ((long)b*IMG_ + (s-TEXT_))*DIM_ + col; }
    else                 { gate = sb[5120 + col]; o = out + O_C + ((long)b*NC_ + (s-S_MAIN))*DIM_ + col; }
    *o = X[i] + gate * ffo[i];
}

extern "C" void kernel_launch(void* const* d_in, const int* in_sizes, int n_in,
                              void* d_out, int out_size, void* d_ws, size_t ws_size,
                              hipStream_t stream)
{
    (void)in_sizes; (void)n_in; (void)out_size; (void)ws_size;
    const float* h_in = (const float*)d_in[0];
    const float* e_in = (const float*)d_in[1];
    const float* c_in = (const float*)d_in[2];
    const float* temb = (const float*)d_in[3];
    const float* rcos = (const float*)d_in[4];
    const float* rsin = (const float*)d_in[5];
    const float* n1w  = (const float*)d_in[6];
    const float* n1b  = (const float*)d_in[7];
    const float* ln1w = (const float*)d_in[8];
    const float* ln1b = (const float*)d_in[9];
    const float* n2w  = (const float*)d_in[10];
    const float* n2b  = (const float*)d_in[11];
    const float* ln2w = (const float*)d_in[12];
    const float* ln2b = (const float*)d_in[13];
    const float* wq   = (const float*)d_in[14];
    const float* wk   = (const float*)d_in[15];
    const float* wv   = (const float*)d_in[16];
    const float* nqw  = (const float*)d_in[17];
    const float* nqb  = (const float*)d_in[18];
    const float* nkw  = (const float*)d_in[19];
    const float* nkb  = (const float*)d_in[20];
    const float* wo   = (const float*)d_in[21];
    const float* bo   = (const float*)d_in[22];
    const float* fw1  = (const float*)d_in[23];
    const float* fb1  = (const float*)d_in[24];
    const float* fw2  = (const float*)d_in[25];
    const float* fb2  = (const float*)d_in[26];

    float* ws  = (float*)d_ws;
    float* out = (float*)d_out;
    float* s1   = ws + OFF_S1;
    float* s2   = ws + OFF_S2;
    float* score  = ws + OFF_MISC;
    int*   selh   = (int*)(ws + OFF_MISC + 16);
    int*   selvis = (int*)(ws + OFF_MISC + 32);
    float* sim  = ws + OFF_SIM;
    float* imap = ws + OFF_IMAP;
    float* ac   = ws + OFF_AC;
    float* X    = ws + OFF_X;
    float* proj = ws + OFF_PROJ;
    float* xn   = ws + OFF_XN;
    float* qh   = ws + OFF_Q;
    float* kh   = ws + OFF_K;
    float* vh   = ws + OFF_V;
    float* ao   = ws + OFF_AO;
    float* ffh  = ws + OFF_FFH;
    float* ffo  = proj;   // reuse after residual1 consumed proj

    // adaLN modulation vectors
    hipLaunchKernelGGL(k_silu_mod, dim3(96), dim3(256), 0, stream, temb, n1w, n1b, n2w, n2b, s1, s2);
    // norm1 + modulation -> xn (B,1770,1024): [e | h | c]
    hipLaunchKernelGGL(k_ln_mod, dim3(ROWS_), dim3(256), 0, stream,
        e_in, (long)TEXT_*DIM_, h_in, (long)IMG_*DIM_, c_in, (long)NC_*DIM_, s1, ln1w, ln1b, xn);
    // QKV projections, headed layout (B,H,1770,64)
    dim3 g1(16, 56);
    hipLaunchKernelGGL(k_gemm, g1, dim3(256), 0, stream, xn, wq, (const float*)nullptr, qh, ROWS_, DIM_, DIM_, 0, 1);
    hipLaunchKernelGGL(k_gemm, g1, dim3(256), 0, stream, xn, wk, (const float*)nullptr, kh, ROWS_, DIM_, DIM_, 0, 1);
    hipLaunchKernelGGL(k_gemm, g1, dim3(256), 0, stream, xn, wv, (const float*)nullptr, vh, ROWS_, DIM_, DIM_, 0, 1);
    // QK layernorm + RoPE in place
    hipLaunchKernelGGL(k_qk_ln_rope, dim3(14160, 2), dim3(256), 0, stream, qh, kh, nqw, nqb, nkw, nkb, rcos, rsin);
    // main attention: queries rows [0,1762), keys [0,1762)
    hipLaunchKernelGGL(k_flash, dim3(111, 16, 2), dim3(256), 0, stream,
        qh, kh, vh, ao, S_MAIN, 0, 0, S_MAIN, 0, 0);
    // concept attention: queries = cq rows [1762,1770), keys = [ck | ik]
    hipLaunchKernelGGL(k_flash, dim3(1, 16, 2), dim3(256), 0, stream,
        qh, kh, vh, ac, NC_, S_MAIN, S_MAIN, S2_, TEXT_, S_MAIN);
    // ---- maps (batch 1) ----
    hipLaunchKernelGGL(k_head_score, dim3(16), dim3(256), 0, stream, ao, score);
    hipLaunchKernelGGL(k_top4, dim3(1), dim3(64), 0, stream, score, selh);
    hipLaunchKernelGGL(k_sim, dim3(512), dim3(512), 0, stream, qh, kh, sim, selvis);
    hipLaunchKernelGGL(k_cross, dim3(48), dim3(256), 0, stream, sim, out);
    hipLaunchKernelGGL(k_concept_maps, dim3(48), dim3(256), 0, stream, ac, ao, out);
    hipLaunchKernelGGL(k_imap_raw, dim3(512), dim3(384), 0, stream, ao, selvis, imap);
    hipLaunchKernelGGL(k_imap_norm, dim3(96), dim3(256), 0, stream, imap);
    hipLaunchKernelGGL(k_imap_reduce, dim3(48), dim3(256), 0, stream, imap, selh, out);
    // ---- merge + output projection + residual ----
    hipLaunchKernelGGL(k_merge, dim3(14160), dim3(256), 0, stream, ao, ac, xn);  // xn reused as xo
    hipLaunchKernelGGL(k_gemm, g1, dim3(256), 0, stream, xn, wo, bo, proj, ROWS_, DIM_, DIM_, 0, 0);
    hipLaunchKernelGGL(k_residual1, dim3(14160), dim3(256), 0, stream, e_in, h_in, c_in, proj, s1, X);
    // ---- norm2 + FF ----
    hipLaunchKernelGGL(k_ln_mod, dim3(ROWS_), dim3(256), 0, stream,
        X, (long)S2_*DIM_, X + (long)TEXT_*DIM_, (long)S2_*DIM_, X + (long)S_MAIN*DIM_, (long)S2_*DIM_,
        s2, ln2w, ln2b, xn);
    hipLaunchKernelGGL(k_gemm, dim3(64, 56), dim3(256), 0, stream, xn, fw1, fb1, ffh, ROWS_, FF_, DIM_, 1, 0);
    hipLaunchKernelGGL(k_gemm, dim3(16, 56), dim3(256), 0, stream, ffh, fw2, fb2, ffo, ROWS_, DIM_, FF_, 0, 0);
    hipLaunchKernelGGL(k_final, dim3(14160), dim3(256), 0, stream, X, ffo, s2, out);
}

// Round 3
// 1946.708 us; speedup vs baseline: 2.9316x; 1.8386x over previous
//
#include <hip/hip_runtime.h>
#include <hip/hip_bf16.h>
#include <math.h>

#define B_ 2
#define HEADS_ 16
#define HD_ 64
#define DIM_ 1024
#define TEXT_ 226
#define NC_ 8
#define FRAMES_ 4
#define PATCHES_ 384
#define IMG_ 1536
#define S_MAIN 1762
#define S2_ 1770
#define TD_ 512
#define FF_ 4096
#define ROWS_ (B_*S2_)   // 3540

// ---- workspace offsets (floats) ----
#define OFF_S1   0L
#define OFF_S2   12288L
#define OFF_MISC 24576L
#define OFF_SIM  25600L
#define OFF_IMAP 222208L
#define OFF_AC   418816L
#define OFF_X    435200L
#define OFF_PROJ 4060160L
#define OFF_XN   7685120L
#define OFF_Q    11310080L
#define OFF_K    14935040L
#define OFF_V    18560000L
#define OFF_AO   22184960L
#define OFF_FFH  OFF_Q     // reuses q/k/v/ao region after maps done

// ---- output offsets (floats) ----
#define O_H    0L
#define O_E    3145728L
#define O_C    3608576L
#define O_SELI 3624960L
#define O_ISUM 3637248L
#define O_CMAP 3649536L
#define O_XMAP 3661824L

typedef __bf16 bf16x8_t __attribute__((ext_vector_type(8)));
typedef float  f32x4_t  __attribute__((ext_vector_type(4)));

__device__ __forceinline__ unsigned int pack2bf(float a, float b) {
    unsigned short ua = __builtin_bit_cast(unsigned short, (__bf16)a);
    unsigned short ub = __builtin_bit_cast(unsigned short, (__bf16)b);
    return (unsigned int)ua | ((unsigned int)ub << 16);
}
__device__ __forceinline__ int4 packi4(float4 a, float4 b) {
    int4 t;
    t.x = (int)pack2bf(a.x, a.y); t.y = (int)pack2bf(a.z, a.w);
    t.z = (int)pack2bf(b.x, b.y); t.w = (int)pack2bf(b.z, b.w);
    return t;
}
__device__ __forceinline__ bf16x8_t cvt_bf8(float4 a, float4 b) {
    return __builtin_bit_cast(bf16x8_t, packi4(a, b));
}

// s1/s2 = silu(temb) @ norm_w + norm_b, both mats
__global__ __launch_bounds__(256) void k_silu_mod(
    const float* __restrict__ temb, const float* __restrict__ w1, const float* __restrict__ b1,
    const float* __restrict__ w2, const float* __restrict__ b2,
    float* __restrict__ s1, float* __restrict__ s2)
{
    int idx = blockIdx.x * 256 + threadIdx.x;   // < 24576
    int which = idx / 12288;
    int r = idx % 12288;
    int b = r / 6144, n = r % 6144;
    const float* w = which ? w2 : w1;
    const float* bb = which ? b2 : b1;
    const float* t = temb + b * TD_;
    float acc = 0.f;
    for (int k = 0; k < TD_; ++k) {
        float tv = t[k];
        float sv = tv / (1.f + expf(-tv));
        acc += sv * w[(long)k * 6144 + n];
    }
    (which ? s2 : s1)[b * 6144 + n] = acc + bb[n];
}

// fused layernorm + adaLN modulation into combined (B,1770,1024) buffer
__global__ __launch_bounds__(256) void k_ln_mod(
    const float* pe, long bse, const float* ph, long bsh, const float* pc, long bsc,
    const float* __restrict__ smod, const float* __restrict__ lnw, const float* __restrict__ lnb,
    float* __restrict__ out)
{
    long row = blockIdx.x;
    int b = (int)(row / S2_), s = (int)(row % S2_);
    const float* src; int shiftB, scaleB;
    if (s < TEXT_)       { src = pe + (long)b*bse + (long)s*DIM_;          shiftB = 3072; scaleB = 4096; }
    else if (s < S_MAIN) { src = ph + (long)b*bsh + (long)(s-TEXT_)*DIM_;  shiftB = 0;    scaleB = 1024; }
    else                 { src = pc + (long)b*bsc + (long)(s-S_MAIN)*DIM_; shiftB = 3072; scaleB = 4096; }
    int tid = threadIdx.x;
    int col = tid * 4;
    float4 x = *(const float4*)(src + col);
    float lsum = x.x + x.y + x.z + x.w;
    float lsq  = x.x*x.x + x.y*x.y + x.z*x.z + x.w*x.w;
    __shared__ float r1[256], r2[256];
    r1[tid] = lsum; r2[tid] = lsq; __syncthreads();
    for (int st = 128; st; st >>= 1) {
        if (tid < st) { r1[tid] += r1[tid+st]; r2[tid] += r2[tid+st]; }
        __syncthreads();
    }
    float mu = r1[0] * (1.f / DIM_);
    float var = r2[0] * (1.f / DIM_) - mu * mu;
    float rstd = rsqrtf(var + 1e-5f);
    const float* sb = smod + (long)b * 6144;
    float xs[4] = {x.x, x.y, x.z, x.w};
    float res[4];
    #pragma unroll
    for (int i = 0; i < 4; ++i) {
        int cc = col + i;
        float yy = (xs[i] - mu) * rstd * lnw[cc] + lnb[cc];
        res[i] = yy * (1.f + sb[scaleB + cc]) + sb[shiftB + cc];
    }
    *(float4*)(out + row * DIM_ + col) = make_float4(res[0], res[1], res[2], res[3]);
}

// fp32 tiled GEMM: C = act(A@W + bias). A (M,K) rm, W (K,N) rm.
// headed=1: store C[(b,h,s,d)] layout with b=r/1770, s=r%1770, h=n>>6, d=n&63
__global__ __launch_bounds__(256) void k_gemm(
    const float* __restrict__ A, const float* __restrict__ W, const float* __restrict__ bias,
    float* __restrict__ C, int M, int N, int K, int act, int headed)
{
    __shared__ float As[16][68];
    __shared__ float Bs[16][68];
    int tid = threadIdx.x;
    int bm = blockIdx.y * 64, bn = blockIdx.x * 64;
    int tr = tid >> 4, tc = tid & 15;
    int ar = tid >> 2, akk = (tid & 3) * 4;
    int bkk = tid >> 4, bn4 = (tid & 15) * 4;
    float acc[4][4] = {{0.f}};
    int garow = bm + ar;
    const float* Aptr = A + (size_t)garow * K + akk;
    const float* Wptr = W + (size_t)bkk * N + bn + bn4;
    for (int k0 = 0; k0 < K; k0 += 16) {
        float4 av = make_float4(0.f, 0.f, 0.f, 0.f);
        if (garow < M) av = *(const float4*)(Aptr + k0);
        As[akk+0][ar] = av.x; As[akk+1][ar] = av.y; As[akk+2][ar] = av.z; As[akk+3][ar] = av.w;
        float4 bv = *(const float4*)(Wptr + (size_t)k0 * N);
        Bs[bkk][bn4+0] = bv.x; Bs[bkk][bn4+1] = bv.y; Bs[bkk][bn4+2] = bv.z; Bs[bkk][bn4+3] = bv.w;
        __syncthreads();
        #pragma unroll
        for (int kk = 0; kk < 16; ++kk) {
            float4 a = *(const float4*)&As[kk][tr*4];
            float4 bq = *(const float4*)&Bs[kk][tc*4];
            float avv[4] = {a.x, a.y, a.z, a.w};
            float bvv[4] = {bq.x, bq.y, bq.z, bq.w};
            #pragma unroll
            for (int i = 0; i < 4; ++i)
                #pragma unroll
                for (int j = 0; j < 4; ++j)
                    acc[i][j] += avv[i] * bvv[j];
        }
        __syncthreads();
    }
    #pragma unroll
    for (int i = 0; i < 4; ++i) {
        int r = bm + tr*4 + i;
        if (r >= M) continue;
        #pragma unroll
        for (int j = 0; j < 4; ++j) {
            int n = bn + tc*4 + j;
            float v = acc[i][j] + (bias ? bias[n] : 0.f);
            if (act == 1) {
                float x = v;
                v = 0.5f * x * (1.f + tanhf(0.7978845608028654f * (x + 0.044715f * x*x*x)));
            }
            if (headed) {
                int b = r / S2_, s = r % S2_;
                int hh = n >> 6, d = n & 63;
                C[(((size_t)b*HEADS_ + hh)*S2_ + s)*64 + d] = v;
            } else {
                C[(size_t)r * N + n] = v;
            }
        }
    }
}

// per-head layernorm (eps 1e-6) + RoPE for image rows, in place on q_h / k_h
__global__ __launch_bounds__(256) void k_qk_ln_rope(
    float* qh, float* kh, const float* __restrict__ nqw, const float* __restrict__ nqb,
    const float* __restrict__ nkw, const float* __restrict__ nkb,
    const float* __restrict__ rc, const float* __restrict__ rs)
{
    int which = blockIdx.y;
    int wid = threadIdx.x >> 6;
    int lane = threadIdx.x & 63;
    long row = (long)blockIdx.x * 4 + wid;   // < 56640 = 2*16*1770
    long s = row % S2_;
    float* base = (which ? kh : qh) + row * 64;
    const float* w  = which ? nkw : nqw;
    const float* bb = which ? nkb : nqb;
    float x = base[lane];
    float sum = x;
    for (int off = 1; off < 64; off <<= 1) sum += __shfl_xor(sum, off, 64);
    float mu = sum * (1.f / 64.f);
    float dx = x - mu;
    float v = dx * dx;
    for (int off = 1; off < 64; off <<= 1) v += __shfl_xor(v, off, 64);
    float rstd = rsqrtf(v * (1.f / 64.f) + 1e-6f);
    float y = dx * rstd * w[lane] + bb[lane];
    if (s >= TEXT_ && s < S_MAIN) {
        long p = s - TEXT_;
        float part = __shfl_xor(y, 1, 64);
        float rot = (lane & 1) ? part : -part;
        y = y * rc[p*64 + lane] + rot * rs[p*64 + lane];
    }
    base[lane] = y;
}

// MFMA flash attention. Block = 64 queries (4 waves x 16q). 64-key chunks, two key ranges.
// q/k/v fp32 in (B,H,1770,64); converted to bf16 on the fly. out fp32 (B,H,NQ,64).
// K tile: kt[key][d] bf16 stride 72. V tile TRANSPOSED: vt[d][key] bf16 stride 72.
// P round-trips through per-wave fp32 LDS buffer (C-layout -> A-layout).
__global__ __launch_bounds__(256) void k_flash(
    const float* __restrict__ qp, const float* __restrict__ kp, const float* __restrict__ vp,
    float* __restrict__ outp, int NQ, int q_off, int r0s, int r0e, int r1s, int r1e)
{
    int h = blockIdx.y, b = blockIdx.z;
    int qt = blockIdx.x * 64;
    int tid = threadIdx.x;
    int w = tid >> 6, lane = tid & 63;
    int lr = lane & 15, lh = lane >> 4;
    __shared__ __align__(16) unsigned short kt[64*72];
    __shared__ __align__(16) unsigned short vt[64*72];
    __shared__ __align__(16) float pbuf[4*16*68];
    float* pw = pbuf + w*16*68;
    const float* qbase = qp + (((size_t)b*HEADS_ + h)*S2_ + q_off)*64;
    const float* kbase = kp + ((size_t)b*HEADS_ + h)*S2_*64;
    const float* vbase = vp + ((size_t)b*HEADS_ + h)*S2_*64;
    // Q fragments: A[m=q=lr][k = c*32 + lh*8 + j]
    int qrow = qt + w*16 + lr; if (qrow >= NQ) qrow = NQ - 1;
    const float* qsrc = qbase + (size_t)qrow*64 + lh*8;
    bf16x8_t aq0 = cvt_bf8(*(const float4*)qsrc,        *(const float4*)(qsrc + 4));
    bf16x8_t aq1 = cvt_bf8(*(const float4*)(qsrc + 32), *(const float4*)(qsrc + 36));
    f32x4_t O[4];
    #pragma unroll
    for (int g = 0; g < 4; ++g) { O[g][0]=0.f; O[g][1]=0.f; O[g][2]=0.f; O[g][3]=0.f; }
    float m[4] = {-INFINITY,-INFINITY,-INFINITY,-INFINITY};
    float l[4] = {0.f,0.f,0.f,0.f};
    for (int rgi = 0; rgi < 2; ++rgi) {
        int rs = rgi ? r1s : r0s, re = rgi ? r1e : r0e;
        for (int j0 = rs; j0 < re; j0 += 64) {
            int cnt = min(64, re - j0);
            __syncthreads();
            // stage K (row-major bf16): thread covers (key = e>>3, dblock = e&7)
            #pragma unroll
            for (int i = 0; i < 2; ++i) {
                int e = tid + i*256;
                int key = e >> 3, db = e & 7;
                int krow = j0 + key; if (krow > re - 1) krow = re - 1;
                const float* s = kbase + (size_t)krow*64 + db*8;
                *(int4*)&kt[key*72 + db*8] = packi4(*(const float4*)s, *(const float4*)(s + 4));
            }
            // stage V transposed: thread covers (d = e&63, keyblock bb = e>>6)
            #pragma unroll
            for (int i = 0; i < 2; ++i) {
                int e = tid + i*256;
                int d = e & 63, bb = e >> 6;
                int vb = j0 + bb*8;
                float vv[8];
                #pragma unroll
                for (int j = 0; j < 8; ++j) {
                    int rr = vb + j; if (rr > re - 1) rr = re - 1;
                    vv[j] = vbase[(size_t)rr*64 + d];
                }
                int4 t;
                t.x = (int)pack2bf(vv[0], vv[1]); t.y = (int)pack2bf(vv[2], vv[3]);
                t.z = (int)pack2bf(vv[4], vv[5]); t.w = (int)pack2bf(vv[6], vv[7]);
                *(int4*)&vt[d*72 + bb*8] = t;
            }
            __syncthreads();
            // QK^T: S[g] = Q(16x64) . K^T -> D[m=q][n=key16g]
            f32x4_t S[4];
            #pragma unroll
            for (int g = 0; g < 4; ++g) {
                const unsigned short* kr = &kt[(16*g + lr)*72 + lh*8];
                bf16x8_t b0 = __builtin_bit_cast(bf16x8_t, *(const int4*)kr);
                bf16x8_t b1 = __builtin_bit_cast(bf16x8_t, *(const int4*)(kr + 32));
                f32x4_t z; z[0]=0.f; z[1]=0.f; z[2]=0.f; z[3]=0.f;
                z = __builtin_amdgcn_mfma_f32_16x16x32_bf16(aq0, b0, z, 0, 0, 0);
                z = __builtin_amdgcn_mfma_f32_16x16x32_bf16(aq1, b1, z, 0, 0, 0);
                S[g] = z;
            }
            // scale + mask + online softmax (rows = (lh*4+r), cols = lr)
            float p[4][4];
            float mx[4] = {-INFINITY,-INFINITY,-INFINITY,-INFINITY};
            #pragma unroll
            for (int g = 0; g < 4; ++g) {
                bool vld = (16*g + lr) < cnt;
                #pragma unroll
                for (int r = 0; r < 4; ++r) {
                    float sv = vld ? S[g][r] * 0.125f : -INFINITY;
                    p[g][r] = sv;
                    mx[r] = fmaxf(mx[r], sv);
                }
            }
            #pragma unroll
            for (int off = 1; off < 16; off <<= 1) {
                #pragma unroll
                for (int r = 0; r < 4; ++r) mx[r] = fmaxf(mx[r], __shfl_xor(mx[r], off, 64));
            }
            float al[4], ps[4];
            #pragma unroll
            for (int r = 0; r < 4; ++r) {
                float newm = fmaxf(m[r], mx[r]);
                al[r] = __expf(m[r] - newm);
                m[r] = newm;
            }
            #pragma unroll
            for (int g = 0; g < 4; ++g)
                #pragma unroll
                for (int r = 0; r < 4; ++r) p[g][r] = __expf(p[g][r] - m[r]);
            #pragma unroll
            for (int r = 0; r < 4; ++r) ps[r] = p[0][r] + p[1][r] + p[2][r] + p[3][r];
            #pragma unroll
            for (int off = 1; off < 16; off <<= 1) {
                #pragma unroll
                for (int r = 0; r < 4; ++r) ps[r] += __shfl_xor(ps[r], off, 64);
            }
            #pragma unroll
            for (int r = 0; r < 4; ++r) l[r] = l[r] * al[r] + ps[r];
            #pragma unroll
            for (int g = 0; g < 4; ++g)
                #pragma unroll
                for (int r = 0; r < 4; ++r) O[g][r] *= al[r];
            // P (C-layout) -> per-wave LDS
            #pragma unroll
            for (int g = 0; g < 4; ++g)
                #pragma unroll
                for (int r = 0; r < 4; ++r)
                    pw[(lh*4 + r)*68 + 16*g + lr] = p[g][r];
            // PV: A[m=q=lr][k=key], B[k=key][n=d] from transposed vt
            #pragma unroll
            for (int c = 0; c < 2; ++c) {
                const float* pr = &pw[lr*68 + c*32 + lh*8];
                bf16x8_t ap = cvt_bf8(*(const float4*)pr, *(const float4*)(pr + 4));
                #pragma unroll
                for (int g = 0; g < 4; ++g) {
                    bf16x8_t bv = __builtin_bit_cast(bf16x8_t,
                        *(const int4*)&vt[(16*g + lr)*72 + c*32 + lh*8]);
                    O[g] = __builtin_amdgcn_mfma_f32_16x16x32_bf16(ap, bv, O[g], 0, 0, 0);
                }
            }
        }
    }
    // store: O[g][r] at row q = qt + w*16 + lh*4 + r, col d = 16g + lr
    #pragma unroll
    for (int r = 0; r < 4; ++r) {
        float inv = 1.f / l[r];
        int gq = qt + w*16 + lh*4 + r;
        if (gq < NQ) {
            float* o = outp + (((size_t)b*HEADS_ + h)*NQ + gq)*64 + lr;
            #pragma unroll
            for (int g = 0; g < 4; ++g) o[16*g] = O[g][r] * inv;
        }
    }
}

// head_score[h] = std over p of mean over d of img_hidden[1]
__global__ __launch_bounds__(256) void k_head_score(const float* __restrict__ ao, float* __restrict__ score)
{
    int h = blockIdx.x, tid = threadIdx.x;
    const float* base = ao + (((long)HEADS_ + h)*S_MAIN + TEXT_)*64;
    float sA = 0.f, sB = 0.f;
    for (int p = tid; p < IMG_; p += 256) {
        const float* r = base + (long)p*64;
        float mm = 0.f;
        for (int d = 0; d < 64; d += 4) {
            float4 v = *(const float4*)(r + d);
            mm += v.x + v.y + v.z + v.w;
        }
        mm *= (1.f / 64.f);
        sA += mm; sB += mm*mm;
    }
    __shared__ float r1[256], r2[256];
    r1[tid] = sA; r2[tid] = sB; __syncthreads();
    for (int st = 128; st; st >>= 1) {
        if (tid < st) { r1[tid] += r1[tid+st]; r2[tid] += r2[tid+st]; }
        __syncthreads();
    }
    if (tid == 0) {
        float mean = r1[0] / IMG_, ms = r2[0] / IMG_;
        score[h] = sqrtf(fmaxf(ms - mean*mean, 0.f));
    }
}

__global__ void k_top4(const float* __restrict__ score, int* __restrict__ sel)
{
    if (threadIdx.x == 0 && blockIdx.x == 0) {
        int used = 0;
        for (int k = 0; k < 4; ++k) {
            float best = -INFINITY; int bi = 0;
            for (int h2 = 0; h2 < 16; ++h2) {
                if (used & (1 << h2)) continue;
                if (score[h2] > best) { best = score[h2]; bi = h2; }
            }
            used |= 1 << bi; sel[k] = bi;
        }
    }
}

// sim[h,t,fp] = iq1[h,fp,:] . ck1[h,t,:]; also per-(h,t,f) argmax over p
__global__ __launch_bounds__(512) void k_sim(
    const float* __restrict__ qh, const float* __restrict__ kh,
    float* __restrict__ sim, int* __restrict__ selvis)
{
    int blk = blockIdx.x;    // (h*8+t)*4+f
    int h = blk >> 5, t = (blk >> 2) & 7, f = blk & 3;
    int tid = threadIdx.x;
    __shared__ float ckv[64];
    if (tid < 64) ckv[tid] = kh[(((long)HEADS_ + h)*S2_ + S_MAIN + t)*64 + tid];
    __syncthreads();
    float val = -INFINITY; int idx = 0x7fffffff;
    if (tid < PATCHES_) {
        const float* qrow = qh + (((long)HEADS_ + h)*S2_ + TEXT_ + f*PATCHES_ + tid)*64;
        float acc = 0.f;
        for (int d = 0; d < 64; d += 4) {
            float4 qv = *(const float4*)(qrow + d);
            acc += qv.x*ckv[d] + qv.y*ckv[d+1] + qv.z*ckv[d+2] + qv.w*ckv[d+3];
        }
        sim[((long)h*NC_ + t)*IMG_ + f*PATCHES_ + tid] = acc;
        val = acc; idx = tid;
    }
    __shared__ float sv[512]; __shared__ int si[512];
    sv[tid] = val; si[tid] = idx; __syncthreads();
    for (int st = 256; st; st >>= 1) {
        if (tid < st) {
            float v2 = sv[tid+st]; int i2 = si[tid+st];
            if (v2 > sv[tid] || (v2 == sv[tid] && i2 < si[tid])) { sv[tid] = v2; si[tid] = i2; }
        }
        __syncthreads();
    }
    if (tid == 0) selvis[blk] = si[0];
}

__global__ __launch_bounds__(256) void k_cross(const float* __restrict__ sim, float* __restrict__ out)
{
    int i = blockIdx.x*256 + threadIdx.x;   // < 12288
    int c = i / IMG_, p = i % IMG_;
    float acc = 0.f;
    for (int h = 0; h < 16; ++h) acc += sim[((long)h*NC_ + c)*IMG_ + p];
    out[O_XMAP + i] = acc * (1.f / 16.f);
}

__global__ __launch_bounds__(256) void k_concept_maps(
    const float* __restrict__ ac, const float* __restrict__ ao, float* __restrict__ out)
{
    int i = blockIdx.x*256 + threadIdx.x;   // < 12288
    int c = i / IMG_, p = i % IMG_;
    float acc = 0.f;
    for (int h = 0; h < 16; ++h) {
        const float* a = ac + (((long)HEADS_ + h)*NC_ + c)*64;
        const float* g = ao + (((long)HEADS_ + h)*S_MAIN + TEXT_ + p)*64;
        for (int d = 0; d < 64; d += 4) {
            float4 av = *(const float4*)(a + d);
            float4 gv = *(const float4*)(g + d);
            acc += av.x*gv.x + av.y*gv.y + av.z*gv.z + av.w*gv.w;
        }
    }
    out[O_CMAP + i] = acc;
}

__global__ void k_imap_raw(const float* __restrict__ ao, const int* __restrict__ selvis,
                           float* __restrict__ imap)
{
    int blk = blockIdx.x;   // (h*8+t)*4+f
    int h = blk >> 5, t = (blk >> 2) & 7, f = blk & 3;
    int tid = threadIdx.x;  // 384
    __shared__ float sel[64];
    int pstar = selvis[blk];
    if (tid < 64) sel[tid] = ao[(((long)HEADS_ + h)*S_MAIN + TEXT_ + f*PATCHES_ + pstar)*64 + tid];
    __syncthreads();
    const float* g = ao + (((long)HEADS_ + h)*S_MAIN + TEXT_ + f*PATCHES_ + tid)*64;
    float acc = 0.f;
    for (int d = 0; d < 64; d += 4) {
        float4 gv = *(const float4*)(g + d);
        acc += gv.x*sel[d] + gv.y*sel[d+1] + gv.z*sel[d+2] + gv.w*sel[d+3];
    }
    imap[((long)h*NC_ + t)*IMG_ + f*PATCHES_ + tid] = acc;
}

__global__ __launch_bounds__(256) void k_imap_norm(float* __restrict__ imap)
{
    int i = blockIdx.x*256 + threadIdx.x;   // < 24576
    int h = i / IMG_, fp = i % IMG_;
    float v[8]; float mu = 0.f;
    #pragma unroll
    for (int t = 0; t < 8; ++t) { v[t] = imap[((long)h*NC_ + t)*IMG_ + fp]; mu += v[t]; }
    mu *= 0.125f;
    float var = 0.f;
    #pragma unroll
    for (int t = 0; t < 8; ++t) var += (v[t]-mu)*(v[t]-mu);
    float sd = sqrtf(var * (1.f / 7.f));
    float inv = 1.f / (sd + 1e-6f);
    #pragma unroll
    for (int t = 0; t < 8; ++t) imap[((long)h*NC_ + t)*IMG_ + fp] = (v[t]-mu)*inv;
}

__global__ __launch_bounds__(256) void k_imap_reduce(
    const float* __restrict__ imap, const int* __restrict__ sel, float* __restrict__ out)
{
    int i = blockIdx.x*256 + threadIdx.x;   // < 12288
    int t = i / IMG_, fp = i % IMG_;
    float sum = 0.f;
    for (int h = 0; h < 16; ++h) sum += imap[((long)h*NC_ + t)*IMG_ + fp];
    float ss = 0.f;
    for (int k = 0; k < 4; ++k) { int h = sel[k]; ss += imap[((long)h*NC_ + t)*IMG_ + fp]; }
    out[O_ISUM + i] = sum;
    out[O_SELI + i] = ss * 0.25f;
}

// merge (B,H,S,64) -> (B,S,1024); concept rows from ac
__global__ __launch_bounds__(256) void k_merge(
    const float* __restrict__ ao, const float* __restrict__ ac, float* __restrict__ xo)
{
    long i = (long)blockIdx.x*256 + threadIdx.x;   // < 3,624,960
    int col = (int)(i & 1023);
    long row = i >> 10;
    int b = (int)(row / S2_), s = (int)(row % S2_);
    int h = col >> 6, d = col & 63;
    float v;
    if (s < S_MAIN) v = ao[(((long)b*HEADS_ + h)*S_MAIN + s)*64 + d];
    else            v = ac[(((long)b*HEADS_ + h)*NC_ + (s - S_MAIN))*64 + d];
    xo[i] = v;
}

__global__ __launch_bounds__(256) void k_residual1(
    const float* __restrict__ pe, const float* __restrict__ ph, const float* __restrict__ pc,
    const float* __restrict__ proj, const float* __restrict__ s1, float* __restrict__ X)
{
    long i = (long)blockIdx.x*256 + threadIdx.x;
    int col = (int)(i & 1023);
    long row = i >> 10;
    int b = (int)(row / S2_), s = (int)(row % S2_);
    const float* sb = s1 + (long)b * 6144;
    float orig, gate;
    if (s < TEXT_)       { orig = pe[((long)b*TEXT_ + s)*DIM_ + col];            gate = sb[5120 + col]; }
    else if (s < S_MAIN) { orig = ph[((long)b*IMG_ + (s-TEXT_))*DIM_ + col];     gate = sb[2048 + col]; }
    else                 { orig = pc[((long)b*NC_ + (s-S_MAIN))*DIM_ + col];     gate = sb[5120 + col]; }
    X[i] = orig + gate * proj[i];
}

__global__ __launch_bounds__(256) void k_final(
    const float* __restrict__ X, const float* __restrict__ ffo,
    const float* __restrict__ s2, float* __restrict__ out)
{
    long i = (long)blockIdx.x*256 + threadIdx.x;
    int col = (int)(i & 1023);
    long row = i >> 10;
    int b = (int)(row / S2_), s = (int)(row % S2_);
    const float* sb = s2 + (long)b * 6144;
    float gate; float* o;
    if (s < TEXT_)       { gate = sb[5120 + col]; o = out + O_E + ((long)b*TEXT_ + s)*DIM_ + col; }
    else if (s < S_MAIN) { gate = sb[2048 + col]; o = out + O_H + ((long)b*IMG_ + (s-TEXT_))*DIM_ + col; }
    else                 { gate = sb[5120 + col]; o = out + O_C + ((long)b*NC_ + (s-S_MAIN))*DIM_ + col; }
    *o = X[i] + gate * ffo[i];
}

extern "C" void kernel_launch(void* const* d_in, const int* in_sizes, int n_in,
                              void* d_out, int out_size, void* d_ws, size_t ws_size,
                              hipStream_t stream)
{
    (void)in_sizes; (void)n_in; (void)out_size; (void)ws_size;
    const float* h_in = (const float*)d_in[0];
    const float* e_in = (const float*)d_in[1];
    const float* c_in = (const float*)d_in[2];
    const float* temb = (const float*)d_in[3];
    const float* rcos = (const float*)d_in[4];
    const float* rsin = (const float*)d_in[5];
    const float* n1w  = (const float*)d_in[6];
    const float* n1b  = (const float*)d_in[7];
    const float* ln1w = (const float*)d_in[8];
    const float* ln1b = (const float*)d_in[9];
    const float* n2w  = (const float*)d_in[10];
    const float* n2b  = (const float*)d_in[11];
    const float* ln2w = (const float*)d_in[12];
    const float* ln2b = (const float*)d_in[13];
    const float* wq   = (const float*)d_in[14];
    const float* wk   = (const float*)d_in[15];
    const float* wv   = (const float*)d_in[16];
    const float* nqw  = (const float*)d_in[17];
    const float* nqb  = (const float*)d_in[18];
    const float* nkw  = (const float*)d_in[19];
    const float* nkb  = (const float*)d_in[20];
    const float* wo   = (const float*)d_in[21];
    const float* bo   = (const float*)d_in[22];
    const float* fw1  = (const float*)d_in[23];
    const float* fb1  = (const float*)d_in[24];
    const float* fw2  = (const float*)d_in[25];
    const float* fb2  = (const float*)d_in[26];

    float* ws  = (float*)d_ws;
    float* out = (float*)d_out;
    float* s1   = ws + OFF_S1;
    float* s2   = ws + OFF_S2;
    float* score  = ws + OFF_MISC;
    int*   selh   = (int*)(ws + OFF_MISC + 16);
    int*   selvis = (int*)(ws + OFF_MISC + 32);
    float* sim  = ws + OFF_SIM;
    float* imap = ws + OFF_IMAP;
    float* ac   = ws + OFF_AC;
    float* X    = ws + OFF_X;
    float* proj = ws + OFF_PROJ;
    float* xn   = ws + OFF_XN;
    float* qh   = ws + OFF_Q;
    float* kh   = ws + OFF_K;
    float* vh   = ws + OFF_V;
    float* ao   = ws + OFF_AO;
    float* ffh  = ws + OFF_FFH;
    float* ffo  = proj;   // reuse after residual1 consumed proj

    // adaLN modulation vectors
    hipLaunchKernelGGL(k_silu_mod, dim3(96), dim3(256), 0, stream, temb, n1w, n1b, n2w, n2b, s1, s2);
    // norm1 + modulation -> xn (B,1770,1024): [e | h | c]
    hipLaunchKernelGGL(k_ln_mod, dim3(ROWS_), dim3(256), 0, stream,
        e_in, (long)TEXT_*DIM_, h_in, (long)IMG_*DIM_, c_in, (long)NC_*DIM_, s1, ln1w, ln1b, xn);
    // QKV projections, headed layout (B,H,1770,64)
    dim3 g1(16, 56);
    hipLaunchKernelGGL(k_gemm, g1, dim3(256), 0, stream, xn, wq, (const float*)nullptr, qh, ROWS_, DIM_, DIM_, 0, 1);
    hipLaunchKernelGGL(k_gemm, g1, dim3(256), 0, stream, xn, wk, (const float*)nullptr, kh, ROWS_, DIM_, DIM_, 0, 1);
    hipLaunchKernelGGL(k_gemm, g1, dim3(256), 0, stream, xn, wv, (const float*)nullptr, vh, ROWS_, DIM_, DIM_, 0, 1);
    // QK layernorm + RoPE in place
    hipLaunchKernelGGL(k_qk_ln_rope, dim3(14160, 2), dim3(256), 0, stream, qh, kh, nqw, nqb, nkw, nkb, rcos, rsin);
    // main attention: queries rows [0,1762), keys [0,1762)
    hipLaunchKernelGGL(k_flash, dim3(28, 16, 2), dim3(256), 0, stream,
        qh, kh, vh, ao, S_MAIN, 0, 0, S_MAIN, 0, 0);
    // concept attention: queries = cq rows [1762,1770), keys = [ck | ik]
    hipLaunchKernelGGL(k_flash, dim3(1, 16, 2), dim3(256), 0, stream,
        qh, kh, vh, ac, NC_, S_MAIN, S_MAIN, S2_, TEXT_, S_MAIN);
    // ---- maps (batch 1) ----
    hipLaunchKernelGGL(k_head_score, dim3(16), dim3(256), 0, stream, ao, score);
    hipLaunchKernelGGL(k_top4, dim3(1), dim3(64), 0, stream, score, selh);
    hipLaunchKernelGGL(k_sim, dim3(512), dim3(512), 0, stream, qh, kh, sim, selvis);
    hipLaunchKernelGGL(k_cross, dim3(48), dim3(256), 0, stream, sim, out);
    hipLaunchKernelGGL(k_concept_maps, dim3(48), dim3(256), 0, stream, ac, ao, out);
    hipLaunchKernelGGL(k_imap_raw, dim3(512), dim3(384), 0, stream, ao, selvis, imap);
    hipLaunchKernelGGL(k_imap_norm, dim3(96), dim3(256), 0, stream, imap);
    hipLaunchKernelGGL(k_imap_reduce, dim3(48), dim3(256), 0, stream, imap, selh, out);
    // ---- merge + output projection + residual ----
    hipLaunchKernelGGL(k_merge, dim3(14160), dim3(256), 0, stream, ao, ac, xn);  // xn reused as xo
    hipLaunchKernelGGL(k_gemm, g1, dim3(256), 0, stream, xn, wo, bo, proj, ROWS_, DIM_, DIM_, 0, 0);
    hipLaunchKernelGGL(k_residual1, dim3(14160), dim3(256), 0, stream, e_in, h_in, c_in, proj, s1, X);
    // ---- norm2 + FF ----
    hipLaunchKernelGGL(k_ln_mod, dim3(ROWS_), dim3(256), 0, stream,
        X, (long)S2_*DIM_, X + (long)TEXT_*DIM_, (long)S2_*DIM_, X + (long)S_MAIN*DIM_, (long)S2_*DIM_,
        s2, ln2w, ln2b, xn);
    hipLaunchKernelGGL(k_gemm, dim3(64, 56), dim3(256), 0, stream, xn, fw1, fb1, ffh, ROWS_, FF_, DIM_, 1, 0);
    hipLaunchKernelGGL(k_gemm, dim3(16, 56), dim3(256), 0, stream, ffh, fw2, fb2, ffo, ROWS_, DIM_, FF_, 0, 0);
    hipLaunchKernelGGL(k_final, dim3(14160), dim3(256), 0, stream, X, ffo, s2, out);
}

// Round 4
// 1001.267 us; speedup vs baseline: 5.6998x; 1.9442x over previous
//
#include <hip/hip_runtime.h>
#include <hip/hip_bf16.h>
#include <math.h>

#define B_ 2
#define HEADS_ 16
#define HD_ 64
#define DIM_ 1024
#define TEXT_ 226
#define NC_ 8
#define FRAMES_ 4
#define PATCHES_ 384
#define IMG_ 1536
#define S_MAIN 1762
#define S2_ 1770
#define TD_ 512
#define FF_ 4096
#define ROWS_ (B_*S2_)   // 3540

// ---- workspace offsets (float slots) ----
#define OFF_S1   0L
#define OFF_S2   12288L
#define OFF_MISC 24576L
#define OFF_SIM  25600L
#define OFF_IMAP 222208L
#define OFF_AC   418816L
#define OFF_X    435200L
#define OFF_PROJ 4060160L
#define OFF_XN   7685120L
#define OFF_Q    11310080L
#define OFF_K    14935040L
#define OFF_V    18560000L
#define OFF_AO   22184960L
#define OFF_XNB  25809920L   // bf16 activations, 1,812,480 slots -> ends 27,622,400
// overlays (all ranges verified non-conflicting by liveness):
//   wqkvT bf16(3072x1024) @ OFF_PROJ (dead before wo-GEMM writes proj)
//   woT   bf16(1024x1024) @ OFF_X    (dead before residual1 writes X)
//   fw1T  bf16(4096x1024) @ OFF_V    (vh dead after flash)
//   fw2T  bf16(1024x4096) @ OFF_AO   (ao dead after merge/maps)
//   ffh   bf16(3540x4096) @ OFF_Q    (qh/kh dead after maps; spans Q+K exactly)

// ---- output offsets (floats) ----
#define O_H    0L
#define O_E    3145728L
#define O_C    3608576L
#define O_SELI 3624960L
#define O_ISUM 3637248L
#define O_CMAP 3649536L
#define O_XMAP 3661824L

typedef __bf16 bf16x8_t __attribute__((ext_vector_type(8)));
typedef float  f32x4_t  __attribute__((ext_vector_type(4)));

__device__ __forceinline__ unsigned int pack2bf(float a, float b) {
    unsigned short ua = __builtin_bit_cast(unsigned short, (__bf16)a);
    unsigned short ub = __builtin_bit_cast(unsigned short, (__bf16)b);
    return (unsigned int)ua | ((unsigned int)ub << 16);
}
__device__ __forceinline__ int4 packi4(float4 a, float4 b) {
    int4 t;
    t.x = (int)pack2bf(a.x, a.y); t.y = (int)pack2bf(a.z, a.w);
    t.z = (int)pack2bf(b.x, b.y); t.w = (int)pack2bf(b.z, b.w);
    return t;
}
__device__ __forceinline__ bf16x8_t cvt_bf8(float4 a, float4 b) {
    return __builtin_bit_cast(bf16x8_t, packi4(a, b));
}

// s1/s2 = silu(temb) @ norm_w + norm_b, both mats
__global__ __launch_bounds__(256) void k_silu_mod(
    const float* __restrict__ temb, const float* __restrict__ w1, const float* __restrict__ b1,
    const float* __restrict__ w2, const float* __restrict__ b2,
    float* __restrict__ s1, float* __restrict__ s2)
{
    int idx = blockIdx.x * 256 + threadIdx.x;   // < 24576
    int which = idx / 12288;
    int r = idx % 12288;
    int b = r / 6144, n = r % 6144;
    const float* w = which ? w2 : w1;
    const float* bb = which ? b2 : b1;
    const float* t = temb + b * TD_;
    float acc = 0.f;
    for (int k = 0; k < TD_; ++k) {
        float tv = t[k];
        float sv = tv / (1.f + expf(-tv));
        acc += sv * w[(long)k * 6144 + n];
    }
    (which ? s2 : s1)[b * 6144 + n] = acc + bb[n];
}

// transpose + convert: src (K,N) fp32 -> dst (N,K) bf16
__global__ __launch_bounds__(256) void k_tcvt(
    const float* __restrict__ src, unsigned short* __restrict__ dst, int K, int N)
{
    __shared__ float t[32][33];
    int n0 = blockIdx.x * 32, k0 = blockIdx.y * 32;
    int tx = threadIdx.x & 31, ty = threadIdx.x >> 5;   // ty 0..7
    #pragma unroll
    for (int i = 0; i < 4; ++i)
        t[ty + 8*i][tx] = src[(size_t)(k0 + ty + 8*i) * N + n0 + tx];
    __syncthreads();
    #pragma unroll
    for (int i = 0; i < 4; ++i) {
        float v = t[tx][ty + 8*i];
        dst[(size_t)(n0 + ty + 8*i) * K + k0 + tx] =
            __builtin_bit_cast(unsigned short, (__bf16)v);
    }
}

// fused layernorm + adaLN modulation -> fp32 xn AND bf16 xnb
__global__ __launch_bounds__(256) void k_ln_mod(
    const float* pe, long bse, const float* ph, long bsh, const float* pc, long bsc,
    const float* __restrict__ smod, const float* __restrict__ lnw, const float* __restrict__ lnb,
    float* __restrict__ out, unsigned short* __restrict__ outb)
{
    long row = blockIdx.x;
    int b = (int)(row / S2_), s = (int)(row % S2_);
    const float* src; int shiftB, scaleB;
    if (s < TEXT_)       { src = pe + (long)b*bse + (long)s*DIM_;          shiftB = 3072; scaleB = 4096; }
    else if (s < S_MAIN) { src = ph + (long)b*bsh + (long)(s-TEXT_)*DIM_;  shiftB = 0;    scaleB = 1024; }
    else                 { src = pc + (long)b*bsc + (long)(s-S_MAIN)*DIM_; shiftB = 3072; scaleB = 4096; }
    int tid = threadIdx.x;
    int col = tid * 4;
    float4 x = *(const float4*)(src + col);
    float lsum = x.x + x.y + x.z + x.w;
    float lsq  = x.x*x.x + x.y*x.y + x.z*x.z + x.w*x.w;
    __shared__ float r1[256], r2[256];
    r1[tid] = lsum; r2[tid] = lsq; __syncthreads();
    for (int st = 128; st; st >>= 1) {
        if (tid < st) { r1[tid] += r1[tid+st]; r2[tid] += r2[tid+st]; }
        __syncthreads();
    }
    float mu = r1[0] * (1.f / DIM_);
    float var = r2[0] * (1.f / DIM_) - mu * mu;
    float rstd = rsqrtf(var + 1e-5f);
    const float* sb = smod + (long)b * 6144;
    float xs[4] = {x.x, x.y, x.z, x.w};
    float res[4];
    #pragma unroll
    for (int i = 0; i < 4; ++i) {
        int cc = col + i;
        float yy = (xs[i] - mu) * rstd * lnw[cc] + lnb[cc];
        res[i] = yy * (1.f + sb[scaleB + cc]) + sb[shiftB + cc];
    }
    *(float4*)(out + row * DIM_ + col) = make_float4(res[0], res[1], res[2], res[3]);
    uint2 pk;
    pk.x = pack2bf(res[0], res[1]); pk.y = pack2bf(res[2], res[3]);
    *(uint2*)(outb + row * DIM_ + col) = pk;
}

// bf16 MFMA GEMM: C = A(M,K)bf16 @ Wt(N,K)bf16^T. 128x128 tile, 4 waves 2x2.
// mode 0: headed fp32 scatter to q/k/v (N=3072). mode 1: fp32 +bias. mode 2: gelu->bf16.
__global__ __launch_bounds__(256, 3) void k_bgemm(
    const unsigned short* __restrict__ A, const unsigned short* __restrict__ Wt,
    const float* __restrict__ bias, float* __restrict__ out_f,
    unsigned short* __restrict__ out_b, int M, int N, int K, int mode,
    float* __restrict__ q_out, float* __restrict__ k_out, float* __restrict__ v_out)
{
    __shared__ unsigned short at[128*40];
    __shared__ unsigned short bt[128*40];
    int tid = threadIdx.x;
    int w = tid >> 6, lane = tid & 63;
    int lr = lane & 15, lh = lane >> 4;
    int wm = w >> 1, wn = w & 1;
    int m0 = blockIdx.y * 128, n0 = blockIdx.x * 128;

    f32x4_t acc[4][4];
    #pragma unroll
    for (int i = 0; i < 4; ++i)
        #pragma unroll
        for (int j = 0; j < 4; ++j) { acc[i][j][0]=0.f; acc[i][j][1]=0.f; acc[i][j][2]=0.f; acc[i][j][3]=0.f; }

    int srow = tid >> 1, shalf = tid & 1;
    int arow = m0 + srow; if (arow >= M) arow = M - 1;
    const unsigned short* aptr = A + (size_t)arow * K + shalf * 16;
    const unsigned short* bptr = Wt + (size_t)(n0 + srow) * K + shalf * 16;
    unsigned short* asd = &at[srow * 40 + shalf * 16];
    unsigned short* bsd = &bt[srow * 40 + shalf * 16];

    for (int k0 = 0; k0 < K; k0 += 32) {
        int4 a0 = *(const int4*)(aptr + k0);
        int4 a1 = *(const int4*)(aptr + k0 + 8);
        int4 b0 = *(const int4*)(bptr + k0);
        int4 b1 = *(const int4*)(bptr + k0 + 8);
        __syncthreads();
        *(int4*)asd = a0; *(int4*)(asd + 8) = a1;
        *(int4*)bsd = b0; *(int4*)(bsd + 8) = b1;
        __syncthreads();
        int4 af[4], bf[4];
        #pragma unroll
        for (int tm = 0; tm < 4; ++tm)
            af[tm] = *(const int4*)&at[(wm*64 + tm*16 + lr)*40 + lh*8];
        #pragma unroll
        for (int tn = 0; tn < 4; ++tn)
            bf[tn] = *(const int4*)&bt[(wn*64 + tn*16 + lr)*40 + lh*8];
        #pragma unroll
        for (int tm = 0; tm < 4; ++tm) {
            bf16x8_t av = __builtin_bit_cast(bf16x8_t, af[tm]);
            #pragma unroll
            for (int tn = 0; tn < 4; ++tn)
                acc[tm][tn] = __builtin_amdgcn_mfma_f32_16x16x32_bf16(
                    av, __builtin_bit_cast(bf16x8_t, bf[tn]), acc[tm][tn], 0, 0, 0);
        }
    }
    // epilogue: row = lh*4+r, col = lr within each 16x16 tile
    #pragma unroll
    for (int tm = 0; tm < 4; ++tm) {
        #pragma unroll
        for (int r = 0; r < 4; ++r) {
            int m = m0 + wm*64 + tm*16 + lh*4 + r;
            if (m >= M) continue;
            int b = m / S2_, s = m % S2_;
            #pragma unroll
            for (int tn = 0; tn < 4; ++tn) {
                int n = n0 + wn*64 + tn*16 + lr;
                float v = acc[tm][tn][r];
                if (mode == 0) {
                    int which = n >> 10, c = n & 1023;
                    int hh = c >> 6, d = c & 63;
                    float* dstp = (which == 0) ? q_out : (which == 1) ? k_out : v_out;
                    dstp[(((size_t)b*HEADS_ + hh)*S2_ + s)*64 + d] = v;
                } else if (mode == 1) {
                    out_f[(size_t)m * N + n] = v + bias[n];
                } else {
                    float x = v + bias[n];
                    float g = 0.5f * x * (1.f + tanhf(0.7978845608028654f * (x + 0.044715f*x*x*x)));
                    out_b[(size_t)m * N + n] = __builtin_bit_cast(unsigned short, (__bf16)g);
                }
            }
        }
    }
}

// fp32 tiled GEMM (fixup for argmax-feeding slices). A (M,K) rm (already row-offset),
// W (K,N) rm. headed store uses global row r+row_off.
__global__ __launch_bounds__(256) void k_gemm(
    const float* __restrict__ A, const float* __restrict__ W, const float* __restrict__ bias,
    float* __restrict__ C, int M, int N, int K, int headed, int row_off)
{
    __shared__ float As[16][68];
    __shared__ float Bs[16][68];
    int tid = threadIdx.x;
    int bm = blockIdx.y * 64, bn = blockIdx.x * 64;
    int tr = tid >> 4, tc = tid & 15;
    int ar = tid >> 2, akk = (tid & 3) * 4;
    int bkk = tid >> 4, bn4 = (tid & 15) * 4;
    float acc[4][4] = {{0.f}};
    int garow = bm + ar;
    const float* Aptr = A + (size_t)garow * K + akk;
    const float* Wptr = W + (size_t)bkk * N + bn + bn4;
    for (int k0 = 0; k0 < K; k0 += 16) {
        float4 av = make_float4(0.f, 0.f, 0.f, 0.f);
        if (garow < M) av = *(const float4*)(Aptr + k0);
        As[akk+0][ar] = av.x; As[akk+1][ar] = av.y; As[akk+2][ar] = av.z; As[akk+3][ar] = av.w;
        float4 bv = *(const float4*)(Wptr + (size_t)k0 * N);
        Bs[bkk][bn4+0] = bv.x; Bs[bkk][bn4+1] = bv.y; Bs[bkk][bn4+2] = bv.z; Bs[bkk][bn4+3] = bv.w;
        __syncthreads();
        #pragma unroll
        for (int kk = 0; kk < 16; ++kk) {
            float4 a = *(const float4*)&As[kk][tr*4];
            float4 bq = *(const float4*)&Bs[kk][tc*4];
            float avv[4] = {a.x, a.y, a.z, a.w};
            float bvv[4] = {bq.x, bq.y, bq.z, bq.w};
            #pragma unroll
            for (int i = 0; i < 4; ++i)
                #pragma unroll
                for (int j = 0; j < 4; ++j)
                    acc[i][j] += avv[i] * bvv[j];
        }
        __syncthreads();
    }
    #pragma unroll
    for (int i = 0; i < 4; ++i) {
        int r = bm + tr*4 + i;
        if (r >= M) continue;
        #pragma unroll
        for (int j = 0; j < 4; ++j) {
            int n = bn + tc*4 + j;
            float v = acc[i][j] + (bias ? bias[n] : 0.f);
            if (headed) {
                int rg = r + row_off;
                int b = rg / S2_, s = rg % S2_;
                int hh = n >> 6, d = n & 63;
                C[(((size_t)b*HEADS_ + hh)*S2_ + s)*64 + d] = v;
            } else {
                C[(size_t)(r + row_off) * N + n] = v;
            }
        }
    }
}

// per-head layernorm (eps 1e-6) + RoPE for image rows, in place on q_h / k_h
__global__ __launch_bounds__(256) void k_qk_ln_rope(
    float* qh, float* kh, const float* __restrict__ nqw, const float* __restrict__ nqb,
    const float* __restrict__ nkw, const float* __restrict__ nkb,
    const float* __restrict__ rc, const float* __restrict__ rs)
{
    int which = blockIdx.y;
    int wid = threadIdx.x >> 6;
    int lane = threadIdx.x & 63;
    long row = (long)blockIdx.x * 4 + wid;   // < 56640 = 2*16*1770
    long s = row % S2_;
    float* base = (which ? kh : qh) + row * 64;
    const float* w  = which ? nkw : nqw;
    const float* bb = which ? nkb : nqb;
    float x = base[lane];
    float sum = x;
    for (int off = 1; off < 64; off <<= 1) sum += __shfl_xor(sum, off, 64);
    float mu = sum * (1.f / 64.f);
    float dx = x - mu;
    float v = dx * dx;
    for (int off = 1; off < 64; off <<= 1) v += __shfl_xor(v, off, 64);
    float rstd = rsqrtf(v * (1.f / 64.f) + 1e-6f);
    float y = dx * rstd * w[lane] + bb[lane];
    if (s >= TEXT_ && s < S_MAIN) {
        long p = s - TEXT_;
        float part = __shfl_xor(y, 1, 64);
        float rot = (lane & 1) ? part : -part;
        y = y * rc[p*64 + lane] + rot * rs[p*64 + lane];
    }
    base[lane] = y;
}

// MFMA flash attention (unchanged from R2)
__global__ __launch_bounds__(256) void k_flash(
    const float* __restrict__ qp, const float* __restrict__ kp, const float* __restrict__ vp,
    float* __restrict__ outp, int NQ, int q_off, int r0s, int r0e, int r1s, int r1e)
{
    int h = blockIdx.y, b = blockIdx.z;
    int qt = blockIdx.x * 64;
    int tid = threadIdx.x;
    int w = tid >> 6, lane = tid & 63;
    int lr = lane & 15, lh = lane >> 4;
    __shared__ __align__(16) unsigned short kt[64*72];
    __shared__ __align__(16) unsigned short vt[64*72];
    __shared__ __align__(16) float pbuf[4*16*68];
    float* pw = pbuf + w*16*68;
    const float* qbase = qp + (((size_t)b*HEADS_ + h)*S2_ + q_off)*64;
    const float* kbase = kp + ((size_t)b*HEADS_ + h)*S2_*64;
    const float* vbase = vp + ((size_t)b*HEADS_ + h)*S2_*64;
    int qrow = qt + w*16 + lr; if (qrow >= NQ) qrow = NQ - 1;
    const float* qsrc = qbase + (size_t)qrow*64 + lh*8;
    bf16x8_t aq0 = cvt_bf8(*(const float4*)qsrc,        *(const float4*)(qsrc + 4));
    bf16x8_t aq1 = cvt_bf8(*(const float4*)(qsrc + 32), *(const float4*)(qsrc + 36));
    f32x4_t O[4];
    #pragma unroll
    for (int g = 0; g < 4; ++g) { O[g][0]=0.f; O[g][1]=0.f; O[g][2]=0.f; O[g][3]=0.f; }
    float m[4] = {-INFINITY,-INFINITY,-INFINITY,-INFINITY};
    float l[4] = {0.f,0.f,0.f,0.f};
    for (int rgi = 0; rgi < 2; ++rgi) {
        int rs = rgi ? r1s : r0s, re = rgi ? r1e : r0e;
        for (int j0 = rs; j0 < re; j0 += 64) {
            int cnt = min(64, re - j0);
            __syncthreads();
            #pragma unroll
            for (int i = 0; i < 2; ++i) {
                int e = tid + i*256;
                int key = e >> 3, db = e & 7;
                int krow = j0 + key; if (krow > re - 1) krow = re - 1;
                const float* s = kbase + (size_t)krow*64 + db*8;
                *(int4*)&kt[key*72 + db*8] = packi4(*(const float4*)s, *(const float4*)(s + 4));
            }
            #pragma unroll
            for (int i = 0; i < 2; ++i) {
                int e = tid + i*256;
                int d = e & 63, bb = e >> 6;
                int vb = j0 + bb*8;
                float vv[8];
                #pragma unroll
                for (int j = 0; j < 8; ++j) {
                    int rr = vb + j; if (rr > re - 1) rr = re - 1;
                    vv[j] = vbase[(size_t)rr*64 + d];
                }
                int4 t;
                t.x = (int)pack2bf(vv[0], vv[1]); t.y = (int)pack2bf(vv[2], vv[3]);
                t.z = (int)pack2bf(vv[4], vv[5]); t.w = (int)pack2bf(vv[6], vv[7]);
                *(int4*)&vt[d*72 + bb*8] = t;
            }
            __syncthreads();
            f32x4_t S[4];
            #pragma unroll
            for (int g = 0; g < 4; ++g) {
                const unsigned short* kr = &kt[(16*g + lr)*72 + lh*8];
                bf16x8_t b0 = __builtin_bit_cast(bf16x8_t, *(const int4*)kr);
                bf16x8_t b1 = __builtin_bit_cast(bf16x8_t, *(const int4*)(kr + 32));
                f32x4_t z; z[0]=0.f; z[1]=0.f; z[2]=0.f; z[3]=0.f;
                z = __builtin_amdgcn_mfma_f32_16x16x32_bf16(aq0, b0, z, 0, 0, 0);
                z = __builtin_amdgcn_mfma_f32_16x16x32_bf16(aq1, b1, z, 0, 0, 0);
                S[g] = z;
            }
            float p[4][4];
            float mx[4] = {-INFINITY,-INFINITY,-INFINITY,-INFINITY};
            #pragma unroll
            for (int g = 0; g < 4; ++g) {
                bool vld = (16*g + lr) < cnt;
                #pragma unroll
                for (int r = 0; r < 4; ++r) {
                    float sv = vld ? S[g][r] * 0.125f : -INFINITY;
                    p[g][r] = sv;
                    mx[r] = fmaxf(mx[r], sv);
                }
            }
            #pragma unroll
            for (int off = 1; off < 16; off <<= 1) {
                #pragma unroll
                for (int r = 0; r < 4; ++r) mx[r] = fmaxf(mx[r], __shfl_xor(mx[r], off, 64));
            }
            float al[4], ps[4];
            #pragma unroll
            for (int r = 0; r < 4; ++r) {
                float newm = fmaxf(m[r], mx[r]);
                al[r] = __expf(m[r] - newm);
                m[r] = newm;
            }
            #pragma unroll
            for (int g = 0; g < 4; ++g)
                #pragma unroll
                for (int r = 0; r < 4; ++r) p[g][r] = __expf(p[g][r] - m[r]);
            #pragma unroll
            for (int r = 0; r < 4; ++r) ps[r] = p[0][r] + p[1][r] + p[2][r] + p[3][r];
            #pragma unroll
            for (int off = 1; off < 16; off <<= 1) {
                #pragma unroll
                for (int r = 0; r < 4; ++r) ps[r] += __shfl_xor(ps[r], off, 64);
            }
            #pragma unroll
            for (int r = 0; r < 4; ++r) l[r] = l[r] * al[r] + ps[r];
            #pragma unroll
            for (int g = 0; g < 4; ++g)
                #pragma unroll
                for (int r = 0; r < 4; ++r) O[g][r] *= al[r];
            #pragma unroll
            for (int g = 0; g < 4; ++g)
                #pragma unroll
                for (int r = 0; r < 4; ++r)
                    pw[(lh*4 + r)*68 + 16*g + lr] = p[g][r];
            #pragma unroll
            for (int c = 0; c < 2; ++c) {
                const float* pr = &pw[lr*68 + c*32 + lh*8];
                bf16x8_t ap = cvt_bf8(*(const float4*)pr, *(const float4*)(pr + 4));
                #pragma unroll
                for (int g = 0; g < 4; ++g) {
                    bf16x8_t bv = __builtin_bit_cast(bf16x8_t,
                        *(const int4*)&vt[(16*g + lr)*72 + c*32 + lh*8]);
                    O[g] = __builtin_amdgcn_mfma_f32_16x16x32_bf16(ap, bv, O[g], 0, 0, 0);
                }
            }
        }
    }
    #pragma unroll
    for (int r = 0; r < 4; ++r) {
        float inv = 1.f / l[r];
        int gq = qt + w*16 + lh*4 + r;
        if (gq < NQ) {
            float* o = outp + (((size_t)b*HEADS_ + h)*NQ + gq)*64 + lr;
            #pragma unroll
            for (int g = 0; g < 4; ++g) o[16*g] = O[g][r] * inv;
        }
    }
}

__global__ __launch_bounds__(256) void k_head_score(const float* __restrict__ ao, float* __restrict__ score)
{
    int h = blockIdx.x, tid = threadIdx.x;
    const float* base = ao + (((long)HEADS_ + h)*S_MAIN + TEXT_)*64;
    float sA = 0.f, sB = 0.f;
    for (int p = tid; p < IMG_; p += 256) {
        const float* r = base + (long)p*64;
        float mm = 0.f;
        for (int d = 0; d < 64; d += 4) {
            float4 v = *(const float4*)(r + d);
            mm += v.x + v.y + v.z + v.w;
        }
        mm *= (1.f / 64.f);
        sA += mm; sB += mm*mm;
    }
    __shared__ float r1[256], r2[256];
    r1[tid] = sA; r2[tid] = sB; __syncthreads();
    for (int st = 128; st; st >>= 1) {
        if (tid < st) { r1[tid] += r1[tid+st]; r2[tid] += r2[tid+st]; }
        __syncthreads();
    }
    if (tid == 0) {
        float mean = r1[0] / IMG_, ms = r2[0] / IMG_;
        score[h] = sqrtf(fmaxf(ms - mean*mean, 0.f));
    }
}

__global__ void k_top4(const float* __restrict__ score, int* __restrict__ sel)
{
    if (threadIdx.x == 0 && blockIdx.x == 0) {
        int used = 0;
        for (int k = 0; k < 4; ++k) {
            float best = -INFINITY; int bi = 0;
            for (int h2 = 0; h2 < 16; ++h2) {
                if (used & (1 << h2)) continue;
                if (score[h2] > best) { best = score[h2]; bi = h2; }
            }
            used |= 1 << bi; sel[k] = bi;
        }
    }
}

__global__ __launch_bounds__(512) void k_sim(
    const float* __restrict__ qh, const float* __restrict__ kh,
    float* __restrict__ sim, int* __restrict__ selvis)
{
    int blk = blockIdx.x;    // (h*8+t)*4+f
    int h = blk >> 5, t = (blk >> 2) & 7, f = blk & 3;
    int tid = threadIdx.x;
    __shared__ float ckv[64];
    if (tid < 64) ckv[tid] = kh[(((long)HEADS_ + h)*S2_ + S_MAIN + t)*64 + tid];
    __syncthreads();
    float val = -INFINITY; int idx = 0x7fffffff;
    if (tid < PATCHES_) {
        const float* qrow = qh + (((long)HEADS_ + h)*S2_ + TEXT_ + f*PATCHES_ + tid)*64;
        float acc = 0.f;
        for (int d = 0; d < 64; d += 4) {
            float4 qv = *(const float4*)(qrow + d);
            acc += qv.x*ckv[d] + qv.y*ckv[d+1] + qv.z*ckv[d+2] + qv.w*ckv[d+3];
        }
        sim[((long)h*NC_ + t)*IMG_ + f*PATCHES_ + tid] = acc;
        val = acc; idx = tid;
    }
    __shared__ float sv[512]; __shared__ int si[512];
    sv[tid] = val; si[tid] = idx; __syncthreads();
    for (int st = 256; st; st >>= 1) {
        if (tid < st) {
            float v2 = sv[tid+st]; int i2 = si[tid+st];
            if (v2 > sv[tid] || (v2 == sv[tid] && i2 < si[tid])) { sv[tid] = v2; si[tid] = i2; }
        }
        __syncthreads();
    }
    if (tid == 0) selvis[blk] = si[0];
}

__global__ __launch_bounds__(256) void k_cross(const float* __restrict__ sim, float* __restrict__ out)
{
    int i = blockIdx.x*256 + threadIdx.x;   // < 12288
    int c = i / IMG_, p = i % IMG_;
    float acc = 0.f;
    for (int h = 0; h < 16; ++h) acc += sim[((long)h*NC_ + c)*IMG_ + p];
    out[O_XMAP + i] = acc * (1.f / 16.f);
}

__global__ __launch_bounds__(256) void k_concept_maps(
    const float* __restrict__ ac, const float* __restrict__ ao, float* __restrict__ out)
{
    int i = blockIdx.x*256 + threadIdx.x;   // < 12288
    int c = i / IMG_, p = i % IMG_;
    float acc = 0.f;
    for (int h = 0; h < 16; ++h) {
        const float* a = ac + (((long)HEADS_ + h)*NC_ + c)*64;
        const float* g = ao + (((long)HEADS_ + h)*S_MAIN + TEXT_ + p)*64;
        for (int d = 0; d < 64; d += 4) {
            float4 av = *(const float4*)(a + d);
            float4 gv = *(const float4*)(g + d);
            acc += av.x*gv.x + av.y*gv.y + av.z*gv.z + av.w*gv.w;
        }
    }
    out[O_CMAP + i] = acc;
}

__global__ void k_imap_raw(const float* __restrict__ ao, const int* __restrict__ selvis,
                           float* __restrict__ imap)
{
    int blk = blockIdx.x;   // (h*8+t)*4+f
    int h = blk >> 5, t = (blk >> 2) & 7, f = blk & 3;
    int tid = threadIdx.x;  // 384
    __shared__ float sel[64];
    int pstar = selvis[blk];
    if (tid < 64) sel[tid] = ao[(((long)HEADS_ + h)*S_MAIN + TEXT_ + f*PATCHES_ + pstar)*64 + tid];
    __syncthreads();
    const float* g = ao + (((long)HEADS_ + h)*S_MAIN + TEXT_ + f*PATCHES_ + tid)*64;
    float acc = 0.f;
    for (int d = 0; d < 64; d += 4) {
        float4 gv = *(const float4*)(g + d);
        acc += gv.x*sel[d] + gv.y*sel[d+1] + gv.z*sel[d+2] + gv.w*sel[d+3];
    }
    imap[((long)h*NC_ + t)*IMG_ + f*PATCHES_ + tid] = acc;
}

__global__ __launch_bounds__(256) void k_imap_norm(float* __restrict__ imap)
{
    int i = blockIdx.x*256 + threadIdx.x;   // < 24576
    int h = i / IMG_, fp = i % IMG_;
    float v[8]; float mu = 0.f;
    #pragma unroll
    for (int t = 0; t < 8; ++t) { v[t] = imap[((long)h*NC_ + t)*IMG_ + fp]; mu += v[t]; }
    mu *= 0.125f;
    float var = 0.f;
    #pragma unroll
    for (int t = 0; t < 8; ++t) var += (v[t]-mu)*(v[t]-mu);
    float sd = sqrtf(var * (1.f / 7.f));
    float inv = 1.f / (sd + 1e-6f);
    #pragma unroll
    for (int t = 0; t < 8; ++t) imap[((long)h*NC_ + t)*IMG_ + fp] = (v[t]-mu)*inv;
}

__global__ __launch_bounds__(256) void k_imap_reduce(
    const float* __restrict__ imap, const int* __restrict__ sel, float* __restrict__ out)
{
    int i = blockIdx.x*256 + threadIdx.x;   // < 12288
    int t = i / IMG_, fp = i % IMG_;
    float sum = 0.f;
    for (int h = 0; h < 16; ++h) sum += imap[((long)h*NC_ + t)*IMG_ + fp];
    float ss = 0.f;
    for (int k = 0; k < 4; ++k) { int h = sel[k]; ss += imap[((long)h*NC_ + t)*IMG_ + fp]; }
    out[O_ISUM + i] = sum;
    out[O_SELI + i] = ss * 0.25f;
}

// merge (B,H,S,64) -> (B,S,1024) bf16; concept rows from ac
__global__ __launch_bounds__(256) void k_merge(
    const float* __restrict__ ao, const float* __restrict__ ac, unsigned short* __restrict__ xo)
{
    long i = (long)blockIdx.x*256 + threadIdx.x;   // < 3,624,960
    int col = (int)(i & 1023);
    long row = i >> 10;
    int b = (int)(row / S2_), s = (int)(row % S2_);
    int h = col >> 6, d = col & 63;
    float v;
    if (s < S_MAIN) v = ao[(((long)b*HEADS_ + h)*S_MAIN + s)*64 + d];
    else            v = ac[(((long)b*HEADS_ + h)*NC_ + (s - S_MAIN))*64 + d];
    xo[i] = __builtin_bit_cast(unsigned short, (__bf16)v);
}

__global__ __launch_bounds__(256) void k_residual1(
    const float* __restrict__ pe, const float* __restrict__ ph, const float* __restrict__ pc,
    const float* __restrict__ proj, const float* __restrict__ s1, float* __restrict__ X)
{
    long i = (long)blockIdx.x*256 + threadIdx.x;
    int col = (int)(i & 1023);
    long row = i >> 10;
    int b = (int)(row / S2_), s = (int)(row % S2_);
    const float* sb = s1 + (long)b * 6144;
    float orig, gate;
    if (s < TEXT_)       { orig = pe[((long)b*TEXT_ + s)*DIM_ + col];            gate = sb[5120 + col]; }
    else if (s < S_MAIN) { orig = ph[((long)b*IMG_ + (s-TEXT_))*DIM_ + col];     gate = sb[2048 + col]; }
    else                 { orig = pc[((long)b*NC_ + (s-S_MAIN))*DIM_ + col];     gate = sb[5120 + col]; }
    X[i] = orig + gate * proj[i];
}

__global__ __launch_bounds__(256) void k_final(
    const float* __restrict__ X, const float* __restrict__ ffo,
    const float* __restrict__ s2, float* __restrict__ out)
{
    long i = (long)blockIdx.x*256 + threadIdx.x;
    int col = (int)(i & 1023);
    long row = i >> 10;
    int b = (int)(row / S2_), s = (int)(row % S2_);
    const float* sb = s2 + (long)b * 6144;
    float gate; float* o;
    if (s < TEXT_)       { gate = sb[5120 + col]; o = out + O_E + ((long)b*TEXT_ + s)*DIM_ + col; }
    else if (s < S_MAIN) { gate = sb[2048 + col]; o = out + O_H + ((long)b*IMG_ + (s-TEXT_))*DIM_ + col; }
    else                 { gate = sb[5120 + col]; o = out + O_C + ((long)b*NC_ + (s-S_MAIN))*DIM_ + col; }
    *o = X[i] + gate * ffo[i];
}

extern "C" void kernel_launch(void* const* d_in, const int* in_sizes, int n_in,
                              void* d_out, int out_size, void* d_ws, size_t ws_size,
                              hipStream_t stream)
{
    (void)in_sizes; (void)n_in; (void)out_size; (void)ws_size;
    const float* h_in = (const float*)d_in[0];
    const float* e_in = (const float*)d_in[1];
    const float* c_in = (const float*)d_in[2];
    const float* temb = (const float*)d_in[3];
    const float* rcos = (const float*)d_in[4];
    const float* rsin = (const float*)d_in[5];
    const float* n1w  = (const float*)d_in[6];
    const float* n1b  = (const float*)d_in[7];
    const float* ln1w = (const float*)d_in[8];
    const float* ln1b = (const float*)d_in[9];
    const float* n2w  = (const float*)d_in[10];
    const float* n2b  = (const float*)d_in[11];
    const float* ln2w = (const float*)d_in[12];
    const float* ln2b = (const float*)d_in[13];
    const float* wq   = (const float*)d_in[14];
    const float* wk   = (const float*)d_in[15];
    const float* wv   = (const float*)d_in[16];
    const float* nqw  = (const float*)d_in[17];
    const float* nqb  = (const float*)d_in[18];
    const float* nkw  = (const float*)d_in[19];
    const float* nkb  = (const float*)d_in[20];
    const float* wo   = (const float*)d_in[21];
    const float* bo   = (const float*)d_in[22];
    const float* fw1  = (const float*)d_in[23];
    const float* fb1  = (const float*)d_in[24];
    const float* fw2  = (const float*)d_in[25];
    const float* fb2  = (const float*)d_in[26];

    float* ws  = (float*)d_ws;
    float* out = (float*)d_out;
    float* s1   = ws + OFF_S1;
    float* s2   = ws + OFF_S2;
    float* score  = ws + OFF_MISC;
    int*   selh   = (int*)(ws + OFF_MISC + 16);
    int*   selvis = (int*)(ws + OFF_MISC + 32);
    float* sim  = ws + OFF_SIM;
    float* imap = ws + OFF_IMAP;
    float* ac   = ws + OFF_AC;
    float* X    = ws + OFF_X;
    float* proj = ws + OFF_PROJ;
    float* xn   = ws + OFF_XN;
    float* qh   = ws + OFF_Q;
    float* kh   = ws + OFF_K;
    float* vh   = ws + OFF_V;
    float* ao   = ws + OFF_AO;
    float* ffo  = proj;
    unsigned short* xnb   = (unsigned short*)(ws + OFF_XNB);
    unsigned short* wqkvT = (unsigned short*)(ws + OFF_PROJ);
    unsigned short* woT   = (unsigned short*)(ws + OFF_X);
    unsigned short* fw1T  = (unsigned short*)(ws + OFF_V);
    unsigned short* fw2T  = (unsigned short*)(ws + OFF_AO);
    unsigned short* ffh   = (unsigned short*)(ws + OFF_Q);

    // 1. adaLN modulation vectors
    hipLaunchKernelGGL(k_silu_mod, dim3(96), dim3(256), 0, stream, temb, n1w, n1b, n2w, n2b, s1, s2);
    // 2. weight transposes (QKV + wo) to bf16
    hipLaunchKernelGGL(k_tcvt, dim3(32, 32), dim3(256), 0, stream, wq, wqkvT,               1024, 1024);
    hipLaunchKernelGGL(k_tcvt, dim3(32, 32), dim3(256), 0, stream, wk, wqkvT + 1024*1024,   1024, 1024);
    hipLaunchKernelGGL(k_tcvt, dim3(32, 32), dim3(256), 0, stream, wv, wqkvT + 2*1024*1024, 1024, 1024);
    hipLaunchKernelGGL(k_tcvt, dim3(32, 32), dim3(256), 0, stream, wo, woT,                 1024, 1024);
    // 3. norm1 + modulation -> xn fp32 + xnb bf16
    hipLaunchKernelGGL(k_ln_mod, dim3(ROWS_), dim3(256), 0, stream,
        e_in, (long)TEXT_*DIM_, h_in, (long)IMG_*DIM_, c_in, (long)NC_*DIM_, s1, ln1w, ln1b, xn, xnb);
    // 4. fused QKV bf16 GEMM, headed scatter
    hipLaunchKernelGGL(k_bgemm, dim3(24, 28), dim3(256), 0, stream,
        xnb, wqkvT, (const float*)nullptr, (float*)nullptr, (unsigned short*)nullptr,
        ROWS_, 3072, 1024, 0, qh, kh, vh);
    // 5-6. fp32 fixups for argmax-feeding slices (batch1 img q rows, batch1 concept k rows)
    hipLaunchKernelGGL(k_gemm, dim3(16, 24), dim3(256), 0, stream,
        xn + (long)(S2_ + TEXT_)*DIM_, wq, (const float*)nullptr, qh, IMG_, DIM_, DIM_, 1, S2_ + TEXT_);
    hipLaunchKernelGGL(k_gemm, dim3(16, 1), dim3(256), 0, stream,
        xn + (long)(S2_ + S_MAIN)*DIM_, wk, (const float*)nullptr, kh, NC_, DIM_, DIM_, 1, S2_ + S_MAIN);
    // 7. QK layernorm + RoPE in place
    hipLaunchKernelGGL(k_qk_ln_rope, dim3(14160, 2), dim3(256), 0, stream, qh, kh, nqw, nqb, nkw, nkb, rcos, rsin);
    // 8. attentions
    hipLaunchKernelGGL(k_flash, dim3(28, 16, 2), dim3(256), 0, stream,
        qh, kh, vh, ao, S_MAIN, 0, 0, S_MAIN, 0, 0);
    hipLaunchKernelGGL(k_flash, dim3(1, 16, 2), dim3(256), 0, stream,
        qh, kh, vh, ac, NC_, S_MAIN, S_MAIN, S2_, TEXT_, S_MAIN);
    // 9. maps (batch 1)
    hipLaunchKernelGGL(k_head_score, dim3(16), dim3(256), 0, stream, ao, score);
    hipLaunchKernelGGL(k_top4, dim3(1), dim3(64), 0, stream, score, selh);
    hipLaunchKernelGGL(k_sim, dim3(512), dim3(512), 0, stream, qh, kh, sim, selvis);
    hipLaunchKernelGGL(k_cross, dim3(48), dim3(256), 0, stream, sim, out);
    hipLaunchKernelGGL(k_concept_maps, dim3(48), dim3(256), 0, stream, ac, ao, out);
    hipLaunchKernelGGL(k_imap_raw, dim3(512), dim3(384), 0, stream, ao, selvis, imap);
    hipLaunchKernelGGL(k_imap_norm, dim3(96), dim3(256), 0, stream, imap);
    hipLaunchKernelGGL(k_imap_reduce, dim3(48), dim3(256), 0, stream, imap, selh, out);
    // 10. merge -> xnb bf16
    hipLaunchKernelGGL(k_merge, dim3(14160), dim3(256), 0, stream, ao, ac, xnb);
    // 11. wo GEMM -> proj (overwrites wqkvT region; woT still intact in X region)
    hipLaunchKernelGGL(k_bgemm, dim3(8, 28), dim3(256), 0, stream,
        xnb, woT, bo, proj, (unsigned short*)nullptr, ROWS_, DIM_, 1024, 1,
        (float*)nullptr, (float*)nullptr, (float*)nullptr);
    // 12. residual1 -> X (overwrites woT region, dead now)
    hipLaunchKernelGGL(k_residual1, dim3(14160), dim3(256), 0, stream, e_in, h_in, c_in, proj, s1, X);
    // 13. FF weight transposes (into dead vh / ao regions)
    hipLaunchKernelGGL(k_tcvt, dim3(128, 32), dim3(256), 0, stream, fw1, fw1T, 1024, 4096);
    hipLaunchKernelGGL(k_tcvt, dim3(32, 128), dim3(256), 0, stream, fw2, fw2T, 4096, 1024);
    // 14. norm2 -> xnb bf16
    hipLaunchKernelGGL(k_ln_mod, dim3(ROWS_), dim3(256), 0, stream,
        X, (long)S2_*DIM_, X + (long)TEXT_*DIM_, (long)S2_*DIM_, X + (long)S_MAIN*DIM_, (long)S2_*DIM_,
        s2, ln2w, ln2b, xn, xnb);
    // 15. ff1 (gelu fused, bf16 out -> ffh over dead qh/kh)
    hipLaunchKernelGGL(k_bgemm, dim3(32, 28), dim3(256), 0, stream,
        xnb, fw1T, fb1, (float*)nullptr, ffh, ROWS_, FF_, 1024, 2,
        (float*)nullptr, (float*)nullptr, (float*)nullptr);
    // 16. ff2 -> ffo
    hipLaunchKernelGGL(k_bgemm, dim3(8, 28), dim3(256), 0, stream,
        ffh, fw2T, fb2, ffo, (unsigned short*)nullptr, ROWS_, DIM_, FF_, 1,
        (float*)nullptr, (float*)nullptr, (float*)nullptr);
    // 17. final gated residual -> outputs
    hipLaunchKernelGGL(k_final, dim3(14160), dim3(256), 0, stream, X, ffo, s2, out);
}

// Round 5
// 878.109 us; speedup vs baseline: 6.4992x; 1.1403x over previous
//
#include <hip/hip_runtime.h>
#include <hip/hip_bf16.h>
#include <math.h>

#define B_ 2
#define HEADS_ 16
#define HD_ 64
#define DIM_ 1024
#define TEXT_ 226
#define NC_ 8
#define FRAMES_ 4
#define PATCHES_ 384
#define IMG_ 1536
#define S_MAIN 1762
#define S2_ 1770
#define TD_ 512
#define FF_ 4096
#define ROWS_ (B_*S2_)   // 3540
#define VPAD_ 1792       // padded key dim for transposed V

// ---- workspace offsets (float slots) ----
#define OFF_S1   0L
#define OFF_S2   12288L
#define OFF_MISC 24576L
#define OFF_SIM  25600L
#define OFF_IMAP 222208L
#define OFF_AC   418816L
#define OFF_X    435200L
#define OFF_PROJ 4060160L
#define OFF_XN   7685120L
#define OFF_Q    11310080L
#define OFF_K    14935040L
#define OFF_V    18560000L
#define OFF_AO   22184960L
#define OFF_XNB  25809920L   // bf16 activations, 1,812,480 slots -> ends 27,622,400
// overlays (liveness-checked):
//   wqkvT bf16(3072x1024) @ OFF_PROJ      [written step2, read step4]
//   vb    bf16(B,H,64,1792) @ OFF_PROJ    [written step7b, read step8; proj overwrites step11]
//   qb/kb bf16(B,H,S2,64) @ OFF_X         [written step7, read step8; X overwrites step12]
//   woT   bf16(1024x1024) @ OFF_AO+2e6    [written step10.5 (ao dead), read step11]
//   fw1T  bf16(4096x1024) @ OFF_V         [step13+, vh dead]
//   fw2T  bf16(1024x4096) @ OFF_AO        [step13+, no overlap with woT]
//   ffh   bf16(3540x4096) @ OFF_Q         [step15+, qh/kh dead]

// ---- output offsets (floats) ----
#define O_H    0L
#define O_E    3145728L
#define O_C    3608576L
#define O_SELI 3624960L
#define O_ISUM 3637248L
#define O_CMAP 3649536L
#define O_XMAP 3661824L

typedef __bf16 bf16x8_t __attribute__((ext_vector_type(8)));
typedef float  f32x4_t  __attribute__((ext_vector_type(4)));

__device__ __forceinline__ unsigned int pack2bf(float a, float b) {
    unsigned short ua = __builtin_bit_cast(unsigned short, (__bf16)a);
    unsigned short ub = __builtin_bit_cast(unsigned short, (__bf16)b);
    return (unsigned int)ua | ((unsigned int)ub << 16);
}
__device__ __forceinline__ int4 packi4(float4 a, float4 b) {
    int4 t;
    t.x = (int)pack2bf(a.x, a.y); t.y = (int)pack2bf(a.z, a.w);
    t.z = (int)pack2bf(b.x, b.y); t.w = (int)pack2bf(b.z, b.w);
    return t;
}
__device__ __forceinline__ bf16x8_t cvt_bf8(float4 a, float4 b) {
    return __builtin_bit_cast(bf16x8_t, packi4(a, b));
}

// s1/s2 = silu(temb) @ norm_w + norm_b (k-split x4 for parallelism)
__global__ __launch_bounds__(256) void k_silu_mod(
    const float* __restrict__ temb, const float* __restrict__ w1, const float* __restrict__ b1,
    const float* __restrict__ w2, const float* __restrict__ b2,
    float* __restrict__ s1, float* __restrict__ s2)
{
    int gout = blockIdx.x * 64 + (threadIdx.x & 63);   // < 24576
    int ks = threadIdx.x >> 6;                          // 0..3
    int which = gout / 12288;
    int r = gout % 12288;
    int b = r / 6144, n = r % 6144;
    const float* w = which ? w2 : w1;
    const float* bb = which ? b2 : b1;
    const float* t = temb + b * TD_;
    float acc = 0.f;
    for (int k = ks*128; k < ks*128 + 128; ++k) {
        float tv = t[k];
        float sv = tv / (1.f + __expf(-tv));
        acc += sv * w[(long)k * 6144 + n];
    }
    __shared__ float red[256];
    red[threadIdx.x] = acc; __syncthreads();
    if (ks == 0) {
        int lt = threadIdx.x;
        float v = red[lt] + red[lt+64] + red[lt+128] + red[lt+192] + bb[n];
        (which ? s2 : s1)[b * 6144 + n] = v;
    }
}

// transpose + convert: src (K,N) fp32 -> dst (N,K) bf16
__global__ __launch_bounds__(256) void k_tcvt(
    const float* __restrict__ src, unsigned short* __restrict__ dst, int K, int N)
{
    __shared__ float t[32][33];
    int n0 = blockIdx.x * 32, k0 = blockIdx.y * 32;
    int tx = threadIdx.x & 31, ty = threadIdx.x >> 5;
    #pragma unroll
    for (int i = 0; i < 4; ++i)
        t[ty + 8*i][tx] = src[(size_t)(k0 + ty + 8*i) * N + n0 + tx];
    __syncthreads();
    #pragma unroll
    for (int i = 0; i < 4; ++i) {
        float v = t[tx][ty + 8*i];
        dst[(size_t)(n0 + ty + 8*i) * K + k0 + tx] =
            __builtin_bit_cast(unsigned short, (__bf16)v);
    }
}

// V (B,H,S2,64) fp32 -> vb (B,H,64,VPAD) bf16 transposed
__global__ __launch_bounds__(256) void k_vtrans(
    const float* __restrict__ vh, unsigned short* __restrict__ vb)
{
    int bh = blockIdx.z;
    int d0 = blockIdx.y * 32;
    int s0 = blockIdx.x * 32;
    __shared__ float t[32][33];
    int tx = threadIdx.x & 31, ty = threadIdx.x >> 5;
    const float* src = vh + (size_t)bh * S2_ * 64;
    #pragma unroll
    for (int i = 0; i < 4; ++i) {
        int s = s0 + ty + 8*i; if (s >= S2_) s = S2_ - 1;
        t[ty + 8*i][tx] = src[(size_t)s*64 + d0 + tx];
    }
    __syncthreads();
    unsigned short* dst = vb + (size_t)bh * 64 * VPAD_;
    #pragma unroll
    for (int i = 0; i < 4; ++i) {
        int d = d0 + ty + 8*i;
        dst[(size_t)d * VPAD_ + s0 + tx] =
            __builtin_bit_cast(unsigned short, (__bf16)t[tx][ty + 8*i]);
    }
}

// fused layernorm + adaLN modulation -> fp32 xn AND bf16 xnb
__global__ __launch_bounds__(256) void k_ln_mod(
    const float* pe, long bse, const float* ph, long bsh, const float* pc, long bsc,
    const float* __restrict__ smod, const float* __restrict__ lnw, const float* __restrict__ lnb,
    float* __restrict__ out, unsigned short* __restrict__ outb)
{
    long row = blockIdx.x;
    int b = (int)(row / S2_), s = (int)(row % S2_);
    const float* src; int shiftB, scaleB;
    if (s < TEXT_)       { src = pe + (long)b*bse + (long)s*DIM_;          shiftB = 3072; scaleB = 4096; }
    else if (s < S_MAIN) { src = ph + (long)b*bsh + (long)(s-TEXT_)*DIM_;  shiftB = 0;    scaleB = 1024; }
    else                 { src = pc + (long)b*bsc + (long)(s-S_MAIN)*DIM_; shiftB = 3072; scaleB = 4096; }
    int tid = threadIdx.x;
    int col = tid * 4;
    float4 x = *(const float4*)(src + col);
    float lsum = x.x + x.y + x.z + x.w;
    float lsq  = x.x*x.x + x.y*x.y + x.z*x.z + x.w*x.w;
    __shared__ float r1[256], r2[256];
    r1[tid] = lsum; r2[tid] = lsq; __syncthreads();
    for (int st = 128; st; st >>= 1) {
        if (tid < st) { r1[tid] += r1[tid+st]; r2[tid] += r2[tid+st]; }
        __syncthreads();
    }
    float mu = r1[0] * (1.f / DIM_);
    float var = r2[0] * (1.f / DIM_) - mu * mu;
    float rstd = rsqrtf(var + 1e-5f);
    const float* sb = smod + (long)b * 6144;
    float xs[4] = {x.x, x.y, x.z, x.w};
    float res[4];
    #pragma unroll
    for (int i = 0; i < 4; ++i) {
        int cc = col + i;
        float yy = (xs[i] - mu) * rstd * lnw[cc] + lnb[cc];
        res[i] = yy * (1.f + sb[scaleB + cc]) + sb[shiftB + cc];
    }
    *(float4*)(out + row * DIM_ + col) = make_float4(res[0], res[1], res[2], res[3]);
    uint2 pk;
    pk.x = pack2bf(res[0], res[1]); pk.y = pack2bf(res[2], res[3]);
    *(uint2*)(outb + row * DIM_ + col) = pk;
}

// bf16 MFMA GEMM: C = A(M,K)bf16 @ Wt(N,K)bf16^T. 128x128 tile, 4 waves 2x2.
// mode 0: headed fp32 scatter to q/k/v (N=3072). mode 1: fp32 +bias. mode 2: gelu->bf16.
__global__ __launch_bounds__(256, 3) void k_bgemm(
    const unsigned short* __restrict__ A, const unsigned short* __restrict__ Wt,
    const float* __restrict__ bias, float* __restrict__ out_f,
    unsigned short* __restrict__ out_b, int M, int N, int K, int mode,
    float* __restrict__ q_out, float* __restrict__ k_out, float* __restrict__ v_out)
{
    __shared__ unsigned short at[128*40];
    __shared__ unsigned short bt[128*40];
    int tid = threadIdx.x;
    int w = tid >> 6, lane = tid & 63;
    int lr = lane & 15, lh = lane >> 4;
    int wm = w >> 1, wn = w & 1;
    int m0 = blockIdx.y * 128, n0 = blockIdx.x * 128;

    f32x4_t acc[4][4];
    #pragma unroll
    for (int i = 0; i < 4; ++i)
        #pragma unroll
        for (int j = 0; j < 4; ++j) { acc[i][j][0]=0.f; acc[i][j][1]=0.f; acc[i][j][2]=0.f; acc[i][j][3]=0.f; }

    int srow = tid >> 1, shalf = tid & 1;
    int arow = m0 + srow; if (arow >= M) arow = M - 1;
    const unsigned short* aptr = A + (size_t)arow * K + shalf * 16;
    const unsigned short* bptr = Wt + (size_t)(n0 + srow) * K + shalf * 16;
    unsigned short* asd = &at[srow * 40 + shalf * 16];
    unsigned short* bsd = &bt[srow * 40 + shalf * 16];

    for (int k0 = 0; k0 < K; k0 += 32) {
        int4 a0 = *(const int4*)(aptr + k0);
        int4 a1 = *(const int4*)(aptr + k0 + 8);
        int4 b0 = *(const int4*)(bptr + k0);
        int4 b1 = *(const int4*)(bptr + k0 + 8);
        __syncthreads();
        *(int4*)asd = a0; *(int4*)(asd + 8) = a1;
        *(int4*)bsd = b0; *(int4*)(bsd + 8) = b1;
        __syncthreads();
        int4 af[4], bf[4];
        #pragma unroll
        for (int tm = 0; tm < 4; ++tm)
            af[tm] = *(const int4*)&at[(wm*64 + tm*16 + lr)*40 + lh*8];
        #pragma unroll
        for (int tn = 0; tn < 4; ++tn)
            bf[tn] = *(const int4*)&bt[(wn*64 + tn*16 + lr)*40 + lh*8];
        #pragma unroll
        for (int tm = 0; tm < 4; ++tm) {
            bf16x8_t av = __builtin_bit_cast(bf16x8_t, af[tm]);
            #pragma unroll
            for (int tn = 0; tn < 4; ++tn)
                acc[tm][tn] = __builtin_amdgcn_mfma_f32_16x16x32_bf16(
                    av, __builtin_bit_cast(bf16x8_t, bf[tn]), acc[tm][tn], 0, 0, 0);
        }
    }
    #pragma unroll
    for (int tm = 0; tm < 4; ++tm) {
        #pragma unroll
        for (int r = 0; r < 4; ++r) {
            int m = m0 + wm*64 + tm*16 + lh*4 + r;
            if (m >= M) continue;
            int b = m / S2_, s = m % S2_;
            #pragma unroll
            for (int tn = 0; tn < 4; ++tn) {
                int n = n0 + wn*64 + tn*16 + lr;
                float v = acc[tm][tn][r];
                if (mode == 0) {
                    int which = n >> 10, c = n & 1023;
                    int hh = c >> 6, d = c & 63;
                    float* dstp = (which == 0) ? q_out : (which == 1) ? k_out : v_out;
                    dstp[(((size_t)b*HEADS_ + hh)*S2_ + s)*64 + d] = v;
                } else if (mode == 1) {
                    out_f[(size_t)m * N + n] = v + bias[n];
                } else {
                    float x = v + bias[n];
                    float u = 0.7978845608028654f * (x + 0.044715f*x*x*x);
                    float g = x / (1.f + __expf(-2.f*u));
                    out_b[(size_t)m * N + n] = __builtin_bit_cast(unsigned short, (__bf16)g);
                }
            }
        }
    }
}

// fp32 tiled GEMM (fixup for argmax-feeding slices).
__global__ __launch_bounds__(256) void k_gemm(
    const float* __restrict__ A, const float* __restrict__ W, const float* __restrict__ bias,
    float* __restrict__ C, int M, int N, int K, int headed, int row_off)
{
    __shared__ float As[16][68];
    __shared__ float Bs[16][68];
    int tid = threadIdx.x;
    int bm = blockIdx.y * 64, bn = blockIdx.x * 64;
    int tr = tid >> 4, tc = tid & 15;
    int ar = tid >> 2, akk = (tid & 3) * 4;
    int bkk = tid >> 4, bn4 = (tid & 15) * 4;
    float acc[4][4] = {{0.f}};
    int garow = bm + ar;
    const float* Aptr = A + (size_t)garow * K + akk;
    const float* Wptr = W + (size_t)bkk * N + bn + bn4;
    for (int k0 = 0; k0 < K; k0 += 16) {
        float4 av = make_float4(0.f, 0.f, 0.f, 0.f);
        if (garow < M) av = *(const float4*)(Aptr + k0);
        As[akk+0][ar] = av.x; As[akk+1][ar] = av.y; As[akk+2][ar] = av.z; As[akk+3][ar] = av.w;
        float4 bv = *(const float4*)(Wptr + (size_t)k0 * N);
        Bs[bkk][bn4+0] = bv.x; Bs[bkk][bn4+1] = bv.y; Bs[bkk][bn4+2] = bv.z; Bs[bkk][bn4+3] = bv.w;
        __syncthreads();
        #pragma unroll
        for (int kk = 0; kk < 16; ++kk) {
            float4 a = *(const float4*)&As[kk][tr*4];
            float4 bq = *(const float4*)&Bs[kk][tc*4];
            float avv[4] = {a.x, a.y, a.z, a.w};
            float bvv[4] = {bq.x, bq.y, bq.z, bq.w};
            #pragma unroll
            for (int i = 0; i < 4; ++i)
                #pragma unroll
                for (int j = 0; j < 4; ++j)
                    acc[i][j] += avv[i] * bvv[j];
        }
        __syncthreads();
    }
    #pragma unroll
    for (int i = 0; i < 4; ++i) {
        int r = bm + tr*4 + i;
        if (r >= M) continue;
        #pragma unroll
        for (int j = 0; j < 4; ++j) {
            int n = bn + tc*4 + j;
            float v = acc[i][j] + (bias ? bias[n] : 0.f);
            if (headed) {
                int rg = r + row_off;
                int b = rg / S2_, s = rg % S2_;
                int hh = n >> 6, d = n & 63;
                C[(((size_t)b*HEADS_ + hh)*S2_ + s)*64 + d] = v;
            } else {
                C[(size_t)(r + row_off) * N + n] = v;
            }
        }
    }
}

// per-head layernorm + RoPE: fp32 in place AND bf16 copies
__global__ __launch_bounds__(256) void k_qk_prep(
    float* qh, float* kh, unsigned short* qbb, unsigned short* kbb,
    const float* __restrict__ nqw, const float* __restrict__ nqb,
    const float* __restrict__ nkw, const float* __restrict__ nkb,
    const float* __restrict__ rc, const float* __restrict__ rs)
{
    int which = blockIdx.y;
    int wid = threadIdx.x >> 6;
    int lane = threadIdx.x & 63;
    long row = (long)blockIdx.x * 4 + wid;
    long s = row % S2_;
    float* base = (which ? kh : qh) + row * 64;
    const float* w  = which ? nkw : nqw;
    const float* bb = which ? nkb : nqb;
    float x = base[lane];
    float sum = x;
    for (int off = 1; off < 64; off <<= 1) sum += __shfl_xor(sum, off, 64);
    float mu = sum * (1.f / 64.f);
    float dx = x - mu;
    float v = dx * dx;
    for (int off = 1; off < 64; off <<= 1) v += __shfl_xor(v, off, 64);
    float rstd = rsqrtf(v * (1.f / 64.f) + 1e-6f);
    float y = dx * rstd * w[lane] + bb[lane];
    if (s >= TEXT_ && s < S_MAIN) {
        long p = s - TEXT_;
        float part = __shfl_xor(y, 1, 64);
        float rot = (lane & 1) ? part : -part;
        y = y * rc[p*64 + lane] + rot * rs[p*64 + lane];
    }
    base[lane] = y;
    (which ? kbb : qbb)[row * 64 + lane] = __builtin_bit_cast(unsigned short, (__bf16)y);
}

// MFMA flash attention, bf16 inputs, no-max softmax, ones-MFMA row sums.
// qb/kb: (B,H,S2,64) bf16. vb: (B,H,64,VPAD) bf16 transposed. out fp32 (B,H,NQ,64).
__global__ __launch_bounds__(256) void k_flash(
    const unsigned short* __restrict__ qb, const unsigned short* __restrict__ kb,
    const unsigned short* __restrict__ vb,
    float* __restrict__ outp, int NQ, int q_off, int r0s, int r0e, int r1s, int r1e)
{
    int h = blockIdx.y, b = blockIdx.z;
    int qt = blockIdx.x * 64;
    int tid = threadIdx.x;
    int w = tid >> 6, lane = tid & 63;
    int lr = lane & 15, lh = lane >> 4;
    __shared__ __align__(16) unsigned short kt[64*72];
    __shared__ __align__(16) unsigned short vt[64*72];
    __shared__ __align__(16) unsigned short pbuf[4*16*72];
    unsigned short* pw = pbuf + w*16*72;
    const unsigned short* qbase = qb + (((size_t)b*HEADS_ + h)*S2_ + q_off)*64;
    const unsigned short* kbase = kb + ((size_t)b*HEADS_ + h)*S2_*64;
    const unsigned short* vbase = vb + (size_t)(b*HEADS_ + h)*64*VPAD_;
    int qrow = qt + w*16 + lr; if (qrow >= NQ) qrow = NQ - 1;
    const unsigned short* qsrc = qbase + (size_t)qrow*64 + lh*8;
    bf16x8_t aq0 = __builtin_bit_cast(bf16x8_t, *(const int4*)qsrc);
    bf16x8_t aq1 = __builtin_bit_cast(bf16x8_t, *(const int4*)(qsrc + 32));
    int4 onesi = make_int4(0x3F803F80, 0x3F803F80, 0x3F803F80, 0x3F803F80);
    bf16x8_t bones = __builtin_bit_cast(bf16x8_t, onesi);
    f32x4_t O[4];
    #pragma unroll
    for (int g = 0; g < 4; ++g) { O[g][0]=0.f; O[g][1]=0.f; O[g][2]=0.f; O[g][3]=0.f; }
    f32x4_t Lacc; Lacc[0]=0.f; Lacc[1]=0.f; Lacc[2]=0.f; Lacc[3]=0.f;
    for (int rgi = 0; rgi < 2; ++rgi) {
        int rs = rgi ? r1s : r0s, re = rgi ? r1e : r0e;
        for (int j0 = rs; j0 < re; j0 += 64) {
            int cnt = min(64, re - j0);
            __syncthreads();
            #pragma unroll
            for (int i = 0; i < 2; ++i) {
                int idx = tid + i*256;
                int key = idx >> 3, p8 = idx & 7;
                int krow = j0 + key; if (krow > re - 1) krow = re - 1;
                *(int4*)&kt[key*72 + p8*8] = *(const int4*)(kbase + (size_t)krow*64 + p8*8);
            }
            #pragma unroll
            for (int i = 0; i < 2; ++i) {
                int idx = tid + i*256;
                int d = idx >> 3, p8 = idx & 7;
                *(int4*)&vt[d*72 + p8*8] = *(const int4*)(vbase + (size_t)d*VPAD_ + j0 + p8*8);
            }
            __syncthreads();
            f32x4_t S[4];
            #pragma unroll
            for (int g = 0; g < 4; ++g) {
                const unsigned short* kr = &kt[(16*g + lr)*72 + lh*8];
                bf16x8_t b0 = __builtin_bit_cast(bf16x8_t, *(const int4*)kr);
                bf16x8_t b1 = __builtin_bit_cast(bf16x8_t, *(const int4*)(kr + 32));
                f32x4_t z; z[0]=0.f; z[1]=0.f; z[2]=0.f; z[3]=0.f;
                z = __builtin_amdgcn_mfma_f32_16x16x32_bf16(aq0, b0, z, 0, 0, 0);
                z = __builtin_amdgcn_mfma_f32_16x16x32_bf16(aq1, b1, z, 0, 0, 0);
                S[g] = z;
            }
            // p = exp(s*0.125), masked; no max subtraction (scores bounded)
            #pragma unroll
            for (int g = 0; g < 4; ++g) {
                bool vld = (16*g + lr) < cnt;
                #pragma unroll
                for (int r = 0; r < 4; ++r) {
                    float p = vld ? __expf(S[g][r] * 0.125f) : 0.f;
                    pw[(lh*4 + r)*72 + 16*g + lr] = __builtin_bit_cast(unsigned short, (__bf16)p);
                }
            }
            #pragma unroll
            for (int c = 0; c < 2; ++c) {
                bf16x8_t ap = __builtin_bit_cast(bf16x8_t,
                    *(const int4*)&pw[lr*72 + c*32 + lh*8]);
                Lacc = __builtin_amdgcn_mfma_f32_16x16x32_bf16(ap, bones, Lacc, 0, 0, 0);
                #pragma unroll
                for (int g = 0; g < 4; ++g) {
                    bf16x8_t bv = __builtin_bit_cast(bf16x8_t,
                        *(const int4*)&vt[(16*g + lr)*72 + c*32 + lh*8]);
                    O[g] = __builtin_amdgcn_mfma_f32_16x16x32_bf16(ap, bv, O[g], 0, 0, 0);
                }
            }
        }
    }
    #pragma unroll
    for (int r = 0; r < 4; ++r) {
        float inv = 1.f / Lacc[r];
        int gq = qt + w*16 + lh*4 + r;
        if (gq < NQ) {
            float* o = outp + (((size_t)b*HEADS_ + h)*NQ + gq)*64 + lr;
            #pragma unroll
            for (int g = 0; g < 4; ++g) o[16*g] = O[g][r] * inv;
        }
    }
}

__global__ __launch_bounds__(256) void k_head_score(const float* __restrict__ ao, float* __restrict__ score)
{
    int h = blockIdx.x, tid = threadIdx.x;
    const float* base = ao + (((long)HEADS_ + h)*S_MAIN + TEXT_)*64;
    float sA = 0.f, sB = 0.f;
    for (int p = tid; p < IMG_; p += 256) {
        const float* r = base + (long)p*64;
        float mm = 0.f;
        for (int d = 0; d < 64; d += 4) {
            float4 v = *(const float4*)(r + d);
            mm += v.x + v.y + v.z + v.w;
        }
        mm *= (1.f / 64.f);
        sA += mm; sB += mm*mm;
    }
    __shared__ float r1[256], r2[256];
    r1[tid] = sA; r2[tid] = sB; __syncthreads();
    for (int st = 128; st; st >>= 1) {
        if (tid < st) { r1[tid] += r1[tid+st]; r2[tid] += r2[tid+st]; }
        __syncthreads();
    }
    if (tid == 0) {
        float mean = r1[0] / IMG_, ms = r2[0] / IMG_;
        score[h] = sqrtf(fmaxf(ms - mean*mean, 0.f));
    }
}

__global__ void k_top4(const float* __restrict__ score, int* __restrict__ sel)
{
    if (threadIdx.x == 0 && blockIdx.x == 0) {
        int used = 0;
        for (int k = 0; k < 4; ++k) {
            float best = -INFINITY; int bi = 0;
            for (int h2 = 0; h2 < 16; ++h2) {
                if (used & (1 << h2)) continue;
                if (score[h2] > best) { best = score[h2]; bi = h2; }
            }
            used |= 1 << bi; sel[k] = bi;
        }
    }
}

__global__ __launch_bounds__(512) void k_sim(
    const float* __restrict__ qh, const float* __restrict__ kh,
    float* __restrict__ sim, int* __restrict__ selvis)
{
    int blk = blockIdx.x;    // (h*8+t)*4+f
    int h = blk >> 5, t = (blk >> 2) & 7, f = blk & 3;
    int tid = threadIdx.x;
    __shared__ float ckv[64];
    if (tid < 64) ckv[tid] = kh[(((long)HEADS_ + h)*S2_ + S_MAIN + t)*64 + tid];
    __syncthreads();
    float val = -INFINITY; int idx = 0x7fffffff;
    if (tid < PATCHES_) {
        const float* qrow = qh + (((long)HEADS_ + h)*S2_ + TEXT_ + f*PATCHES_ + tid)*64;
        float acc = 0.f;
        for (int d = 0; d < 64; d += 4) {
            float4 qv = *(const float4*)(qrow + d);
            acc += qv.x*ckv[d] + qv.y*ckv[d+1] + qv.z*ckv[d+2] + qv.w*ckv[d+3];
        }
        sim[((long)h*NC_ + t)*IMG_ + f*PATCHES_ + tid] = acc;
        val = acc; idx = tid;
    }
    __shared__ float sv[512]; __shared__ int si[512];
    sv[tid] = val; si[tid] = idx; __syncthreads();
    for (int st = 256; st; st >>= 1) {
        if (tid < st) {
            float v2 = sv[tid+st]; int i2 = si[tid+st];
            if (v2 > sv[tid] || (v2 == sv[tid] && i2 < si[tid])) { sv[tid] = v2; si[tid] = i2; }
        }
        __syncthreads();
    }
    if (tid == 0) selvis[blk] = si[0];
}

__global__ __launch_bounds__(256) void k_cross(const float* __restrict__ sim, float* __restrict__ out)
{
    int i = blockIdx.x*256 + threadIdx.x;   // < 12288
    int c = i / IMG_, p = i % IMG_;
    float acc = 0.f;
    for (int h = 0; h < 16; ++h) acc += sim[((long)h*NC_ + c)*IMG_ + p];
    out[O_XMAP + i] = acc * (1.f / 16.f);
}

__global__ __launch_bounds__(256) void k_concept_maps(
    const float* __restrict__ ac, const float* __restrict__ ao, float* __restrict__ out)
{
    int i = blockIdx.x*256 + threadIdx.x;   // < 12288
    int c = i / IMG_, p = i % IMG_;
    float acc = 0.f;
    for (int h = 0; h < 16; ++h) {
        const float* a = ac + (((long)HEADS_ + h)*NC_ + c)*64;
        const float* g = ao + (((long)HEADS_ + h)*S_MAIN + TEXT_ + p)*64;
        for (int d = 0; d < 64; d += 4) {
            float4 av = *(const float4*)(a + d);
            float4 gv = *(const float4*)(g + d);
            acc += av.x*gv.x + av.y*gv.y + av.z*gv.z + av.w*gv.w;
        }
    }
    out[O_CMAP + i] = acc;
}

__global__ void k_imap_raw(const float* __restrict__ ao, const int* __restrict__ selvis,
                           float* __restrict__ imap)
{
    int blk = blockIdx.x;   // (h*8+t)*4+f
    int h = blk >> 5, t = (blk >> 2) & 7, f = blk & 3;
    int tid = threadIdx.x;  // 384
    __shared__ float sel[64];
    int pstar = selvis[blk];
    if (tid < 64) sel[tid] = ao[(((long)HEADS_ + h)*S_MAIN + TEXT_ + f*PATCHES_ + pstar)*64 + tid];
    __syncthreads();
    const float* g = ao + (((long)HEADS_ + h)*S_MAIN + TEXT_ + f*PATCHES_ + tid)*64;
    float acc = 0.f;
    for (int d = 0; d < 64; d += 4) {
        float4 gv = *(const float4*)(g + d);
        acc += gv.x*sel[d] + gv.y*sel[d+1] + gv.z*sel[d+2] + gv.w*sel[d+3];
    }
    imap[((long)h*NC_ + t)*IMG_ + f*PATCHES_ + tid] = acc;
}

__global__ __launch_bounds__(256) void k_imap_norm(float* __restrict__ imap)
{
    int i = blockIdx.x*256 + threadIdx.x;   // < 24576
    int h = i / IMG_, fp = i % IMG_;
    float v[8]; float mu = 0.f;
    #pragma unroll
    for (int t = 0; t < 8; ++t) { v[t] = imap[((long)h*NC_ + t)*IMG_ + fp]; mu += v[t]; }
    mu *= 0.125f;
    float var = 0.f;
    #pragma unroll
    for (int t = 0; t < 8; ++t) var += (v[t]-mu)*(v[t]-mu);
    float sd = sqrtf(var * (1.f / 7.f));
    float inv = 1.f / (sd + 1e-6f);
    #pragma unroll
    for (int t = 0; t < 8; ++t) imap[((long)h*NC_ + t)*IMG_ + fp] = (v[t]-mu)*inv;
}

__global__ __launch_bounds__(256) void k_imap_reduce(
    const float* __restrict__ imap, const int* __restrict__ sel, float* __restrict__ out)
{
    int i = blockIdx.x*256 + threadIdx.x;   // < 12288
    int t = i / IMG_, fp = i % IMG_;
    float sum = 0.f;
    for (int h = 0; h < 16; ++h) sum += imap[((long)h*NC_ + t)*IMG_ + fp];
    float ss = 0.f;
    for (int k = 0; k < 4; ++k) { int h = sel[k]; ss += imap[((long)h*NC_ + t)*IMG_ + fp]; }
    out[O_ISUM + i] = sum;
    out[O_SELI + i] = ss * 0.25f;
}

__global__ __launch_bounds__(256) void k_merge(
    const float* __restrict__ ao, const float* __restrict__ ac, unsigned short* __restrict__ xo)
{
    long i = (long)blockIdx.x*256 + threadIdx.x;   // < 3,624,960
    int col = (int)(i & 1023);
    long row = i >> 10;
    int b = (int)(row / S2_), s = (int)(row % S2_);
    int h = col >> 6, d = col & 63;
    float v;
    if (s < S_MAIN) v = ao[(((long)b*HEADS_ + h)*S_MAIN + s)*64 + d];
    else            v = ac[(((long)b*HEADS_ + h)*NC_ + (s - S_MAIN))*64 + d];
    xo[i] = __builtin_bit_cast(unsigned short, (__bf16)v);
}

__global__ __launch_bounds__(256) void k_residual1(
    const float* __restrict__ pe, const float* __restrict__ ph, const float* __restrict__ pc,
    const float* __restrict__ proj, const float* __restrict__ s1, float* __restrict__ X)
{
    long i = (long)blockIdx.x*256 + threadIdx.x;
    int col = (int)(i & 1023);
    long row = i >> 10;
    int b = (int)(row / S2_), s = (int)(row % S2_);
    const float* sb = s1 + (long)b * 6144;
    float orig, gate;
    if (s < TEXT_)       { orig = pe[((long)b*TEXT_ + s)*DIM_ + col];            gate = sb[5120 + col]; }
    else if (s < S_MAIN) { orig = ph[((long)b*IMG_ + (s-TEXT_))*DIM_ + col];     gate = sb[2048 + col]; }
    else                 { orig = pc[((long)b*NC_ + (s-S_MAIN))*DIM_ + col];     gate = sb[5120 + col]; }
    X[i] = orig + gate * proj[i];
}

__global__ __launch_bounds__(256) void k_final(
    const float* __restrict__ X, const float* __restrict__ ffo,
    const float* __restrict__ s2, float* __restrict__ out)
{
    long i = (long)blockIdx.x*256 + threadIdx.x;
    int col = (int)(i & 1023);
    long row = i >> 10;
    int b = (int)(row / S2_), s = (int)(row % S2_);
    const float* sb = s2 + (long)b * 6144;
    float gate; float* o;
    if (s < TEXT_)       { gate = sb[5120 + col]; o = out + O_E + ((long)b*TEXT_ + s)*DIM_ + col; }
    else if (s < S_MAIN) { gate = sb[2048 + col]; o = out + O_H + ((long)b*IMG_ + (s-TEXT_))*DIM_ + col; }
    else                 { gate = sb[5120 + col]; o = out + O_C + ((long)b*NC_ + (s-S_MAIN))*DIM_ + col; }
    *o = X[i] + gate * ffo[i];
}

extern "C" void kernel_launch(void* const* d_in, const int* in_sizes, int n_in,
                              void* d_out, int out_size, void* d_ws, size_t ws_size,
                              hipStream_t stream)
{
    (void)in_sizes; (void)n_in; (void)out_size; (void)ws_size;
    const float* h_in = (const float*)d_in[0];
    const float* e_in = (const float*)d_in[1];
    const float* c_in = (const float*)d_in[2];
    const float* temb = (const float*)d_in[3];
    const float* rcos = (const float*)d_in[4];
    const float* rsin = (const float*)d_in[5];
    const float* n1w  = (const float*)d_in[6];
    const float* n1b  = (const float*)d_in[7];
    const float* ln1w = (const float*)d_in[8];
    const float* ln1b = (const float*)d_in[9];
    const float* n2w  = (const float*)d_in[10];
    const float* n2b  = (const float*)d_in[11];
    const float* ln2w = (const float*)d_in[12];
    const float* ln2b = (const float*)d_in[13];
    const float* wq   = (const float*)d_in[14];
    const float* wk   = (const float*)d_in[15];
    const float* wv   = (const float*)d_in[16];
    const float* nqw  = (const float*)d_in[17];
    const float* nqb  = (const float*)d_in[18];
    const float* nkw  = (const float*)d_in[19];
    const float* nkb  = (const float*)d_in[20];
    const float* wo   = (const float*)d_in[21];
    const float* bo   = (const float*)d_in[22];
    const float* fw1  = (const float*)d_in[23];
    const float* fb1  = (const float*)d_in[24];
    const float* fw2  = (const float*)d_in[25];
    const float* fb2  = (const float*)d_in[26];

    float* ws  = (float*)d_ws;
    float* out = (float*)d_out;
    float* s1   = ws + OFF_S1;
    float* s2   = ws + OFF_S2;
    float* score  = ws + OFF_MISC;
    int*   selh   = (int*)(ws + OFF_MISC + 16);
    int*   selvis = (int*)(ws + OFF_MISC + 32);
    float* sim  = ws + OFF_SIM;
    float* imap = ws + OFF_IMAP;
    float* ac   = ws + OFF_AC;
    float* X    = ws + OFF_X;
    float* proj = ws + OFF_PROJ;
    float* xn   = ws + OFF_XN;
    float* qh   = ws + OFF_Q;
    float* kh   = ws + OFF_K;
    float* vh   = ws + OFF_V;
    float* ao   = ws + OFF_AO;
    float* ffo  = proj;
    unsigned short* xnb   = (unsigned short*)(ws + OFF_XNB);
    unsigned short* wqkvT = (unsigned short*)(ws + OFF_PROJ);
    unsigned short* vb    = (unsigned short*)(ws + OFF_PROJ);        // after QKV gemm
    unsigned short* qbb   = (unsigned short*)(ws + OFF_X);
    unsigned short* kbb   = qbb + (size_t)B_*HEADS_*S2_*64;
    unsigned short* woT   = (unsigned short*)(ws + OFF_AO + 2000000);
    unsigned short* fw1T  = (unsigned short*)(ws + OFF_V);
    unsigned short* fw2T  = (unsigned short*)(ws + OFF_AO);
    unsigned short* ffh   = (unsigned short*)(ws + OFF_Q);

    // 1. adaLN modulation vectors
    hipLaunchKernelGGL(k_silu_mod, dim3(384), dim3(256), 0, stream, temb, n1w, n1b, n2w, n2b, s1, s2);
    // 2. QKV weight transposes to bf16
    hipLaunchKernelGGL(k_tcvt, dim3(32, 32), dim3(256), 0, stream, wq, wqkvT,               1024, 1024);
    hipLaunchKernelGGL(k_tcvt, dim3(32, 32), dim3(256), 0, stream, wk, wqkvT + 1024*1024,   1024, 1024);
    hipLaunchKernelGGL(k_tcvt, dim3(32, 32), dim3(256), 0, stream, wv, wqkvT + 2*1024*1024, 1024, 1024);
    // 3. norm1 + modulation -> xn fp32 + xnb bf16
    hipLaunchKernelGGL(k_ln_mod, dim3(ROWS_), dim3(256), 0, stream,
        e_in, (long)TEXT_*DIM_, h_in, (long)IMG_*DIM_, c_in, (long)NC_*DIM_, s1, ln1w, ln1b, xn, xnb);
    // 4. fused QKV bf16 GEMM, headed fp32 scatter
    hipLaunchKernelGGL(k_bgemm, dim3(24, 28), dim3(256), 0, stream,
        xnb, wqkvT, (const float*)nullptr, (float*)nullptr, (unsigned short*)nullptr,
        ROWS_, 3072, 1024, 0, qh, kh, vh);
    // 5-6. fp32 fixups for argmax-feeding slices
    hipLaunchKernelGGL(k_gemm, dim3(16, 24), dim3(256), 0, stream,
        xn + (long)(S2_ + TEXT_)*DIM_, wq, (const float*)nullptr, qh, IMG_, DIM_, DIM_, 1, S2_ + TEXT_);
    hipLaunchKernelGGL(k_gemm, dim3(16, 1), dim3(256), 0, stream,
        xn + (long)(S2_ + S_MAIN)*DIM_, wk, (const float*)nullptr, kh, NC_, DIM_, DIM_, 1, S2_ + S_MAIN);
    // 7. QK layernorm + RoPE (fp32 in place + bf16 qb/kb); V transpose to bf16
    hipLaunchKernelGGL(k_qk_prep, dim3(14160, 2), dim3(256), 0, stream,
        qh, kh, qbb, kbb, nqw, nqb, nkw, nkb, rcos, rsin);
    hipLaunchKernelGGL(k_vtrans, dim3(56, 2, 32), dim3(256), 0, stream, vh, vb);
    // 8. attentions (bf16 inputs)
    hipLaunchKernelGGL(k_flash, dim3(28, 16, 2), dim3(256), 0, stream,
        qbb, kbb, vb, ao, S_MAIN, 0, 0, S_MAIN, 0, 0);
    hipLaunchKernelGGL(k_flash, dim3(1, 16, 2), dim3(256), 0, stream,
        qbb, kbb, vb, ac, NC_, S_MAIN, S_MAIN, S2_, TEXT_, S_MAIN);
    // 9. maps (batch 1)
    hipLaunchKernelGGL(k_head_score, dim3(16), dim3(256), 0, stream, ao, score);
    hipLaunchKernelGGL(k_top4, dim3(1), dim3(64), 0, stream, score, selh);
    hipLaunchKernelGGL(k_sim, dim3(512), dim3(512), 0, stream, qh, kh, sim, selvis);
    hipLaunchKernelGGL(k_cross, dim3(48), dim3(256), 0, stream, sim, out);
    hipLaunchKernelGGL(k_concept_maps, dim3(48), dim3(256), 0, stream, ac, ao, out);
    hipLaunchKernelGGL(k_imap_raw, dim3(512), dim3(384), 0, stream, ao, selvis, imap);
    hipLaunchKernelGGL(k_imap_norm, dim3(96), dim3(256), 0, stream, imap);
    hipLaunchKernelGGL(k_imap_reduce, dim3(48), dim3(256), 0, stream, imap, selh, out);
    // 10. merge -> xnb bf16; then wo transpose into dead ao region
    hipLaunchKernelGGL(k_merge, dim3(14160), dim3(256), 0, stream, ao, ac, xnb);
    hipLaunchKernelGGL(k_tcvt, dim3(32, 32), dim3(256), 0, stream, wo, woT, 1024, 1024);
    // 11. wo GEMM -> proj
    hipLaunchKernelGGL(k_bgemm, dim3(8, 28), dim3(256), 0, stream,
        xnb, woT, bo, proj, (unsigned short*)nullptr, ROWS_, DIM_, 1024, 1,
        (float*)nullptr, (float*)nullptr, (float*)nullptr);
    // 12. residual1 -> X
    hipLaunchKernelGGL(k_residual1, dim3(14160), dim3(256), 0, stream, e_in, h_in, c_in, proj, s1, X);
    // 13. FF weight transposes
    hipLaunchKernelGGL(k_tcvt, dim3(128, 32), dim3(256), 0, stream, fw1, fw1T, 1024, 4096);
    hipLaunchKernelGGL(k_tcvt, dim3(32, 128), dim3(256), 0, stream, fw2, fw2T, 4096, 1024);
    // 14. norm2 -> xnb bf16
    hipLaunchKernelGGL(k_ln_mod, dim3(ROWS_), dim3(256), 0, stream,
        X, (long)S2_*DIM_, X + (long)TEXT_*DIM_, (long)S2_*DIM_, X + (long)S_MAIN*DIM_, (long)S2_*DIM_,
        s2, ln2w, ln2b, xn, xnb);
    // 15. ff1 (gelu fused, bf16 out)
    hipLaunchKernelGGL(k_bgemm, dim3(32, 28), dim3(256), 0, stream,
        xnb, fw1T, fb1, (float*)nullptr, ffh, ROWS_, FF_, 1024, 2,
        (float*)nullptr, (float*)nullptr, (float*)nullptr);
    // 16. ff2 -> ffo
    hipLaunchKernelGGL(k_bgemm, dim3(8, 28), dim3(256), 0, stream,
        ffh, fw2T, fb2, ffo, (unsigned short*)nullptr, ROWS_, DIM_, FF_, 1,
        (float*)nullptr, (float*)nullptr, (float*)nullptr);
    // 17. final gated residual -> outputs
    hipLaunchKernelGGL(k_final, dim3(14160), dim3(256), 0, stream, X, ffo, s2, out);
}

// Round 6
// 831.764 us; speedup vs baseline: 6.8614x; 1.0557x over previous
//
#include <hip/hip_runtime.h>
#include <hip/hip_bf16.h>
#include <math.h>

#define B_ 2
#define HEADS_ 16
#define HD_ 64
#define DIM_ 1024
#define TEXT_ 226
#define NC_ 8
#define FRAMES_ 4
#define PATCHES_ 384
#define IMG_ 1536
#define S_MAIN 1762
#define S2_ 1770
#define TD_ 512
#define FF_ 4096
#define ROWS_ (B_*S2_)   // 3540
#define VPAD_ 1792       // padded key dim for transposed V

// ---- workspace offsets (float slots) ----
#define OFF_S1   0L
#define OFF_S2   12288L
#define OFF_MISC 24576L
#define OFF_SIM  25600L
#define OFF_IMAP 222208L
#define OFF_AC   418816L
#define OFF_X    435200L
#define OFF_PROJ 4060160L
#define OFF_XN   7685120L
#define OFF_Q    11310080L
#define OFF_K    14935040L
#define OFF_V    18560000L
#define OFF_AO   22184960L
#define OFF_XNB  25809920L   // bf16 activations, 1,812,480 slots -> ends 27,622,400
// overlays (liveness-checked):
//   wqkvT bf16(3072x1024) @ OFF_PROJ      [written step2, read step4]
//   vb    bf16(B,H,64,1792) @ OFF_PROJ    [written step7b, read step8]
//   qb/kb bf16(B,H,S2,64) @ OFF_X         [written step7, read step8; X overwrites step12]
//   woT   bf16(1024x1024) @ OFF_AO+2e6    [step10.5 (ao dead), read step11]
//   fw1T  bf16(4096x1024) @ OFF_V         [step13+, vh dead]
//   fw2T  bf16(1024x4096) @ OFF_AO        [step13+]
//   ffh   bf16(3540x4096) @ OFF_Q         [step15+, qh/kh dead]
//   split-K partials: z0 @ OFF_PROJ, z1 @ OFF_XN (contiguous: PROJ+M*N == XN;
//     xn fp32 dead at step 11 and write-only at step 14)

// ---- output offsets (floats) ----
#define O_H    0L
#define O_E    3145728L
#define O_C    3608576L
#define O_SELI 3624960L
#define O_ISUM 3637248L
#define O_CMAP 3649536L
#define O_XMAP 3661824L

typedef __bf16 bf16x8_t __attribute__((ext_vector_type(8)));
typedef float  f32x4_t  __attribute__((ext_vector_type(4)));

__device__ __forceinline__ unsigned int pack2bf(float a, float b) {
    unsigned short ua = __builtin_bit_cast(unsigned short, (__bf16)a);
    unsigned short ub = __builtin_bit_cast(unsigned short, (__bf16)b);
    return (unsigned int)ua | ((unsigned int)ub << 16);
}
__device__ __forceinline__ int4 packi4(float4 a, float4 b) {
    int4 t;
    t.x = (int)pack2bf(a.x, a.y); t.y = (int)pack2bf(a.z, a.w);
    t.z = (int)pack2bf(b.x, b.y); t.w = (int)pack2bf(b.z, b.w);
    return t;
}

// s1/s2 = silu(temb) @ norm_w + norm_b (k-split x4)
__global__ __launch_bounds__(256) void k_silu_mod(
    const float* __restrict__ temb, const float* __restrict__ w1, const float* __restrict__ b1,
    const float* __restrict__ w2, const float* __restrict__ b2,
    float* __restrict__ s1, float* __restrict__ s2)
{
    int gout = blockIdx.x * 64 + (threadIdx.x & 63);   // < 24576
    int ks = threadIdx.x >> 6;                          // 0..3
    int which = gout / 12288;
    int r = gout % 12288;
    int b = r / 6144, n = r % 6144;
    const float* w = which ? w2 : w1;
    const float* bb = which ? b2 : b1;
    const float* t = temb + b * TD_;
    float acc = 0.f;
    for (int k = ks*128; k < ks*128 + 128; ++k) {
        float tv = t[k];
        float sv = tv / (1.f + __expf(-tv));
        acc += sv * w[(long)k * 6144 + n];
    }
    __shared__ float red[256];
    red[threadIdx.x] = acc; __syncthreads();
    if (ks == 0) {
        int lt = threadIdx.x;
        float v = red[lt] + red[lt+64] + red[lt+128] + red[lt+192] + bb[n];
        (which ? s2 : s1)[b * 6144 + n] = v;
    }
}

// transpose + convert: src (K,N) fp32 -> dst (N,K) bf16
__global__ __launch_bounds__(256) void k_tcvt(
    const float* __restrict__ src, unsigned short* __restrict__ dst, int K, int N)
{
    __shared__ float t[32][33];
    int n0 = blockIdx.x * 32, k0 = blockIdx.y * 32;
    int tx = threadIdx.x & 31, ty = threadIdx.x >> 5;
    #pragma unroll
    for (int i = 0; i < 4; ++i)
        t[ty + 8*i][tx] = src[(size_t)(k0 + ty + 8*i) * N + n0 + tx];
    __syncthreads();
    #pragma unroll
    for (int i = 0; i < 4; ++i) {
        float v = t[tx][ty + 8*i];
        dst[(size_t)(n0 + ty + 8*i) * K + k0 + tx] =
            __builtin_bit_cast(unsigned short, (__bf16)v);
    }
}

// V (B,H,S2,64) fp32 -> vb (B,H,64,VPAD) bf16 transposed
__global__ __launch_bounds__(256) void k_vtrans(
    const float* __restrict__ vh, unsigned short* __restrict__ vb)
{
    int bh = blockIdx.z;
    int d0 = blockIdx.y * 32;
    int s0 = blockIdx.x * 32;
    __shared__ float t[32][33];
    int tx = threadIdx.x & 31, ty = threadIdx.x >> 5;
    const float* src = vh + (size_t)bh * S2_ * 64;
    #pragma unroll
    for (int i = 0; i < 4; ++i) {
        int s = s0 + ty + 8*i; if (s >= S2_) s = S2_ - 1;
        t[ty + 8*i][tx] = src[(size_t)s*64 + d0 + tx];
    }
    __syncthreads();
    unsigned short* dst = vb + (size_t)bh * 64 * VPAD_;
    #pragma unroll
    for (int i = 0; i < 4; ++i) {
        int d = d0 + ty + 8*i;
        dst[(size_t)d * VPAD_ + s0 + tx] =
            __builtin_bit_cast(unsigned short, (__bf16)t[tx][ty + 8*i]);
    }
}

// fused layernorm + adaLN modulation -> fp32 xn AND bf16 xnb
__global__ __launch_bounds__(256) void k_ln_mod(
    const float* pe, long bse, const float* ph, long bsh, const float* pc, long bsc,
    const float* __restrict__ smod, const float* __restrict__ lnw, const float* __restrict__ lnb,
    float* __restrict__ out, unsigned short* __restrict__ outb)
{
    long row = blockIdx.x;
    int b = (int)(row / S2_), s = (int)(row % S2_);
    const float* src; int shiftB, scaleB;
    if (s < TEXT_)       { src = pe + (long)b*bse + (long)s*DIM_;          shiftB = 3072; scaleB = 4096; }
    else if (s < S_MAIN) { src = ph + (long)b*bsh + (long)(s-TEXT_)*DIM_;  shiftB = 0;    scaleB = 1024; }
    else                 { src = pc + (long)b*bsc + (long)(s-S_MAIN)*DIM_; shiftB = 3072; scaleB = 4096; }
    int tid = threadIdx.x;
    int col = tid * 4;
    float4 x = *(const float4*)(src + col);
    float lsum = x.x + x.y + x.z + x.w;
    float lsq  = x.x*x.x + x.y*x.y + x.z*x.z + x.w*x.w;
    __shared__ float r1[256], r2[256];
    r1[tid] = lsum; r2[tid] = lsq; __syncthreads();
    for (int st = 128; st; st >>= 1) {
        if (tid < st) { r1[tid] += r1[tid+st]; r2[tid] += r2[tid+st]; }
        __syncthreads();
    }
    float mu = r1[0] * (1.f / DIM_);
    float var = r2[0] * (1.f / DIM_) - mu * mu;
    float rstd = rsqrtf(var + 1e-5f);
    const float* sb = smod + (long)b * 6144;
    float xs[4] = {x.x, x.y, x.z, x.w};
    float res[4];
    #pragma unroll
    for (int i = 0; i < 4; ++i) {
        int cc = col + i;
        float yy = (xs[i] - mu) * rstd * lnw[cc] + lnb[cc];
        res[i] = yy * (1.f + sb[scaleB + cc]) + sb[shiftB + cc];
    }
    *(float4*)(out + row * DIM_ + col) = make_float4(res[0], res[1], res[2], res[3]);
    uint2 pk;
    pk.x = pack2bf(res[0], res[1]); pk.y = pack2bf(res[2], res[3]);
    *(uint2*)(outb + row * DIM_ + col) = pk;
}

// bf16 MFMA GEMM, double-buffered LDS, optional split-K via gridDim.z.
// C = A(M,K)bf16 @ Wt(N,K)bf16^T over K range [z*kz_len, (z+1)*kz_len).
// mode 0: headed fp32 scatter q/k/v. mode 1: fp32 (+bias; z>0 writes partial at
// out_f + z*M*N). mode 2: gelu->bf16.
__global__ __launch_bounds__(256, 3) void k_bgemm(
    const unsigned short* __restrict__ A, const unsigned short* __restrict__ Wt,
    const float* __restrict__ bias, float* __restrict__ out_f,
    unsigned short* __restrict__ out_b, int M, int N, int K, int kz_len, int mode,
    float* __restrict__ q_out, float* __restrict__ k_out, float* __restrict__ v_out)
{
    __shared__ unsigned short at[2][128*40];
    __shared__ unsigned short bt[2][128*40];
    int tid = threadIdx.x;
    int w = tid >> 6, lane = tid & 63;
    int lr = lane & 15, lh = lane >> 4;
    int wm = w >> 1, wn = w & 1;
    int m0 = blockIdx.y * 128, n0 = blockIdx.x * 128;
    int kbeg = blockIdx.z * kz_len, kend = kbeg + kz_len;

    f32x4_t acc[4][4];
    #pragma unroll
    for (int i = 0; i < 4; ++i)
        #pragma unroll
        for (int j = 0; j < 4; ++j) { acc[i][j][0]=0.f; acc[i][j][1]=0.f; acc[i][j][2]=0.f; acc[i][j][3]=0.f; }

    int srow = tid >> 1, shalf = tid & 1;
    int arow = m0 + srow; if (arow >= M) arow = M - 1;
    const unsigned short* aptr = A + (size_t)arow * K + shalf * 16;
    const unsigned short* bptr = Wt + (size_t)(n0 + srow) * K + shalf * 16;
    int soff = srow * 40 + shalf * 16;

    // prologue: stage tile kbeg into buffer 0
    {
        int4 a0 = *(const int4*)(aptr + kbeg);
        int4 a1 = *(const int4*)(aptr + kbeg + 8);
        int4 b0 = *(const int4*)(bptr + kbeg);
        int4 b1 = *(const int4*)(bptr + kbeg + 8);
        *(int4*)&at[0][soff] = a0; *(int4*)&at[0][soff + 8] = a1;
        *(int4*)&bt[0][soff] = b0; *(int4*)&bt[0][soff + 8] = b1;
    }
    __syncthreads();
    int buf = 0;
    for (int k0 = kbeg; k0 < kend; k0 += 32) {
        bool more = (k0 + 32) < kend;
        int4 na0, na1, nb0, nb1;
        if (more) {
            na0 = *(const int4*)(aptr + k0 + 32);
            na1 = *(const int4*)(aptr + k0 + 40);
            nb0 = *(const int4*)(bptr + k0 + 32);
            nb1 = *(const int4*)(bptr + k0 + 40);
        }
        int4 af[4], bf[4];
        #pragma unroll
        for (int tm = 0; tm < 4; ++tm)
            af[tm] = *(const int4*)&at[buf][(wm*64 + tm*16 + lr)*40 + lh*8];
        #pragma unroll
        for (int tn = 0; tn < 4; ++tn)
            bf[tn] = *(const int4*)&bt[buf][(wn*64 + tn*16 + lr)*40 + lh*8];
        #pragma unroll
        for (int tm = 0; tm < 4; ++tm) {
            bf16x8_t av = __builtin_bit_cast(bf16x8_t, af[tm]);
            #pragma unroll
            for (int tn = 0; tn < 4; ++tn)
                acc[tm][tn] = __builtin_amdgcn_mfma_f32_16x16x32_bf16(
                    av, __builtin_bit_cast(bf16x8_t, bf[tn]), acc[tm][tn], 0, 0, 0);
        }
        if (more) {
            int nb = buf ^ 1;
            *(int4*)&at[nb][soff] = na0; *(int4*)&at[nb][soff + 8] = na1;
            *(int4*)&bt[nb][soff] = nb0; *(int4*)&bt[nb][soff + 8] = nb1;
            __syncthreads();
            buf = nb;
        }
    }
    float* of = out_f;
    if (mode == 1) of += (size_t)blockIdx.z * M * N;
    #pragma unroll
    for (int tm = 0; tm < 4; ++tm) {
        #pragma unroll
        for (int r = 0; r < 4; ++r) {
            int m = m0 + wm*64 + tm*16 + lh*4 + r;
            if (m >= M) continue;
            int b = m / S2_, s = m % S2_;
            #pragma unroll
            for (int tn = 0; tn < 4; ++tn) {
                int n = n0 + wn*64 + tn*16 + lr;
                float v = acc[tm][tn][r];
                if (mode == 0) {
                    int which = n >> 10, c = n & 1023;
                    int hh = c >> 6, d = c & 63;
                    float* dstp = (which == 0) ? q_out : (which == 1) ? k_out : v_out;
                    dstp[(((size_t)b*HEADS_ + hh)*S2_ + s)*64 + d] = v;
                } else if (mode == 1) {
                    of[(size_t)m * N + n] = v + (bias ? bias[n] : 0.f);
                } else {
                    float x = v + bias[n];
                    float u = 0.7978845608028654f * (x + 0.044715f*x*x*x);
                    float g = x / (1.f + __expf(-2.f*u));
                    out_b[(size_t)m * N + n] = __builtin_bit_cast(unsigned short, (__bf16)g);
                }
            }
        }
    }
}

// split-K reduce: dst[i] = dst[i] + p1[i] + bias[i & 1023]  (N == 1024)
__global__ __launch_bounds__(256) void k_kred(
    const float* __restrict__ p1, const float* __restrict__ bias, float* __restrict__ dst)
{
    long i = (long)blockIdx.x*256 + threadIdx.x;
    dst[i] = dst[i] + p1[i] + bias[(int)(i & 1023)];
}

// fp32 tiled GEMM (fixup for argmax-feeding slices).
__global__ __launch_bounds__(256) void k_gemm(
    const float* __restrict__ A, const float* __restrict__ W, const float* __restrict__ bias,
    float* __restrict__ C, int M, int N, int K, int headed, int row_off)
{
    __shared__ float As[16][68];
    __shared__ float Bs[16][68];
    int tid = threadIdx.x;
    int bm = blockIdx.y * 64, bn = blockIdx.x * 64;
    int tr = tid >> 4, tc = tid & 15;
    int ar = tid >> 2, akk = (tid & 3) * 4;
    int bkk = tid >> 4, bn4 = (tid & 15) * 4;
    float acc[4][4] = {{0.f}};
    int garow = bm + ar;
    const float* Aptr = A + (size_t)garow * K + akk;
    const float* Wptr = W + (size_t)bkk * N + bn + bn4;
    for (int k0 = 0; k0 < K; k0 += 16) {
        float4 av = make_float4(0.f, 0.f, 0.f, 0.f);
        if (garow < M) av = *(const float4*)(Aptr + k0);
        As[akk+0][ar] = av.x; As[akk+1][ar] = av.y; As[akk+2][ar] = av.z; As[akk+3][ar] = av.w;
        float4 bv = *(const float4*)(Wptr + (size_t)k0 * N);
        Bs[bkk][bn4+0] = bv.x; Bs[bkk][bn4+1] = bv.y; Bs[bkk][bn4+2] = bv.z; Bs[bkk][bn4+3] = bv.w;
        __syncthreads();
        #pragma unroll
        for (int kk = 0; kk < 16; ++kk) {
            float4 a = *(const float4*)&As[kk][tr*4];
            float4 bq = *(const float4*)&Bs[kk][tc*4];
            float avv[4] = {a.x, a.y, a.z, a.w};
            float bvv[4] = {bq.x, bq.y, bq.z, bq.w};
            #pragma unroll
            for (int i = 0; i < 4; ++i)
                #pragma unroll
                for (int j = 0; j < 4; ++j)
                    acc[i][j] += avv[i] * bvv[j];
        }
        __syncthreads();
    }
    #pragma unroll
    for (int i = 0; i < 4; ++i) {
        int r = bm + tr*4 + i;
        if (r >= M) continue;
        #pragma unroll
        for (int j = 0; j < 4; ++j) {
            int n = bn + tc*4 + j;
            float v = acc[i][j] + (bias ? bias[n] : 0.f);
            if (headed) {
                int rg = r + row_off;
                int b = rg / S2_, s = rg % S2_;
                int hh = n >> 6, d = n & 63;
                C[(((size_t)b*HEADS_ + hh)*S2_ + s)*64 + d] = v;
            } else {
                C[(size_t)(r + row_off) * N + n] = v;
            }
        }
    }
}

// per-head layernorm + RoPE: fp32 in place AND bf16 copies
__global__ __launch_bounds__(256) void k_qk_prep(
    float* qh, float* kh, unsigned short* qbb, unsigned short* kbb,
    const float* __restrict__ nqw, const float* __restrict__ nqb,
    const float* __restrict__ nkw, const float* __restrict__ nkb,
    const float* __restrict__ rc, const float* __restrict__ rs)
{
    int which = blockIdx.y;
    int wid = threadIdx.x >> 6;
    int lane = threadIdx.x & 63;
    long row = (long)blockIdx.x * 4 + wid;
    long s = row % S2_;
    float* base = (which ? kh : qh) + row * 64;
    const float* w  = which ? nkw : nqw;
    const float* bb = which ? nkb : nqb;
    float x = base[lane];
    float sum = x;
    for (int off = 1; off < 64; off <<= 1) sum += __shfl_xor(sum, off, 64);
    float mu = sum * (1.f / 64.f);
    float dx = x - mu;
    float v = dx * dx;
    for (int off = 1; off < 64; off <<= 1) v += __shfl_xor(v, off, 64);
    float rstd = rsqrtf(v * (1.f / 64.f) + 1e-6f);
    float y = dx * rstd * w[lane] + bb[lane];
    if (s >= TEXT_ && s < S_MAIN) {
        long p = s - TEXT_;
        float part = __shfl_xor(y, 1, 64);
        float rot = (lane & 1) ? part : -part;
        y = y * rc[p*64 + lane] + rot * rs[p*64 + lane];
    }
    base[lane] = y;
    (which ? kbb : qbb)[row * 64 + lane] = __builtin_bit_cast(unsigned short, (__bf16)y);
}

// MFMA flash attention, bf16 inputs, no-max softmax, ones-MFMA row sums.
__global__ __launch_bounds__(256) void k_flash(
    const unsigned short* __restrict__ qb, const unsigned short* __restrict__ kb,
    const unsigned short* __restrict__ vb,
    float* __restrict__ outp, int NQ, int q_off, int r0s, int r0e, int r1s, int r1e)
{
    int h = blockIdx.y, b = blockIdx.z;
    int qt = blockIdx.x * 64;
    int tid = threadIdx.x;
    int w = tid >> 6, lane = tid & 63;
    int lr = lane & 15, lh = lane >> 4;
    __shared__ __align__(16) unsigned short kt[64*72];
    __shared__ __align__(16) unsigned short vt[64*72];
    __shared__ __align__(16) unsigned short pbuf[4*16*72];
    unsigned short* pw = pbuf + w*16*72;
    const unsigned short* qbase = qb + (((size_t)b*HEADS_ + h)*S2_ + q_off)*64;
    const unsigned short* kbase = kb + ((size_t)b*HEADS_ + h)*S2_*64;
    const unsigned short* vbase = vb + (size_t)(b*HEADS_ + h)*64*VPAD_;
    int qrow = qt + w*16 + lr; if (qrow >= NQ) qrow = NQ - 1;
    const unsigned short* qsrc = qbase + (size_t)qrow*64 + lh*8;
    bf16x8_t aq0 = __builtin_bit_cast(bf16x8_t, *(const int4*)qsrc);
    bf16x8_t aq1 = __builtin_bit_cast(bf16x8_t, *(const int4*)(qsrc + 32));
    int4 onesi = make_int4(0x3F803F80, 0x3F803F80, 0x3F803F80, 0x3F803F80);
    bf16x8_t bones = __builtin_bit_cast(bf16x8_t, onesi);
    f32x4_t O[4];
    #pragma unroll
    for (int g = 0; g < 4; ++g) { O[g][0]=0.f; O[g][1]=0.f; O[g][2]=0.f; O[g][3]=0.f; }
    f32x4_t Lacc; Lacc[0]=0.f; Lacc[1]=0.f; Lacc[2]=0.f; Lacc[3]=0.f;
    for (int rgi = 0; rgi < 2; ++rgi) {
        int rs = rgi ? r1s : r0s, re = rgi ? r1e : r0e;
        for (int j0 = rs; j0 < re; j0 += 64) {
            int cnt = min(64, re - j0);
            __syncthreads();
            #pragma unroll
            for (int i = 0; i < 2; ++i) {
                int idx = tid + i*256;
                int key = idx >> 3, p8 = idx & 7;
                int krow = j0 + key; if (krow > re - 1) krow = re - 1;
                *(int4*)&kt[key*72 + p8*8] = *(const int4*)(kbase + (size_t)krow*64 + p8*8);
            }
            #pragma unroll
            for (int i = 0; i < 2; ++i) {
                int idx = tid + i*256;
                int d = idx >> 3, p8 = idx & 7;
                *(int4*)&vt[d*72 + p8*8] = *(const int4*)(vbase + (size_t)d*VPAD_ + j0 + p8*8);
            }
            __syncthreads();
            f32x4_t S[4];
            #pragma unroll
            for (int g = 0; g < 4; ++g) {
                const unsigned short* kr = &kt[(16*g + lr)*72 + lh*8];
                bf16x8_t b0 = __builtin_bit_cast(bf16x8_t, *(const int4*)kr);
                bf16x8_t b1 = __builtin_bit_cast(bf16x8_t, *(const int4*)(kr + 32));
                f32x4_t z; z[0]=0.f; z[1]=0.f; z[2]=0.f; z[3]=0.f;
                z = __builtin_amdgcn_mfma_f32_16x16x32_bf16(aq0, b0, z, 0, 0, 0);
                z = __builtin_amdgcn_mfma_f32_16x16x32_bf16(aq1, b1, z, 0, 0, 0);
                S[g] = z;
            }
            #pragma unroll
            for (int g = 0; g < 4; ++g) {
                bool vld = (16*g + lr) < cnt;
                #pragma unroll
                for (int r = 0; r < 4; ++r) {
                    float p = vld ? __expf(S[g][r] * 0.125f) : 0.f;
                    pw[(lh*4 + r)*72 + 16*g + lr] = __builtin_bit_cast(unsigned short, (__bf16)p);
                }
            }
            #pragma unroll
            for (int c = 0; c < 2; ++c) {
                bf16x8_t ap = __builtin_bit_cast(bf16x8_t,
                    *(const int4*)&pw[lr*72 + c*32 + lh*8]);
                Lacc = __builtin_amdgcn_mfma_f32_16x16x32_bf16(ap, bones, Lacc, 0, 0, 0);
                #pragma unroll
                for (int g = 0; g < 4; ++g) {
                    bf16x8_t bv = __builtin_bit_cast(bf16x8_t,
                        *(const int4*)&vt[(16*g + lr)*72 + c*32 + lh*8]);
                    O[g] = __builtin_amdgcn_mfma_f32_16x16x32_bf16(ap, bv, O[g], 0, 0, 0);
                }
            }
        }
    }
    #pragma unroll
    for (int r = 0; r < 4; ++r) {
        float inv = 1.f / Lacc[r];
        int gq = qt + w*16 + lh*4 + r;
        if (gq < NQ) {
            float* o = outp + (((size_t)b*HEADS_ + h)*NQ + gq)*64 + lr;
            #pragma unroll
            for (int g = 0; g < 4; ++g) o[16*g] = O[g][r] * inv;
        }
    }
}

__global__ __launch_bounds__(256) void k_head_score(const float* __restrict__ ao, float* __restrict__ score)
{
    int h = blockIdx.x, tid = threadIdx.x;
    const float* base = ao + (((long)HEADS_ + h)*S_MAIN + TEXT_)*64;
    float sA = 0.f, sB = 0.f;
    for (int p = tid; p < IMG_; p += 256) {
        const float* r = base + (long)p*64;
        float mm = 0.f;
        for (int d = 0; d < 64; d += 4) {
            float4 v = *(const float4*)(r + d);
            mm += v.x + v.y + v.z + v.w;
        }
        mm *= (1.f / 64.f);
        sA += mm; sB += mm*mm;
    }
    __shared__ float r1[256], r2[256];
    r1[tid] = sA; r2[tid] = sB; __syncthreads();
    for (int st = 128; st; st >>= 1) {
        if (tid < st) { r1[tid] += r1[tid+st]; r2[tid] += r2[tid+st]; }
        __syncthreads();
    }
    if (tid == 0) {
        float mean = r1[0] / IMG_, ms = r2[0] / IMG_;
        score[h] = sqrtf(fmaxf(ms - mean*mean, 0.f));
    }
}

__global__ void k_top4(const float* __restrict__ score, int* __restrict__ sel)
{
    if (threadIdx.x == 0 && blockIdx.x == 0) {
        int used = 0;
        for (int k = 0; k < 4; ++k) {
            float best = -INFINITY; int bi = 0;
            for (int h2 = 0; h2 < 16; ++h2) {
                if (used & (1 << h2)) continue;
                if (score[h2] > best) { best = score[h2]; bi = h2; }
            }
            used |= 1 << bi; sel[k] = bi;
        }
    }
}

__global__ __launch_bounds__(512) void k_sim(
    const float* __restrict__ qh, const float* __restrict__ kh,
    float* __restrict__ sim, int* __restrict__ selvis)
{
    int blk = blockIdx.x;    // (h*8+t)*4+f
    int h = blk >> 5, t = (blk >> 2) & 7, f = blk & 3;
    int tid = threadIdx.x;
    __shared__ float ckv[64];
    if (tid < 64) ckv[tid] = kh[(((long)HEADS_ + h)*S2_ + S_MAIN + t)*64 + tid];
    __syncthreads();
    float val = -INFINITY; int idx = 0x7fffffff;
    if (tid < PATCHES_) {
        const float* qrow = qh + (((long)HEADS_ + h)*S2_ + TEXT_ + f*PATCHES_ + tid)*64;
        float acc = 0.f;
        for (int d = 0; d < 64; d += 4) {
            float4 qv = *(const float4*)(qrow + d);
            acc += qv.x*ckv[d] + qv.y*ckv[d+1] + qv.z*ckv[d+2] + qv.w*ckv[d+3];
        }
        sim[((long)h*NC_ + t)*IMG_ + f*PATCHES_ + tid] = acc;
        val = acc; idx = tid;
    }
    __shared__ float sv[512]; __shared__ int si[512];
    sv[tid] = val; si[tid] = idx; __syncthreads();
    for (int st = 256; st; st >>= 1) {
        if (tid < st) {
            float v2 = sv[tid+st]; int i2 = si[tid+st];
            if (v2 > sv[tid] || (v2 == sv[tid] && i2 < si[tid])) { sv[tid] = v2; si[tid] = i2; }
        }
        __syncthreads();
    }
    if (tid == 0) selvis[blk] = si[0];
}

__global__ __launch_bounds__(256) void k_cross(const float* __restrict__ sim, float* __restrict__ out)
{
    int i = blockIdx.x*256 + threadIdx.x;   // < 12288
    int c = i / IMG_, p = i % IMG_;
    float acc = 0.f;
    for (int h = 0; h < 16; ++h) acc += sim[((long)h*NC_ + c)*IMG_ + p];
    out[O_XMAP + i] = acc * (1.f / 16.f);
}

__global__ __launch_bounds__(256) void k_concept_maps(
    const float* __restrict__ ac, const float* __restrict__ ao, float* __restrict__ out)
{
    int i = blockIdx.x*256 + threadIdx.x;   // < 12288
    int c = i / IMG_, p = i % IMG_;
    float acc = 0.f;
    for (int h = 0; h < 16; ++h) {
        const float* a = ac + (((long)HEADS_ + h)*NC_ + c)*64;
        const float* g = ao + (((long)HEADS_ + h)*S_MAIN + TEXT_ + p)*64;
        for (int d = 0; d < 64; d += 4) {
            float4 av = *(const float4*)(a + d);
            float4 gv = *(const float4*)(g + d);
            acc += av.x*gv.x + av.y*gv.y + av.z*gv.z + av.w*gv.w;
        }
    }
    out[O_CMAP + i] = acc;
}

__global__ void k_imap_raw(const float* __restrict__ ao, const int* __restrict__ selvis,
                           float* __restrict__ imap)
{
    int blk = blockIdx.x;   // (h*8+t)*4+f
    int h = blk >> 5, t = (blk >> 2) & 7, f = blk & 3;
    int tid = threadIdx.x;  // 384
    __shared__ float sel[64];
    int pstar = selvis[blk];
    if (tid < 64) sel[tid] = ao[(((long)HEADS_ + h)*S_MAIN + TEXT_ + f*PATCHES_ + pstar)*64 + tid];
    __syncthreads();
    const float* g = ao + (((long)HEADS_ + h)*S_MAIN + TEXT_ + f*PATCHES_ + tid)*64;
    float acc = 0.f;
    for (int d = 0; d < 64; d += 4) {
        float4 gv = *(const float4*)(g + d);
        acc += gv.x*sel[d] + gv.y*sel[d+1] + gv.z*sel[d+2] + gv.w*sel[d+3];
    }
    imap[((long)h*NC_ + t)*IMG_ + f*PATCHES_ + tid] = acc;
}

__global__ __launch_bounds__(256) void k_imap_norm(float* __restrict__ imap)
{
    int i = blockIdx.x*256 + threadIdx.x;   // < 24576
    int h = i / IMG_, fp = i % IMG_;
    float v[8]; float mu = 0.f;
    #pragma unroll
    for (int t = 0; t < 8; ++t) { v[t] = imap[((long)h*NC_ + t)*IMG_ + fp]; mu += v[t]; }
    mu *= 0.125f;
    float var = 0.f;
    #pragma unroll
    for (int t = 0; t < 8; ++t) var += (v[t]-mu)*(v[t]-mu);
    float sd = sqrtf(var * (1.f / 7.f));
    float inv = 1.f / (sd + 1e-6f);
    #pragma unroll
    for (int t = 0; t < 8; ++t) imap[((long)h*NC_ + t)*IMG_ + fp] = (v[t]-mu)*inv;
}

__global__ __launch_bounds__(256) void k_imap_reduce(
    const float* __restrict__ imap, const int* __restrict__ sel, float* __restrict__ out)
{
    int i = blockIdx.x*256 + threadIdx.x;   // < 12288
    int t = i / IMG_, fp = i % IMG_;
    float sum = 0.f;
    for (int h = 0; h < 16; ++h) sum += imap[((long)h*NC_ + t)*IMG_ + fp];
    float ss = 0.f;
    for (int k = 0; k < 4; ++k) { int h = sel[k]; ss += imap[((long)h*NC_ + t)*IMG_ + fp]; }
    out[O_ISUM + i] = sum;
    out[O_SELI + i] = ss * 0.25f;
}

__global__ __launch_bounds__(256) void k_merge(
    const float* __restrict__ ao, const float* __restrict__ ac, unsigned short* __restrict__ xo)
{
    long i = (long)blockIdx.x*256 + threadIdx.x;   // < 3,624,960
    int col = (int)(i & 1023);
    long row = i >> 10;
    int b = (int)(row / S2_), s = (int)(row % S2_);
    int h = col >> 6, d = col & 63;
    float v;
    if (s < S_MAIN) v = ao[(((long)b*HEADS_ + h)*S_MAIN + s)*64 + d];
    else            v = ac[(((long)b*HEADS_ + h)*NC_ + (s - S_MAIN))*64 + d];
    xo[i] = __builtin_bit_cast(unsigned short, (__bf16)v);
}

__global__ __launch_bounds__(256) void k_residual1(
    const float* __restrict__ pe, const float* __restrict__ ph, const float* __restrict__ pc,
    const float* __restrict__ proj, const float* __restrict__ s1, float* __restrict__ X)
{
    long i = (long)blockIdx.x*256 + threadIdx.x;
    int col = (int)(i & 1023);
    long row = i >> 10;
    int b = (int)(row / S2_), s = (int)(row % S2_);
    const float* sb = s1 + (long)b * 6144;
    float orig, gate;
    if (s < TEXT_)       { orig = pe[((long)b*TEXT_ + s)*DIM_ + col];            gate = sb[5120 + col]; }
    else if (s < S_MAIN) { orig = ph[((long)b*IMG_ + (s-TEXT_))*DIM_ + col];     gate = sb[2048 + col]; }
    else                 { orig = pc[((long)b*NC_ + (s-S_MAIN))*DIM_ + col];     gate = sb[5120 + col]; }
    X[i] = orig + gate * proj[i];
}

__global__ __launch_bounds__(256) void k_final(
    const float* __restrict__ X, const float* __restrict__ ffo,
    const float* __restrict__ s2, float* __restrict__ out)
{
    long i = (long)blockIdx.x*256 + threadIdx.x;
    int col = (int)(i & 1023);
    long row = i >> 10;
    int b = (int)(row / S2_), s = (int)(row % S2_);
    const float* sb = s2 + (long)b * 6144;
    float gate; float* o;
    if (s < TEXT_)       { gate = sb[5120 + col]; o = out + O_E + ((long)b*TEXT_ + s)*DIM_ + col; }
    else if (s < S_MAIN) { gate = sb[2048 + col]; o = out + O_H + ((long)b*IMG_ + (s-TEXT_))*DIM_ + col; }
    else                 { gate = sb[5120 + col]; o = out + O_C + ((long)b*NC_ + (s-S_MAIN))*DIM_ + col; }
    *o = X[i] + gate * ffo[i];
}

extern "C" void kernel_launch(void* const* d_in, const int* in_sizes, int n_in,
                              void* d_out, int out_size, void* d_ws, size_t ws_size,
                              hipStream_t stream)
{
    (void)in_sizes; (void)n_in; (void)out_size; (void)ws_size;
    const float* h_in = (const float*)d_in[0];
    const float* e_in = (const float*)d_in[1];
    const float* c_in = (const float*)d_in[2];
    const float* temb = (const float*)d_in[3];
    const float* rcos = (const float*)d_in[4];
    const float* rsin = (const float*)d_in[5];
    const float* n1w  = (const float*)d_in[6];
    const float* n1b  = (const float*)d_in[7];
    const float* ln1w = (const float*)d_in[8];
    const float* ln1b = (const float*)d_in[9];
    const float* n2w  = (const float*)d_in[10];
    const float* n2b  = (const float*)d_in[11];
    const float* ln2w = (const float*)d_in[12];
    const float* ln2b = (const float*)d_in[13];
    const float* wq   = (const float*)d_in[14];
    const float* wk   = (const float*)d_in[15];
    const float* wv   = (const float*)d_in[16];
    const float* nqw  = (const float*)d_in[17];
    const float* nqb  = (const float*)d_in[18];
    const float* nkw  = (const float*)d_in[19];
    const float* nkb  = (const float*)d_in[20];
    const float* wo   = (const float*)d_in[21];
    const float* bo   = (const float*)d_in[22];
    const float* fw1  = (const float*)d_in[23];
    const float* fb1  = (const float*)d_in[24];
    const float* fw2  = (const float*)d_in[25];
    const float* fb2  = (const float*)d_in[26];

    float* ws  = (float*)d_ws;
    float* out = (float*)d_out;
    float* s1   = ws + OFF_S1;
    float* s2   = ws + OFF_S2;
    float* score  = ws + OFF_MISC;
    int*   selh   = (int*)(ws + OFF_MISC + 16);
    int*   selvis = (int*)(ws + OFF_MISC + 32);
    float* sim  = ws + OFF_SIM;
    float* imap = ws + OFF_IMAP;
    float* ac   = ws + OFF_AC;
    float* X    = ws + OFF_X;
    float* proj = ws + OFF_PROJ;
    float* xn   = ws + OFF_XN;
    float* qh   = ws + OFF_Q;
    float* kh   = ws + OFF_K;
    float* vh   = ws + OFF_V;
    float* ao   = ws + OFF_AO;
    float* ffo  = proj;
    unsigned short* xnb   = (unsigned short*)(ws + OFF_XNB);
    unsigned short* wqkvT = (unsigned short*)(ws + OFF_PROJ);
    unsigned short* vb    = (unsigned short*)(ws + OFF_PROJ);        // after QKV gemm
    unsigned short* qbb   = (unsigned short*)(ws + OFF_X);
    unsigned short* kbb   = qbb + (size_t)B_*HEADS_*S2_*64;
    unsigned short* woT   = (unsigned short*)(ws + OFF_AO + 2000000);
    unsigned short* fw1T  = (unsigned short*)(ws + OFF_V);
    unsigned short* fw2T  = (unsigned short*)(ws + OFF_AO);
    unsigned short* ffh   = (unsigned short*)(ws + OFF_Q);

    // 1. adaLN modulation vectors
    hipLaunchKernelGGL(k_silu_mod, dim3(384), dim3(256), 0, stream, temb, n1w, n1b, n2w, n2b, s1, s2);
    // 2. QKV weight transposes to bf16
    hipLaunchKernelGGL(k_tcvt, dim3(32, 32), dim3(256), 0, stream, wq, wqkvT,               1024, 1024);
    hipLaunchKernelGGL(k_tcvt, dim3(32, 32), dim3(256), 0, stream, wk, wqkvT + 1024*1024,   1024, 1024);
    hipLaunchKernelGGL(k_tcvt, dim3(32, 32), dim3(256), 0, stream, wv, wqkvT + 2*1024*1024, 1024, 1024);
    // 3. norm1 + modulation -> xn fp32 + xnb bf16
    hipLaunchKernelGGL(k_ln_mod, dim3(ROWS_), dim3(256), 0, stream,
        e_in, (long)TEXT_*DIM_, h_in, (long)IMG_*DIM_, c_in, (long)NC_*DIM_, s1, ln1w, ln1b, xn, xnb);
    // 4. fused QKV bf16 GEMM, headed fp32 scatter
    hipLaunchKernelGGL(k_bgemm, dim3(24, 28, 1), dim3(256), 0, stream,
        xnb, wqkvT, (const float*)nullptr, (float*)nullptr, (unsigned short*)nullptr,
        ROWS_, 3072, 1024, 1024, 0, qh, kh, vh);
    // 5-6. fp32 fixups for argmax-feeding slices
    hipLaunchKernelGGL(k_gemm, dim3(16, 24), dim3(256), 0, stream,
        xn + (long)(S2_ + TEXT_)*DIM_, wq, (const float*)nullptr, qh, IMG_, DIM_, DIM_, 1, S2_ + TEXT_);
    hipLaunchKernelGGL(k_gemm, dim3(16, 1), dim3(256), 0, stream,
        xn + (long)(S2_ + S_MAIN)*DIM_, wk, (const float*)nullptr, kh, NC_, DIM_, DIM_, 1, S2_ + S_MAIN);
    // 7. QK layernorm + RoPE (fp32 in place + bf16 qb/kb); V transpose to bf16
    hipLaunchKernelGGL(k_qk_prep, dim3(14160, 2), dim3(256), 0, stream,
        qh, kh, qbb, kbb, nqw, nqb, nkw, nkb, rcos, rsin);
    hipLaunchKernelGGL(k_vtrans, dim3(56, 2, 32), dim3(256), 0, stream, vh, vb);
    // 8. attentions (bf16 inputs)
    hipLaunchKernelGGL(k_flash, dim3(28, 16, 2), dim3(256), 0, stream,
        qbb, kbb, vb, ao, S_MAIN, 0, 0, S_MAIN, 0, 0);
    hipLaunchKernelGGL(k_flash, dim3(1, 16, 2), dim3(256), 0, stream,
        qbb, kbb, vb, ac, NC_, S_MAIN, S_MAIN, S2_, TEXT_, S_MAIN);
    // 9. maps (batch 1)
    hipLaunchKernelGGL(k_head_score, dim3(16), dim3(256), 0, stream, ao, score);
    hipLaunchKernelGGL(k_top4, dim3(1), dim3(64), 0, stream, score, selh);
    hipLaunchKernelGGL(k_sim, dim3(512), dim3(512), 0, stream, qh, kh, sim, selvis);
    hipLaunchKernelGGL(k_cross, dim3(48), dim3(256), 0, stream, sim, out);
    hipLaunchKernelGGL(k_concept_maps, dim3(48), dim3(256), 0, stream, ac, ao, out);
    hipLaunchKernelGGL(k_imap_raw, dim3(512), dim3(384), 0, stream, ao, selvis, imap);
    hipLaunchKernelGGL(k_imap_norm, dim3(96), dim3(256), 0, stream, imap);
    hipLaunchKernelGGL(k_imap_reduce, dim3(48), dim3(256), 0, stream, imap, selh, out);
    // 10. merge -> xnb bf16; then wo transpose into dead ao region
    hipLaunchKernelGGL(k_merge, dim3(14160), dim3(256), 0, stream, ao, ac, xnb);
    hipLaunchKernelGGL(k_tcvt, dim3(32, 32), dim3(256), 0, stream, wo, woT, 1024, 1024);
    // 11. wo GEMM -> proj, split-K x2 (z1 partial lands at OFF_XN), then reduce+bias
    hipLaunchKernelGGL(k_bgemm, dim3(8, 28, 2), dim3(256), 0, stream,
        xnb, woT, (const float*)nullptr, proj, (unsigned short*)nullptr, ROWS_, DIM_, 1024, 512, 1,
        (float*)nullptr, (float*)nullptr, (float*)nullptr);
    hipLaunchKernelGGL(k_kred, dim3(14160), dim3(256), 0, stream,
        proj + (size_t)ROWS_*DIM_, bo, proj);
    // 12. residual1 -> X
    hipLaunchKernelGGL(k_residual1, dim3(14160), dim3(256), 0, stream, e_in, h_in, c_in, proj, s1, X);
    // 13. FF weight transposes
    hipLaunchKernelGGL(k_tcvt, dim3(128, 32), dim3(256), 0, stream, fw1, fw1T, 1024, 4096);
    hipLaunchKernelGGL(k_tcvt, dim3(32, 128), dim3(256), 0, stream, fw2, fw2T, 4096, 1024);
    // 14. norm2 -> xnb bf16 (xn fp32 write is dead; region reused by ff2 partial)
    hipLaunchKernelGGL(k_ln_mod, dim3(ROWS_), dim3(256), 0, stream,
        X, (long)S2_*DIM_, X + (long)TEXT_*DIM_, (long)S2_*DIM_, X + (long)S_MAIN*DIM_, (long)S2_*DIM_,
        s2, ln2w, ln2b, xn, xnb);
    // 15. ff1 (gelu fused, bf16 out)
    hipLaunchKernelGGL(k_bgemm, dim3(32, 28, 1), dim3(256), 0, stream,
        xnb, fw1T, fb1, (float*)nullptr, ffh, ROWS_, FF_, 1024, 1024, 2,
        (float*)nullptr, (float*)nullptr, (float*)nullptr);
    // 16. ff2 -> ffo, split-K x2 (z1 partial at OFF_XN), then reduce+bias
    hipLaunchKernelGGL(k_bgemm, dim3(8, 28, 2), dim3(256), 0, stream,
        ffh, fw2T, (const float*)nullptr, ffo, (unsigned short*)nullptr, ROWS_, DIM_, FF_, 2048, 1,
        (float*)nullptr, (float*)nullptr, (float*)nullptr);
    hipLaunchKernelGGL(k_kred, dim3(14160), dim3(256), 0, stream,
        ffo + (size_t)ROWS_*DIM_, fb2, ffo);
    // 17. final gated residual -> outputs
    hipLaunchKernelGGL(k_final, dim3(14160), dim3(256), 0, stream, X, ffo, s2, out);
}

// Round 7
// 764.635 us; speedup vs baseline: 7.4638x; 1.0878x over previous
//
#include <hip/hip_runtime.h>
#include <hip/hip_bf16.h>
#include <math.h>

#define B_ 2
#define HEADS_ 16
#define HD_ 64
#define DIM_ 1024
#define TEXT_ 226
#define NC_ 8
#define FRAMES_ 4
#define PATCHES_ 384
#define IMG_ 1536
#define S_MAIN 1762
#define S2_ 1770
#define TD_ 512
#define FF_ 4096
#define ROWS_ (B_*S2_)   // 3540
#define VPAD_ 1792       // padded key dim for transposed V

// ---- workspace offsets (float slots) ----
#define OFF_S1   0L
#define OFF_S2   12288L
#define OFF_MISC 24576L
#define OFF_SIM  25600L
#define OFF_IMAP 222208L
#define OFF_AC   418816L
#define OFF_X    435200L
#define OFF_PROJ 4060160L
#define OFF_XN   7685120L
#define OFF_Q    11310080L
#define OFF_K    14935040L
#define OFF_V    18560000L
#define OFF_AO   22184960L
#define OFF_XNB  25809920L
// overlays (liveness-checked):
//   wqkvT bf16(3072x1024) @ OFF_PROJ   [step2 -> step4]
//   vb    bf16(B,H,64,1792) @ OFF_PROJ [step7b -> step8]
//   qb/kb bf16(B,H,S2,64) @ OFF_X      [step7 -> step8; X overwrites step12]
//   fixup partials fp32 2x(1536x1024) @ OFF_AO [step5 -> step5b; ao written step8]
//   woT   bf16(1024x1024) @ OFF_AO+2e6 [step10.5 -> step11]
//   fw1T  bf16(4096x1024) @ OFF_V      [step13+]
//   fw2T  bf16(1024x4096) @ OFF_AO     [step13+]
//   ffh   bf16(3540x4096) @ OFF_Q      [step15+]
//   split-K partials: z0 @ OFF_PROJ, z1 @ OFF_XN (contiguous)

// ---- output offsets (floats) ----
#define O_H    0L
#define O_E    3145728L
#define O_C    3608576L
#define O_SELI 3624960L
#define O_ISUM 3637248L
#define O_CMAP 3649536L
#define O_XMAP 3661824L

typedef __bf16 bf16x8_t __attribute__((ext_vector_type(8)));
typedef float  f32x4_t  __attribute__((ext_vector_type(4)));

__device__ __forceinline__ unsigned int pack2bf(float a, float b) {
    unsigned short ua = __builtin_bit_cast(unsigned short, (__bf16)a);
    unsigned short ub = __builtin_bit_cast(unsigned short, (__bf16)b);
    return (unsigned int)ua | ((unsigned int)ub << 16);
}

// s1/s2 = silu(temb) @ norm_w + norm_b (k-split x4)
__global__ __launch_bounds__(256) void k_silu_mod(
    const float* __restrict__ temb, const float* __restrict__ w1, const float* __restrict__ b1,
    const float* __restrict__ w2, const float* __restrict__ b2,
    float* __restrict__ s1, float* __restrict__ s2)
{
    int gout = blockIdx.x * 64 + (threadIdx.x & 63);   // < 24576
    int ks = threadIdx.x >> 6;
    int which = gout / 12288;
    int r = gout % 12288;
    int b = r / 6144, n = r % 6144;
    const float* w = which ? w2 : w1;
    const float* bb = which ? b2 : b1;
    const float* t = temb + b * TD_;
    float acc = 0.f;
    for (int k = ks*128; k < ks*128 + 128; ++k) {
        float tv = t[k];
        float sv = tv / (1.f + __expf(-tv));
        acc += sv * w[(long)k * 6144 + n];
    }
    __shared__ float red[256];
    red[threadIdx.x] = acc; __syncthreads();
    if (ks == 0) {
        int lt = threadIdx.x;
        float v = red[lt] + red[lt+64] + red[lt+128] + red[lt+192] + bb[n];
        (which ? s2 : s1)[b * 6144 + n] = v;
    }
}

// transpose + convert: src (K,N) fp32 -> dst (N,K) bf16
__global__ __launch_bounds__(256) void k_tcvt(
    const float* __restrict__ src, unsigned short* __restrict__ dst, int K, int N)
{
    __shared__ float t[32][33];
    int n0 = blockIdx.x * 32, k0 = blockIdx.y * 32;
    int tx = threadIdx.x & 31, ty = threadIdx.x >> 5;
    #pragma unroll
    for (int i = 0; i < 4; ++i)
        t[ty + 8*i][tx] = src[(size_t)(k0 + ty + 8*i) * N + n0 + tx];
    __syncthreads();
    #pragma unroll
    for (int i = 0; i < 4; ++i) {
        float v = t[tx][ty + 8*i];
        dst[(size_t)(n0 + ty + 8*i) * K + k0 + tx] =
            __builtin_bit_cast(unsigned short, (__bf16)v);
    }
}

// batched QKV transpose (z selects wq/wk/wv), 1024x1024 each
__global__ __launch_bounds__(256) void k_tcvt_qkv(
    const float* __restrict__ wq, const float* __restrict__ wk, const float* __restrict__ wv,
    unsigned short* __restrict__ dst)
{
    const float* src = (blockIdx.z == 0) ? wq : (blockIdx.z == 1) ? wk : wv;
    unsigned short* d = dst + (size_t)blockIdx.z * 1024 * 1024;
    __shared__ float t[32][33];
    int n0 = blockIdx.x * 32, k0 = blockIdx.y * 32;
    int tx = threadIdx.x & 31, ty = threadIdx.x >> 5;
    #pragma unroll
    for (int i = 0; i < 4; ++i)
        t[ty + 8*i][tx] = src[(size_t)(k0 + ty + 8*i) * 1024 + n0 + tx];
    __syncthreads();
    #pragma unroll
    for (int i = 0; i < 4; ++i) {
        float v = t[tx][ty + 8*i];
        d[(size_t)(n0 + ty + 8*i) * 1024 + k0 + tx] =
            __builtin_bit_cast(unsigned short, (__bf16)v);
    }
}

// V (B,H,S2,64) fp32 -> vb (B,H,64,VPAD) bf16 transposed
__global__ __launch_bounds__(256) void k_vtrans(
    const float* __restrict__ vh, unsigned short* __restrict__ vb)
{
    int bh = blockIdx.z;
    int d0 = blockIdx.y * 32;
    int s0 = blockIdx.x * 32;
    __shared__ float t[32][33];
    int tx = threadIdx.x & 31, ty = threadIdx.x >> 5;
    const float* src = vh + (size_t)bh * S2_ * 64;
    #pragma unroll
    for (int i = 0; i < 4; ++i) {
        int s = s0 + ty + 8*i; if (s >= S2_) s = S2_ - 1;
        t[ty + 8*i][tx] = src[(size_t)s*64 + d0 + tx];
    }
    __syncthreads();
    unsigned short* dst = vb + (size_t)bh * 64 * VPAD_;
    #pragma unroll
    for (int i = 0; i < 4; ++i) {
        int d = d0 + ty + 8*i;
        dst[(size_t)d * VPAD_ + s0 + tx] =
            __builtin_bit_cast(unsigned short, (__bf16)t[tx][ty + 8*i]);
    }
}

// fused layernorm + adaLN modulation -> optional fp32 out AND bf16 outb
__global__ __launch_bounds__(256) void k_ln_mod(
    const float* pe, long bse, const float* ph, long bsh, const float* pc, long bsc,
    const float* __restrict__ smod, const float* __restrict__ lnw, const float* __restrict__ lnb,
    float* __restrict__ out, unsigned short* __restrict__ outb)
{
    long row = blockIdx.x;
    int b = (int)(row / S2_), s = (int)(row % S2_);
    const float* src; int shiftB, scaleB;
    if (s < TEXT_)       { src = pe + (long)b*bse + (long)s*DIM_;          shiftB = 3072; scaleB = 4096; }
    else if (s < S_MAIN) { src = ph + (long)b*bsh + (long)(s-TEXT_)*DIM_;  shiftB = 0;    scaleB = 1024; }
    else                 { src = pc + (long)b*bsc + (long)(s-S_MAIN)*DIM_; shiftB = 3072; scaleB = 4096; }
    int tid = threadIdx.x;
    int col = tid * 4;
    float4 x = *(const float4*)(src + col);
    float lsum = x.x + x.y + x.z + x.w;
    float lsq  = x.x*x.x + x.y*x.y + x.z*x.z + x.w*x.w;
    __shared__ float r1[256], r2[256];
    r1[tid] = lsum; r2[tid] = lsq; __syncthreads();
    for (int st = 128; st; st >>= 1) {
        if (tid < st) { r1[tid] += r1[tid+st]; r2[tid] += r2[tid+st]; }
        __syncthreads();
    }
    float mu = r1[0] * (1.f / DIM_);
    float var = r2[0] * (1.f / DIM_) - mu * mu;
    float rstd = rsqrtf(var + 1e-5f);
    const float* sb = smod + (long)b * 6144;
    float xs[4] = {x.x, x.y, x.z, x.w};
    float res[4];
    #pragma unroll
    for (int i = 0; i < 4; ++i) {
        int cc = col + i;
        float yy = (xs[i] - mu) * rstd * lnw[cc] + lnb[cc];
        res[i] = yy * (1.f + sb[scaleB + cc]) + sb[shiftB + cc];
    }
    if (out)
        *(float4*)(out + row * DIM_ + col) = make_float4(res[0], res[1], res[2], res[3]);
    uint2 pk;
    pk.x = pack2bf(res[0], res[1]); pk.y = pack2bf(res[2], res[3]);
    *(uint2*)(outb + row * DIM_ + col) = pk;
}

// bf16 MFMA GEMM, double-buffered LDS, optional split-K via gridDim.z.
__global__ __launch_bounds__(256, 3) void k_bgemm(
    const unsigned short* __restrict__ A, const unsigned short* __restrict__ Wt,
    const float* __restrict__ bias, float* __restrict__ out_f,
    unsigned short* __restrict__ out_b, int M, int N, int K, int kz_len, int mode,
    float* __restrict__ q_out, float* __restrict__ k_out, float* __restrict__ v_out)
{
    __shared__ unsigned short at[2][128*40];
    __shared__ unsigned short bt[2][128*40];
    int tid = threadIdx.x;
    int w = tid >> 6, lane = tid & 63;
    int lr = lane & 15, lh = lane >> 4;
    int wm = w >> 1, wn = w & 1;
    int m0 = blockIdx.y * 128, n0 = blockIdx.x * 128;
    int kbeg = blockIdx.z * kz_len, kend = kbeg + kz_len;

    f32x4_t acc[4][4];
    #pragma unroll
    for (int i = 0; i < 4; ++i)
        #pragma unroll
        for (int j = 0; j < 4; ++j) { acc[i][j][0]=0.f; acc[i][j][1]=0.f; acc[i][j][2]=0.f; acc[i][j][3]=0.f; }

    int srow = tid >> 1, shalf = tid & 1;
    int arow = m0 + srow; if (arow >= M) arow = M - 1;
    const unsigned short* aptr = A + (size_t)arow * K + shalf * 16;
    const unsigned short* bptr = Wt + (size_t)(n0 + srow) * K + shalf * 16;
    int soff = srow * 40 + shalf * 16;

    {
        int4 a0 = *(const int4*)(aptr + kbeg);
        int4 a1 = *(const int4*)(aptr + kbeg + 8);
        int4 b0 = *(const int4*)(bptr + kbeg);
        int4 b1 = *(const int4*)(bptr + kbeg + 8);
        *(int4*)&at[0][soff] = a0; *(int4*)&at[0][soff + 8] = a1;
        *(int4*)&bt[0][soff] = b0; *(int4*)&bt[0][soff + 8] = b1;
    }
    __syncthreads();
    int buf = 0;
    for (int k0 = kbeg; k0 < kend; k0 += 32) {
        bool more = (k0 + 32) < kend;
        int4 na0, na1, nb0, nb1;
        if (more) {
            na0 = *(const int4*)(aptr + k0 + 32);
            na1 = *(const int4*)(aptr + k0 + 40);
            nb0 = *(const int4*)(bptr + k0 + 32);
            nb1 = *(const int4*)(bptr + k0 + 40);
        }
        int4 af[4], bf[4];
        #pragma unroll
        for (int tm = 0; tm < 4; ++tm)
            af[tm] = *(const int4*)&at[buf][(wm*64 + tm*16 + lr)*40 + lh*8];
        #pragma unroll
        for (int tn = 0; tn < 4; ++tn)
            bf[tn] = *(const int4*)&bt[buf][(wn*64 + tn*16 + lr)*40 + lh*8];
        #pragma unroll
        for (int tm = 0; tm < 4; ++tm) {
            bf16x8_t av = __builtin_bit_cast(bf16x8_t, af[tm]);
            #pragma unroll
            for (int tn = 0; tn < 4; ++tn)
                acc[tm][tn] = __builtin_amdgcn_mfma_f32_16x16x32_bf16(
                    av, __builtin_bit_cast(bf16x8_t, bf[tn]), acc[tm][tn], 0, 0, 0);
        }
        if (more) {
            int nb = buf ^ 1;
            *(int4*)&at[nb][soff] = na0; *(int4*)&at[nb][soff + 8] = na1;
            *(int4*)&bt[nb][soff] = nb0; *(int4*)&bt[nb][soff + 8] = nb1;
            __syncthreads();
            buf = nb;
        }
    }
    float* of = out_f;
    if (mode == 1) of += (size_t)blockIdx.z * M * N;
    #pragma unroll
    for (int tm = 0; tm < 4; ++tm) {
        #pragma unroll
        for (int r = 0; r < 4; ++r) {
            int m = m0 + wm*64 + tm*16 + lh*4 + r;
            if (m >= M) continue;
            int b = m / S2_, s = m % S2_;
            #pragma unroll
            for (int tn = 0; tn < 4; ++tn) {
                int n = n0 + wn*64 + tn*16 + lr;
                float v = acc[tm][tn][r];
                if (mode == 0) {
                    int which = n >> 10, c = n & 1023;
                    int hh = c >> 6, d = c & 63;
                    float* dstp = (which == 0) ? q_out : (which == 1) ? k_out : v_out;
                    dstp[(((size_t)b*HEADS_ + hh)*S2_ + s)*64 + d] = v;
                } else if (mode == 1) {
                    of[(size_t)m * N + n] = v + (bias ? bias[n] : 0.f);
                } else {
                    float x = v + bias[n];
                    float u = 0.7978845608028654f * (x + 0.044715f*x*x*x);
                    float g = x / (1.f + __expf(-2.f*u));
                    out_b[(size_t)m * N + n] = __builtin_bit_cast(unsigned short, (__bf16)g);
                }
            }
        }
    }
}

// fp32 tiled GEMM (argmax fixups). If part != nullptr: write plain partial at
// part + z*M*N (split-K, K range [z*kz, (z+1)*kz)). Else headed/plain store.
__global__ __launch_bounds__(256) void k_gemm(
    const float* __restrict__ A, const float* __restrict__ W,
    float* __restrict__ C, int M, int N, int K, int kz_len, int headed, int row_off,
    float* __restrict__ part)
{
    __shared__ float As[16][68];
    __shared__ float Bs[16][68];
    int tid = threadIdx.x;
    int bm = blockIdx.y * 64, bn = blockIdx.x * 64;
    int tr = tid >> 4, tc = tid & 15;
    int ar = tid >> 2, akk = (tid & 3) * 4;
    int bkk = tid >> 4, bn4 = (tid & 15) * 4;
    float acc[4][4] = {{0.f}};
    int garow = bm + ar;
    const float* Aptr = A + (size_t)garow * K + akk;
    const float* Wptr = W + (size_t)bkk * N + bn + bn4;
    int kbeg = blockIdx.z * kz_len;
    for (int k0 = kbeg; k0 < kbeg + kz_len; k0 += 16) {
        float4 av = make_float4(0.f, 0.f, 0.f, 0.f);
        if (garow < M) av = *(const float4*)(Aptr + k0);
        As[akk+0][ar] = av.x; As[akk+1][ar] = av.y; As[akk+2][ar] = av.z; As[akk+3][ar] = av.w;
        float4 bv = *(const float4*)(Wptr + (size_t)k0 * N);
        Bs[bkk][bn4+0] = bv.x; Bs[bkk][bn4+1] = bv.y; Bs[bkk][bn4+2] = bv.z; Bs[bkk][bn4+3] = bv.w;
        __syncthreads();
        #pragma unroll
        for (int kk = 0; kk < 16; ++kk) {
            float4 a = *(const float4*)&As[kk][tr*4];
            float4 bq = *(const float4*)&Bs[kk][tc*4];
            float avv[4] = {a.x, a.y, a.z, a.w};
            float bvv[4] = {bq.x, bq.y, bq.z, bq.w};
            #pragma unroll
            for (int i = 0; i < 4; ++i)
                #pragma unroll
                for (int j = 0; j < 4; ++j)
                    acc[i][j] += avv[i] * bvv[j];
        }
        __syncthreads();
    }
    #pragma unroll
    for (int i = 0; i < 4; ++i) {
        int r = bm + tr*4 + i;
        if (r >= M) continue;
        #pragma unroll
        for (int j = 0; j < 4; ++j) {
            int n = bn + tc*4 + j;
            float v = acc[i][j];
            if (part) {
                part[(size_t)blockIdx.z*M*N + (size_t)r*N + n] = v;
            } else if (headed) {
                int rg = r + row_off;
                int b = rg / S2_, s = rg % S2_;
                int hh = n >> 6, d = n & 63;
                C[(((size_t)b*HEADS_ + hh)*S2_ + s)*64 + d] = v;
            } else {
                C[(size_t)(r + row_off) * N + n] = v;
            }
        }
    }
}

// sum 2 fixup partials -> headed fp32 store into qh (batch1 img rows)
__global__ __launch_bounds__(256) void k_fixred(
    const float* __restrict__ pa, float* __restrict__ qh_out)
{
    long i = (long)blockIdx.x*256 + threadIdx.x;   // < 1536*1024
    int r = (int)(i >> 10), n = (int)(i & 1023);
    float v = pa[i] + pa[i + (long)IMG_*DIM_];
    int hh = n >> 6, d = n & 63;
    qh_out[(((size_t)HEADS_ + hh)*S2_ + TEXT_ + r)*64 + d] = v;
}

// per-head layernorm + RoPE: bf16 everywhere; fp32 write-back only for argmax rows
__global__ __launch_bounds__(256) void k_qk_prep(
    float* qh, float* kh, unsigned short* qbb, unsigned short* kbb,
    const float* __restrict__ nqw, const float* __restrict__ nqb,
    const float* __restrict__ nkw, const float* __restrict__ nkb,
    const float* __restrict__ rc, const float* __restrict__ rs)
{
    int which = blockIdx.y;
    int wid = threadIdx.x >> 6;
    int lane = threadIdx.x & 63;
    long row = (long)blockIdx.x * 4 + wid;   // (b*16+h)*S2 + s
    long s = row % S2_;
    bool b1 = row >= (long)HEADS_*S2_;
    float* base = (which ? kh : qh) + row * 64;
    const float* w  = which ? nkw : nqw;
    const float* bb = which ? nkb : nqb;
    float x = base[lane];
    float sum = x;
    for (int off = 1; off < 64; off <<= 1) sum += __shfl_xor(sum, off, 64);
    float mu = sum * (1.f / 64.f);
    float dx = x - mu;
    float v = dx * dx;
    for (int off = 1; off < 64; off <<= 1) v += __shfl_xor(v, off, 64);
    float rstd = rsqrtf(v * (1.f / 64.f) + 1e-6f);
    float y = dx * rstd * w[lane] + bb[lane];
    if (s >= TEXT_ && s < S_MAIN) {
        long p = s - TEXT_;
        float part = __shfl_xor(y, 1, 64);
        float rot = (lane & 1) ? part : -part;
        y = y * rc[p*64 + lane] + rot * rs[p*64 + lane];
    }
    bool needf = b1 && (which ? (s >= S_MAIN) : (s >= TEXT_ && s < S_MAIN));
    if (needf) base[lane] = y;
    (which ? kbb : qbb)[row * 64 + lane] = __builtin_bit_cast(unsigned short, (__bf16)y);
}

// MFMA flash attention: 128-q blocks (4 waves x 2 q-tiles), concept stream fused
// as the extra grid.x block. bf16 in, no-max softmax, ones-MFMA row sums.
__global__ __launch_bounds__(256) void k_flash(
    const unsigned short* __restrict__ qb, const unsigned short* __restrict__ kb,
    const unsigned short* __restrict__ vb,
    float* __restrict__ ao_out, float* __restrict__ ac_out, int nx_main)
{
    int bx = blockIdx.x;
    int h = blockIdx.y, b = blockIdx.z;
    int qt, NQ, q_off, r0s, r0e, r1s, r1e; float* obase;
    if (bx < nx_main) { qt = bx*128; NQ = S_MAIN; q_off = 0;      r0s = 0;      r0e = S_MAIN; r1s = 0;     r1e = 0;      obase = ao_out; }
    else              { qt = 0;      NQ = NC_;    q_off = S_MAIN; r0s = S_MAIN; r0e = S2_;    r1s = TEXT_; r1e = S_MAIN; obase = ac_out; }
    int tid = threadIdx.x;
    int w = tid >> 6, lane = tid & 63;
    int lr = lane & 15, lh = lane >> 4;
    __shared__ __align__(16) unsigned short kt[64*72];
    __shared__ __align__(16) unsigned short vt[64*72];
    __shared__ __align__(16) unsigned short pbuf[4*32*72];
    unsigned short* pw = pbuf + w*32*72;
    const unsigned short* qbase = qb + (((size_t)b*HEADS_ + h)*S2_ + q_off)*64;
    const unsigned short* kbase = kb + ((size_t)b*HEADS_ + h)*S2_*64;
    const unsigned short* vbase = vb + (size_t)(b*HEADS_ + h)*64*VPAD_;
    bf16x8_t aq[2][2];
    #pragma unroll
    for (int t = 0; t < 2; ++t) {
        int qrow = qt + w*32 + t*16 + lr; if (qrow >= NQ) qrow = NQ - 1;
        const unsigned short* qsrc = qbase + (size_t)qrow*64 + lh*8;
        aq[t][0] = __builtin_bit_cast(bf16x8_t, *(const int4*)qsrc);
        aq[t][1] = __builtin_bit_cast(bf16x8_t, *(const int4*)(qsrc + 32));
    }
    int4 onesi = make_int4(0x3F803F80, 0x3F803F80, 0x3F803F80, 0x3F803F80);
    bf16x8_t bones = __builtin_bit_cast(bf16x8_t, onesi);
    f32x4_t O[2][4];
    f32x4_t Lacc[2];
    #pragma unroll
    for (int t = 0; t < 2; ++t) {
        Lacc[t][0]=0.f; Lacc[t][1]=0.f; Lacc[t][2]=0.f; Lacc[t][3]=0.f;
        #pragma unroll
        for (int g = 0; g < 4; ++g) { O[t][g][0]=0.f; O[t][g][1]=0.f; O[t][g][2]=0.f; O[t][g][3]=0.f; }
    }
    for (int rgi = 0; rgi < 2; ++rgi) {
        int rs = rgi ? r1s : r0s, re = rgi ? r1e : r0e;
        for (int j0 = rs; j0 < re; j0 += 64) {
            int cnt = min(64, re - j0);
            __syncthreads();
            #pragma unroll
            for (int i = 0; i < 2; ++i) {
                int idx = tid + i*256;
                int key = idx >> 3, p8 = idx & 7;
                int krow = j0 + key; if (krow > re - 1) krow = re - 1;
                *(int4*)&kt[key*72 + p8*8] = *(const int4*)(kbase + (size_t)krow*64 + p8*8);
            }
            #pragma unroll
            for (int i = 0; i < 2; ++i) {
                int idx = tid + i*256;
                int d = idx >> 3, p8 = idx & 7;
                *(int4*)&vt[d*72 + p8*8] = *(const int4*)(vbase + (size_t)d*VPAD_ + j0 + p8*8);
            }
            __syncthreads();
            f32x4_t S[2][4];
            #pragma unroll
            for (int g = 0; g < 4; ++g) {
                const unsigned short* kr = &kt[(16*g + lr)*72 + lh*8];
                bf16x8_t b0 = __builtin_bit_cast(bf16x8_t, *(const int4*)kr);
                bf16x8_t b1 = __builtin_bit_cast(bf16x8_t, *(const int4*)(kr + 32));
                #pragma unroll
                for (int t = 0; t < 2; ++t) {
                    f32x4_t z; z[0]=0.f; z[1]=0.f; z[2]=0.f; z[3]=0.f;
                    z = __builtin_amdgcn_mfma_f32_16x16x32_bf16(aq[t][0], b0, z, 0, 0, 0);
                    z = __builtin_amdgcn_mfma_f32_16x16x32_bf16(aq[t][1], b1, z, 0, 0, 0);
                    S[t][g] = z;
                }
            }
            #pragma unroll
            for (int t = 0; t < 2; ++t)
                #pragma unroll
                for (int g = 0; g < 4; ++g) {
                    bool vld = (16*g + lr) < cnt;
                    #pragma unroll
                    for (int r = 0; r < 4; ++r) {
                        float p = vld ? __expf(S[t][g][r] * 0.125f) : 0.f;
                        pw[(t*16 + lh*4 + r)*72 + 16*g + lr] = __builtin_bit_cast(unsigned short, (__bf16)p);
                    }
                }
            #pragma unroll
            for (int c = 0; c < 2; ++c) {
                bf16x8_t ap[2];
                #pragma unroll
                for (int t = 0; t < 2; ++t) {
                    ap[t] = __builtin_bit_cast(bf16x8_t,
                        *(const int4*)&pw[(t*16 + lr)*72 + c*32 + lh*8]);
                    Lacc[t] = __builtin_amdgcn_mfma_f32_16x16x32_bf16(ap[t], bones, Lacc[t], 0, 0, 0);
                }
                #pragma unroll
                for (int g = 0; g < 4; ++g) {
                    bf16x8_t bv = __builtin_bit_cast(bf16x8_t,
                        *(const int4*)&vt[(16*g + lr)*72 + c*32 + lh*8]);
                    #pragma unroll
                    for (int t = 0; t < 2; ++t)
                        O[t][g] = __builtin_amdgcn_mfma_f32_16x16x32_bf16(ap[t], bv, O[t][g], 0, 0, 0);
                }
            }
        }
    }
    #pragma unroll
    for (int t = 0; t < 2; ++t)
        #pragma unroll
        for (int r = 0; r < 4; ++r) {
            float inv = 1.f / Lacc[t][r];
            int gq = qt + w*32 + t*16 + lh*4 + r;
            if (gq < NQ) {
                float* o = obase + (((size_t)b*HEADS_ + h)*NQ + gq)*64 + lr;
                #pragma unroll
                for (int g = 0; g < 4; ++g) o[16*g] = O[t][g][r] * inv;
            }
        }
}

__global__ __launch_bounds__(256) void k_head_score(const float* __restrict__ ao, float* __restrict__ score)
{
    int h = blockIdx.x, tid = threadIdx.x;
    const float* base = ao + (((long)HEADS_ + h)*S_MAIN + TEXT_)*64;
    float sA = 0.f, sB = 0.f;
    for (int p = tid; p < IMG_; p += 256) {
        const float* r = base + (long)p*64;
        float mm = 0.f;
        for (int d = 0; d < 64; d += 4) {
            float4 v = *(const float4*)(r + d);
            mm += v.x + v.y + v.z + v.w;
        }
        mm *= (1.f / 64.f);
        sA += mm; sB += mm*mm;
    }
    __shared__ float r1[256], r2[256];
    r1[tid] = sA; r2[tid] = sB; __syncthreads();
    for (int st = 128; st; st >>= 1) {
        if (tid < st) { r1[tid] += r1[tid+st]; r2[tid] += r2[tid+st]; }
        __syncthreads();
    }
    if (tid == 0) {
        float mean = r1[0] / IMG_, ms = r2[0] / IMG_;
        score[h] = sqrtf(fmaxf(ms - mean*mean, 0.f));
    }
}

__global__ void k_top4(const float* __restrict__ score, int* __restrict__ sel)
{
    if (threadIdx.x == 0 && blockIdx.x == 0) {
        int used = 0;
        for (int k = 0; k < 4; ++k) {
            float best = -INFINITY; int bi = 0;
            for (int h2 = 0; h2 < 16; ++h2) {
                if (used & (1 << h2)) continue;
                if (score[h2] > best) { best = score[h2]; bi = h2; }
            }
            used |= 1 << bi; sel[k] = bi;
        }
    }
}

__global__ __launch_bounds__(512) void k_sim(
    const float* __restrict__ qh, const float* __restrict__ kh,
    float* __restrict__ sim, int* __restrict__ selvis)
{
    int blk = blockIdx.x;    // (h*8+t)*4+f
    int h = blk >> 5, t = (blk >> 2) & 7, f = blk & 3;
    int tid = threadIdx.x;
    __shared__ float ckv[64];
    if (tid < 64) ckv[tid] = kh[(((long)HEADS_ + h)*S2_ + S_MAIN + t)*64 + tid];
    __syncthreads();
    float val = -INFINITY; int idx = 0x7fffffff;
    if (tid < PATCHES_) {
        const float* qrow = qh + (((long)HEADS_ + h)*S2_ + TEXT_ + f*PATCHES_ + tid)*64;
        float acc = 0.f;
        for (int d = 0; d < 64; d += 4) {
            float4 qv = *(const float4*)(qrow + d);
            acc += qv.x*ckv[d] + qv.y*ckv[d+1] + qv.z*ckv[d+2] + qv.w*ckv[d+3];
        }
        sim[((long)h*NC_ + t)*IMG_ + f*PATCHES_ + tid] = acc;
        val = acc; idx = tid;
    }
    __shared__ float sv[512]; __shared__ int si[512];
    sv[tid] = val; si[tid] = idx; __syncthreads();
    for (int st = 256; st; st >>= 1) {
        if (tid < st) {
            float v2 = sv[tid+st]; int i2 = si[tid+st];
            if (v2 > sv[tid] || (v2 == sv[tid] && i2 < si[tid])) { sv[tid] = v2; si[tid] = i2; }
        }
        __syncthreads();
    }
    if (tid == 0) selvis[blk] = si[0];
}

__global__ __launch_bounds__(256) void k_cross(const float* __restrict__ sim, float* __restrict__ out)
{
    int i = blockIdx.x*256 + threadIdx.x;   // < 12288
    int c = i / IMG_, p = i % IMG_;
    float acc = 0.f;
    for (int h = 0; h < 16; ++h) acc += sim[((long)h*NC_ + c)*IMG_ + p];
    out[O_XMAP + i] = acc * (1.f / 16.f);
}

__global__ __launch_bounds__(256) void k_concept_maps(
    const float* __restrict__ ac, const float* __restrict__ ao, float* __restrict__ out)
{
    int i = blockIdx.x*256 + threadIdx.x;   // < 12288
    int c = i / IMG_, p = i % IMG_;
    float acc = 0.f;
    for (int h = 0; h < 16; ++h) {
        const float* a = ac + (((long)HEADS_ + h)*NC_ + c)*64;
        const float* g = ao + (((long)HEADS_ + h)*S_MAIN + TEXT_ + p)*64;
        for (int d = 0; d < 64; d += 4) {
            float4 av = *(const float4*)(a + d);
            float4 gv = *(const float4*)(g + d);
            acc += av.x*gv.x + av.y*gv.y + av.z*gv.z + av.w*gv.w;
        }
    }
    out[O_CMAP + i] = acc;
}

__global__ void k_imap_raw(const float* __restrict__ ao, const int* __restrict__ selvis,
                           float* __restrict__ imap)
{
    int blk = blockIdx.x;   // (h*8+t)*4+f
    int h = blk >> 5, t = (blk >> 2) & 7, f = blk & 3;
    int tid = threadIdx.x;  // 384
    __shared__ float sel[64];
    int pstar = selvis[blk];
    if (tid < 64) sel[tid] = ao[(((long)HEADS_ + h)*S_MAIN + TEXT_ + f*PATCHES_ + pstar)*64 + tid];
    __syncthreads();
    const float* g = ao + (((long)HEADS_ + h)*S_MAIN + TEXT_ + f*PATCHES_ + tid)*64;
    float acc = 0.f;
    for (int d = 0; d < 64; d += 4) {
        float4 gv = *(const float4*)(g + d);
        acc += gv.x*sel[d] + gv.y*sel[d+1] + gv.z*sel[d+2] + gv.w*sel[d+3];
    }
    imap[((long)h*NC_ + t)*IMG_ + f*PATCHES_ + tid] = acc;
}

__global__ __launch_bounds__(256) void k_imap_norm(float* __restrict__ imap)
{
    int i = blockIdx.x*256 + threadIdx.x;   // < 24576
    int h = i / IMG_, fp = i % IMG_;
    float v[8]; float mu = 0.f;
    #pragma unroll
    for (int t = 0; t < 8; ++t) { v[t] = imap[((long)h*NC_ + t)*IMG_ + fp]; mu += v[t]; }
    mu *= 0.125f;
    float var = 0.f;
    #pragma unroll
    for (int t = 0; t < 8; ++t) var += (v[t]-mu)*(v[t]-mu);
    float sd = sqrtf(var * (1.f / 7.f));
    float inv = 1.f / (sd + 1e-6f);
    #pragma unroll
    for (int t = 0; t < 8; ++t) imap[((long)h*NC_ + t)*IMG_ + fp] = (v[t]-mu)*inv;
}

__global__ __launch_bounds__(256) void k_imap_reduce(
    const float* __restrict__ imap, const int* __restrict__ sel, float* __restrict__ out)
{
    int i = blockIdx.x*256 + threadIdx.x;   // < 12288
    int t = i / IMG_, fp = i % IMG_;
    float sum = 0.f;
    for (int h = 0; h < 16; ++h) sum += imap[((long)h*NC_ + t)*IMG_ + fp];
    float ss = 0.f;
    for (int k = 0; k < 4; ++k) { int h = sel[k]; ss += imap[((long)h*NC_ + t)*IMG_ + fp]; }
    out[O_ISUM + i] = sum;
    out[O_SELI + i] = ss * 0.25f;
}

__global__ __launch_bounds__(256) void k_merge(
    const float* __restrict__ ao, const float* __restrict__ ac, unsigned short* __restrict__ xo)
{
    long i = (long)blockIdx.x*256 + threadIdx.x;
    int col = (int)(i & 1023);
    long row = i >> 10;
    int b = (int)(row / S2_), s = (int)(row % S2_);
    int h = col >> 6, d = col & 63;
    float v;
    if (s < S_MAIN) v = ao[(((long)b*HEADS_ + h)*S_MAIN + s)*64 + d];
    else            v = ac[(((long)b*HEADS_ + h)*NC_ + (s - S_MAIN))*64 + d];
    xo[i] = __builtin_bit_cast(unsigned short, (__bf16)v);
}

// residual with fused split-K reduce: X = orig + gate * (p0 + p1 + bo)
__global__ __launch_bounds__(256) void k_residual1(
    const float* __restrict__ pe, const float* __restrict__ ph, const float* __restrict__ pc,
    const float* __restrict__ p0, const float* __restrict__ p1, const float* __restrict__ bo,
    const float* __restrict__ s1, float* __restrict__ X)
{
    long i = (long)blockIdx.x*256 + threadIdx.x;
    int col = (int)(i & 1023);
    long row = i >> 10;
    int b = (int)(row / S2_), s = (int)(row % S2_);
    const float* sb = s1 + (long)b * 6144;
    float orig, gate;
    if (s < TEXT_)       { orig = pe[((long)b*TEXT_ + s)*DIM_ + col];            gate = sb[5120 + col]; }
    else if (s < S_MAIN) { orig = ph[((long)b*IMG_ + (s-TEXT_))*DIM_ + col];     gate = sb[2048 + col]; }
    else                 { orig = pc[((long)b*NC_ + (s-S_MAIN))*DIM_ + col];     gate = sb[5120 + col]; }
    X[i] = orig + gate * (p0[i] + p1[i] + bo[col]);
}

// final with fused split-K reduce: out = X + gate * (f0 + f1 + fb2)
__global__ __launch_bounds__(256) void k_final(
    const float* __restrict__ X, const float* __restrict__ f0, const float* __restrict__ f1,
    const float* __restrict__ fb2, const float* __restrict__ s2, float* __restrict__ out)
{
    long i = (long)blockIdx.x*256 + threadIdx.x;
    int col = (int)(i & 1023);
    long row = i >> 10;
    int b = (int)(row / S2_), s = (int)(row % S2_);
    const float* sb = s2 + (long)b * 6144;
    float gate; float* o;
    if (s < TEXT_)       { gate = sb[5120 + col]; o = out + O_E + ((long)b*TEXT_ + s)*DIM_ + col; }
    else if (s < S_MAIN) { gate = sb[2048 + col]; o = out + O_H + ((long)b*IMG_ + (s-TEXT_))*DIM_ + col; }
    else                 { gate = sb[5120 + col]; o = out + O_C + ((long)b*NC_ + (s-S_MAIN))*DIM_ + col; }
    *o = X[i] + gate * (f0[i] + f1[i] + fb2[col]);
}

extern "C" void kernel_launch(void* const* d_in, const int* in_sizes, int n_in,
                              void* d_out, int out_size, void* d_ws, size_t ws_size,
                              hipStream_t stream)
{
    (void)in_sizes; (void)n_in; (void)out_size; (void)ws_size;
    const float* h_in = (const float*)d_in[0];
    const float* e_in = (const float*)d_in[1];
    const float* c_in = (const float*)d_in[2];
    const float* temb = (const float*)d_in[3];
    const float* rcos = (const float*)d_in[4];
    const float* rsin = (const float*)d_in[5];
    const float* n1w  = (const float*)d_in[6];
    const float* n1b  = (const float*)d_in[7];
    const float* ln1w = (const float*)d_in[8];
    const float* ln1b = (const float*)d_in[9];
    const float* n2w  = (const float*)d_in[10];
    const float* n2b  = (const float*)d_in[11];
    const float* ln2w = (const float*)d_in[12];
    const float* ln2b = (const float*)d_in[13];
    const float* wq   = (const float*)d_in[14];
    const float* wk   = (const float*)d_in[15];
    const float* wv   = (const float*)d_in[16];
    const float* nqw  = (const float*)d_in[17];
    const float* nqb  = (const float*)d_in[18];
    const float* nkw  = (const float*)d_in[19];
    const float* nkb  = (const float*)d_in[20];
    const float* wo   = (const float*)d_in[21];
    const float* bo   = (const float*)d_in[22];
    const float* fw1  = (const float*)d_in[23];
    const float* fb1  = (const float*)d_in[24];
    const float* fw2  = (const float*)d_in[25];
    const float* fb2  = (const float*)d_in[26];

    float* ws  = (float*)d_ws;
    float* out = (float*)d_out;
    float* s1   = ws + OFF_S1;
    float* s2   = ws + OFF_S2;
    float* score  = ws + OFF_MISC;
    int*   selh   = (int*)(ws + OFF_MISC + 16);
    int*   selvis = (int*)(ws + OFF_MISC + 32);
    float* sim  = ws + OFF_SIM;
    float* imap = ws + OFF_IMAP;
    float* ac   = ws + OFF_AC;
    float* X    = ws + OFF_X;
    float* proj = ws + OFF_PROJ;
    float* xn   = ws + OFF_XN;
    float* qh   = ws + OFF_Q;
    float* kh   = ws + OFF_K;
    float* vh   = ws + OFF_V;
    float* ao   = ws + OFF_AO;
    float* ffo  = proj;
    float* fixp = ws + OFF_AO;             // fixup split-K partials (2 x 1536x1024)
    unsigned short* xnb   = (unsigned short*)(ws + OFF_XNB);
    unsigned short* wqkvT = (unsigned short*)(ws + OFF_PROJ);
    unsigned short* vb    = (unsigned short*)(ws + OFF_PROJ);
    unsigned short* qbb   = (unsigned short*)(ws + OFF_X);
    unsigned short* kbb   = qbb + (size_t)B_*HEADS_*S2_*64;
    unsigned short* woT   = (unsigned short*)(ws + OFF_AO + 2000000);
    unsigned short* fw1T  = (unsigned short*)(ws + OFF_V);
    unsigned short* fw2T  = (unsigned short*)(ws + OFF_AO);
    unsigned short* ffh   = (unsigned short*)(ws + OFF_Q);

    // 1. adaLN modulation vectors
    hipLaunchKernelGGL(k_silu_mod, dim3(384), dim3(256), 0, stream, temb, n1w, n1b, n2w, n2b, s1, s2);
    // 2. QKV weight transposes (batched z=3)
    hipLaunchKernelGGL(k_tcvt_qkv, dim3(32, 32, 3), dim3(256), 0, stream, wq, wk, wv, wqkvT);
    // 3. norm1 + modulation -> xn fp32 + xnb bf16
    hipLaunchKernelGGL(k_ln_mod, dim3(ROWS_), dim3(256), 0, stream,
        e_in, (long)TEXT_*DIM_, h_in, (long)IMG_*DIM_, c_in, (long)NC_*DIM_, s1, ln1w, ln1b, xn, xnb);
    // 4. fused QKV bf16 GEMM, headed fp32 scatter
    hipLaunchKernelGGL(k_bgemm, dim3(24, 28, 1), dim3(256), 0, stream,
        xnb, wqkvT, (const float*)nullptr, (float*)nullptr, (unsigned short*)nullptr,
        ROWS_, 3072, 1024, 1024, 0, qh, kh, vh);
    // 5. fp32 q-fixup split-K x2 -> partials, then reduce into headed qh
    hipLaunchKernelGGL(k_gemm, dim3(16, 24, 2), dim3(256), 0, stream,
        xn + (long)(S2_ + TEXT_)*DIM_, wq, (float*)nullptr, IMG_, DIM_, DIM_, 512, 0, 0, fixp);
    hipLaunchKernelGGL(k_fixred, dim3(6144), dim3(256), 0, stream, fixp, qh);
    // 6. fp32 k-fixup (8 concept rows, batch 1) headed
    hipLaunchKernelGGL(k_gemm, dim3(16, 1, 1), dim3(256), 0, stream,
        xn + (long)(S2_ + S_MAIN)*DIM_, wk, kh, NC_, DIM_, DIM_, 1024, 1, S2_ + S_MAIN, (float*)nullptr);
    // 7. QK layernorm + RoPE; V transpose to bf16
    hipLaunchKernelGGL(k_qk_prep, dim3(14160, 2), dim3(256), 0, stream,
        qh, kh, qbb, kbb, nqw, nqb, nkw, nkb, rcos, rsin);
    hipLaunchKernelGGL(k_vtrans, dim3(56, 2, 32), dim3(256), 0, stream, vh, vb);
    // 8. attention (main 14 blocks + concept fused as block 14)
    hipLaunchKernelGGL(k_flash, dim3(15, 16, 2), dim3(256), 0, stream,
        qbb, kbb, vb, ao, ac, 14);
    // 9. maps (batch 1)
    hipLaunchKernelGGL(k_head_score, dim3(16), dim3(256), 0, stream, ao, score);
    hipLaunchKernelGGL(k_top4, dim3(1), dim3(64), 0, stream, score, selh);
    hipLaunchKernelGGL(k_sim, dim3(512), dim3(512), 0, stream, qh, kh, sim, selvis);
    hipLaunchKernelGGL(k_cross, dim3(48), dim3(256), 0, stream, sim, out);
    hipLaunchKernelGGL(k_concept_maps, dim3(48), dim3(256), 0, stream, ac, ao, out);
    hipLaunchKernelGGL(k_imap_raw, dim3(512), dim3(384), 0, stream, ao, selvis, imap);
    hipLaunchKernelGGL(k_imap_norm, dim3(96), dim3(256), 0, stream, imap);
    hipLaunchKernelGGL(k_imap_reduce, dim3(48), dim3(256), 0, stream, imap, selh, out);
    // 10. merge -> xnb bf16; wo transpose into dead ao region
    hipLaunchKernelGGL(k_merge, dim3(14160), dim3(256), 0, stream, ao, ac, xnb);
    hipLaunchKernelGGL(k_tcvt, dim3(32, 32), dim3(256), 0, stream, wo, woT, 1024, 1024);
    // 11. wo GEMM split-K x2 (partials at PROJ / XN)
    hipLaunchKernelGGL(k_bgemm, dim3(8, 28, 2), dim3(256), 0, stream,
        xnb, woT, (const float*)nullptr, proj, (unsigned short*)nullptr, ROWS_, DIM_, 1024, 512, 1,
        (float*)nullptr, (float*)nullptr, (float*)nullptr);
    // 12. residual1 (fused reduce + bias) -> X
    hipLaunchKernelGGL(k_residual1, dim3(14160), dim3(256), 0, stream,
        e_in, h_in, c_in, proj, proj + (size_t)ROWS_*DIM_, bo, s1, X);
    // 13. FF weight transposes
    hipLaunchKernelGGL(k_tcvt, dim3(128, 32), dim3(256), 0, stream, fw1, fw1T, 1024, 4096);
    hipLaunchKernelGGL(k_tcvt, dim3(32, 128), dim3(256), 0, stream, fw2, fw2T, 4096, 1024);
    // 14. norm2 -> xnb bf16 only
    hipLaunchKernelGGL(k_ln_mod, dim3(ROWS_), dim3(256), 0, stream,
        X, (long)S2_*DIM_, X + (long)TEXT_*DIM_, (long)S2_*DIM_, X + (long)S_MAIN*DIM_, (long)S2_*DIM_,
        s2, ln2w, ln2b, (float*)nullptr, xnb);
    // 15. ff1 (gelu fused, bf16 out)
    hipLaunchKernelGGL(k_bgemm, dim3(32, 28, 1), dim3(256), 0, stream,
        xnb, fw1T, fb1, (float*)nullptr, ffh, ROWS_, FF_, 1024, 1024, 2,
        (float*)nullptr, (float*)nullptr, (float*)nullptr);
    // 16. ff2 split-K x2 (partials at PROJ / XN)
    hipLaunchKernelGGL(k_bgemm, dim3(8, 28, 2), dim3(256), 0, stream,
        ffh, fw2T, (const float*)nullptr, ffo, (unsigned short*)nullptr, ROWS_, DIM_, FF_, 2048, 1,
        (float*)nullptr, (float*)nullptr, (float*)nullptr);
    // 17. final (fused reduce + bias) -> outputs
    hipLaunchKernelGGL(k_final, dim3(14160), dim3(256), 0, stream,
        X, ffo, ffo + (size_t)ROWS_*DIM_, fb2, s2, out);
}